// Round 7
// baseline (961.042 us; speedup 1.0000x reference)
//
#include <hip/hip_runtime.h>
#include <cstddef>
#include <cstdint>

#define EPSF 1e-5f

constexpr int BB = 32, SS = 512, DD = 512, HH = 8, DH = 64;
constexpr int NTOK = BB * SS;              // 16384 rows
constexpr size_t ND = (size_t)NTOK * DD;   // 8,388,608

typedef __attribute__((ext_vector_type(8))) short bf16x8;
typedef __attribute__((ext_vector_type(4))) float f32x4;

__device__ __forceinline__ float sigmf(float v) { return 1.f / (1.f + __expf(-v)); }

__device__ __forceinline__ ushort f2bf(float f) {
  union { float f; uint32_t u; } x{f};
  uint32_t r = x.u + 0x7FFF + ((x.u >> 16) & 1);
  return (ushort)(r >> 16);
}
__device__ __forceinline__ float bf2f(ushort u) {
  union { uint32_t u; float f; } x{(uint32_t)u << 16};
  return x.f;
}

__device__ __forceinline__ void gload16(const ushort* g, ushort* ldsbase) {
  __builtin_amdgcn_global_load_lds((const __attribute__((address_space(1))) void*)g,
                                   (__attribute__((address_space(3))) void*)ldsbase, 16, 0, 0);
}

// bijective XCD-chunk swizzle (m204); requires nwg % 8 == 0.
__device__ __forceinline__ void xcd_swz(int& bx, int& by) {
  const int gx = gridDim.x;
  const int nwg = gx * gridDim.y;
  const int cpx = nwg >> 3;
  int id = by * gx + bx;
  id = (id & 7) * cpx + (id >> 3);
  bx = id % gx;
  by = id / gx;
}

// ---------------- LayerNorm: one wave per row, f32 out --------------------------
__global__ __launch_bounds__(256) void ln_f32(const float* __restrict__ x,
                                              const float* __restrict__ g,
                                              const float* __restrict__ b,
                                              float* __restrict__ y) {
  const int lane = threadIdx.x & 63;
  const int row = blockIdx.x * 4 + (threadIdx.x >> 6);
  const float* xr = x + (size_t)row * 512;
  const float4 v0 = *(const float4*)&xr[lane << 2];
  const float4 v1 = *(const float4*)&xr[256 + (lane << 2)];
  float s = v0.x + v0.y + v0.z + v0.w + v1.x + v1.y + v1.z + v1.w;
#pragma unroll
  for (int o = 32; o > 0; o >>= 1) s += __shfl_xor(s, o);
  const float mean = s * (1.f / 512.f);
  float q = 0.f;
  q += (v0.x - mean) * (v0.x - mean); q += (v0.y - mean) * (v0.y - mean);
  q += (v0.z - mean) * (v0.z - mean); q += (v0.w - mean) * (v0.w - mean);
  q += (v1.x - mean) * (v1.x - mean); q += (v1.y - mean) * (v1.y - mean);
  q += (v1.z - mean) * (v1.z - mean); q += (v1.w - mean) * (v1.w - mean);
#pragma unroll
  for (int o = 32; o > 0; o >>= 1) q += __shfl_xor(q, o);
  const float rs = rsqrtf(q * (1.f / 512.f) + EPSF);
  const float4 g0 = *(const float4*)&g[lane << 2];
  const float4 g1 = *(const float4*)&g[256 + (lane << 2)];
  const float4 b0 = *(const float4*)&b[lane << 2];
  const float4 b1 = *(const float4*)&b[256 + (lane << 2)];
  float* yr = y + (size_t)row * 512;
  float4 o0, o1;
  o0.x = (v0.x - mean) * rs * g0.x + b0.x; o0.y = (v0.y - mean) * rs * g0.y + b0.y;
  o0.z = (v0.z - mean) * rs * g0.z + b0.z; o0.w = (v0.w - mean) * rs * g0.w + b0.w;
  o1.x = (v1.x - mean) * rs * g1.x + b1.x; o1.y = (v1.y - mean) * rs * g1.y + b1.y;
  o1.z = (v1.z - mean) * rs * g1.z + b1.z; o1.w = (v1.w - mean) * rs * g1.w + b1.w;
  *(float4*)&yr[lane << 2] = o0;
  *(float4*)&yr[256 + (lane << 2)] = o1;
}

// ---------------- LayerNorm writing bf16 ----------------------------------------
__global__ __launch_bounds__(256) void ln_bf16(const float* __restrict__ x,
                                               const float* __restrict__ g,
                                               const float* __restrict__ b,
                                               ushort* __restrict__ y) {
  const int lane = threadIdx.x & 63;
  const int row = blockIdx.x * 4 + (threadIdx.x >> 6);
  const float* xr = x + (size_t)row * 512;
  const float4 v0 = *(const float4*)&xr[lane << 2];
  const float4 v1 = *(const float4*)&xr[256 + (lane << 2)];
  float s = v0.x + v0.y + v0.z + v0.w + v1.x + v1.y + v1.z + v1.w;
#pragma unroll
  for (int o = 32; o > 0; o >>= 1) s += __shfl_xor(s, o);
  const float mean = s * (1.f / 512.f);
  float q = 0.f;
  q += (v0.x - mean) * (v0.x - mean); q += (v0.y - mean) * (v0.y - mean);
  q += (v0.z - mean) * (v0.z - mean); q += (v0.w - mean) * (v0.w - mean);
  q += (v1.x - mean) * (v1.x - mean); q += (v1.y - mean) * (v1.y - mean);
  q += (v1.z - mean) * (v1.z - mean); q += (v1.w - mean) * (v1.w - mean);
#pragma unroll
  for (int o = 32; o > 0; o >>= 1) q += __shfl_xor(q, o);
  const float rs = rsqrtf(q * (1.f / 512.f) + EPSF);
  const float4 g0 = *(const float4*)&g[lane << 2];
  const float4 g1 = *(const float4*)&g[256 + (lane << 2)];
  const float4 b0 = *(const float4*)&b[lane << 2];
  const float4 b1 = *(const float4*)&b[256 + (lane << 2)];
  ushort* yr = y + (size_t)row * 512;
  ushort4 o0, o1;
  o0.x = f2bf((v0.x - mean) * rs * g0.x + b0.x); o0.y = f2bf((v0.y - mean) * rs * g0.y + b0.y);
  o0.z = f2bf((v0.z - mean) * rs * g0.z + b0.z); o0.w = f2bf((v0.w - mean) * rs * g0.w + b0.w);
  o1.x = f2bf((v1.x - mean) * rs * g1.x + b1.x); o1.y = f2bf((v1.y - mean) * rs * g1.y + b1.y);
  o1.z = f2bf((v1.z - mean) * rs * g1.z + b1.z); o1.w = f2bf((v1.w - mean) * rs * g1.w + b1.w);
  *(ushort4*)&yr[lane << 2] = o0;
  *(ushort4*)&yr[256 + (lane << 2)] = o1;
}

// ---------------- merged weight transpose: 11 segments, one dispatch ------------
struct TpArgs {
  const float* src[11];
  ushort* dst[11];
  int K[11];
  int N[11];
  int base[12];
};

__global__ __launch_bounds__(256) void transpose_all(TpArgs a) {
  __shared__ float tile[32][33];
  int s = 0;
  const int bid = blockIdx.x;
  while (s < 10 && bid >= a.base[s + 1]) ++s;
  const int r = bid - a.base[s];
  const int K = a.K[s], N = a.N[s];
  const int ntx = N >> 5;
  const int n0 = (r % ntx) << 5;
  const int k0 = (r / ntx) << 5;
  const float* in = a.src[s];
  ushort* out = a.dst[s];
  const int tx = threadIdx.x & 31, ty = threadIdx.x >> 5;
#pragma unroll
  for (int i = 0; i < 32; i += 8)
    tile[ty + i][tx] = in[(size_t)(k0 + ty + i) * N + n0 + tx];
  __syncthreads();
#pragma unroll
  for (int i = 0; i < 32; i += 8)
    out[(size_t)(n0 + ty + i) * K + k0 + tx] = f2bf(tile[tx][ty + i]);
}

// ---------------- bf16 MFMA GEMM, T3-minimum 2-phase double-buffer --------------
template <int ACT, int RES, int HB, int OBF>
__global__ __launch_bounds__(256) void gemm_bf16(const ushort* __restrict__ A,
                                                 const ushort* __restrict__ Wt,
                                                 const float* __restrict__ bias,
                                                 const float* __restrict__ res,
                                                 void* __restrict__ Cv,
                                                 int M, int K, int N) {
  __shared__ ushort Al[2][8192];
  __shared__ ushort Bl[2][8192];
  const int t = threadIdx.x;
  const int lane = t & 63;
  const int w = t >> 6;
  const int wr = (w >> 1) << 6, wc = (w & 1) << 6;
  int bx = blockIdx.x, by = blockIdx.y;
  xcd_swz(bx, by);
  const int m0 = by << 7, n0 = bx << 7;
  const int lm = lane & 15;
  const int grow = lane >> 3;
  const int gcol = (lane & 7) << 3;

  f32x4 acc[4][4];
#pragma unroll
  for (int i = 0; i < 4; ++i)
#pragma unroll
    for (int j = 0; j < 4; ++j) acc[i][j] = (f32x4)(0.f);

  const int NT = K >> 6;
#pragma unroll
  for (int i = 0; i < 4; ++i) {
    const int s = (w << 2) + i;
    gload16(A + (size_t)(m0 + (s << 3) + grow) * K + gcol, &Al[0][s << 9]);
    gload16(Wt + (size_t)(n0 + (s << 3) + grow) * K + gcol, &Bl[0][s << 9]);
  }
  __syncthreads();
  int cur = 0;
  for (int tt = 0; tt < NT; ++tt) {
    if (tt + 1 < NT) {
      const int k0 = (tt + 1) << 6;
#pragma unroll
      for (int i = 0; i < 4; ++i) {
        const int s = (w << 2) + i;
        gload16(A + (size_t)(m0 + (s << 3) + grow) * K + k0 + gcol, &Al[cur ^ 1][s << 9]);
        gload16(Wt + (size_t)(n0 + (s << 3) + grow) * K + k0 + gcol, &Bl[cur ^ 1][s << 9]);
      }
    }
#pragma unroll
    for (int ks = 0; ks < 2; ++ks) {
      const int kof = (ks << 5) + ((lane >> 4) << 3);
      bf16x8 af[4], bfr[4];
#pragma unroll
      for (int i = 0; i < 4; ++i) af[i] = *(const bf16x8*)&Al[cur][(wr + (i << 4) + lm) * 64 + kof];
#pragma unroll
      for (int j = 0; j < 4; ++j) bfr[j] = *(const bf16x8*)&Bl[cur][(wc + (j << 4) + lm) * 64 + kof];
#pragma unroll
      for (int i = 0; i < 4; ++i)
#pragma unroll
        for (int j = 0; j < 4; ++j)
          acc[i][j] = __builtin_amdgcn_mfma_f32_16x16x32_bf16(af[i], bfr[j], acc[i][j], 0, 0, 0);
    }
    __syncthreads();
    cur ^= 1;
  }

  float bb[4] = {0.f, 0.f, 0.f, 0.f};
  if (HB) {
#pragma unroll
    for (int j = 0; j < 4; ++j) bb[j] = bias[n0 + wc + j * 16 + lm];
  }
  const int rbase = m0 + wr + ((lane >> 4) << 2);
#pragma unroll
  for (int i = 0; i < 4; ++i) {
#pragma unroll
    for (int r = 0; r < 4; ++r) {
      const size_t row = (size_t)(rbase + i * 16 + r);
#pragma unroll
      for (int j = 0; j < 4; ++j) {
        const int col = n0 + wc + j * 16 + lm;
        float v = acc[i][j][r] + bb[j];
        if (ACT == 1) v = v * sigmf(v);
        if (RES == 1) v += res[row * N + col];
        else if (RES == 2) v = res[row * N + col] + 0.5f * v;
        if (OBF) ((ushort*)Cv)[row * N + col] = f2bf(v);
        else ((float*)Cv)[row * N + col] = v;
      }
    }
  }
}

// ---------------- merged QKV projection: N=1536, routed epilogue ----------------
__global__ __launch_bounds__(256) void gemm_qkv(const ushort* __restrict__ A,
                                                const ushort* __restrict__ Wt,
                                                const float* __restrict__ bq,
                                                const float* __restrict__ bk,
                                                const float* __restrict__ bv,
                                                const float* __restrict__ ub,
                                                const float* __restrict__ vb,
                                                ushort* __restrict__ qu,
                                                ushort* __restrict__ qv,
                                                ushort* __restrict__ kbb,
                                                ushort* __restrict__ vT,
                                                int M, int K) {
  __shared__ ushort Al[2][8192];
  __shared__ ushort Bl[2][8192];
  const int t = threadIdx.x;
  const int lane = t & 63;
  const int w = t >> 6;
  const int wr = (w >> 1) << 6, wc = (w & 1) << 6;
  int bx = blockIdx.x, by = blockIdx.y;
  xcd_swz(bx, by);
  const int m0 = by << 7, n0 = bx << 7;
  const int lm = lane & 15;
  const int grow = lane >> 3;
  const int gcol = (lane & 7) << 3;
  f32x4 acc[4][4];
#pragma unroll
  for (int i = 0; i < 4; ++i)
#pragma unroll
    for (int j = 0; j < 4; ++j) acc[i][j] = (f32x4)(0.f);
  const int NT = K >> 6;
#pragma unroll
  for (int i = 0; i < 4; ++i) {
    const int s = (w << 2) + i;
    gload16(A + (size_t)(m0 + (s << 3) + grow) * K + gcol, &Al[0][s << 9]);
    gload16(Wt + (size_t)(n0 + (s << 3) + grow) * K + gcol, &Bl[0][s << 9]);
  }
  __syncthreads();
  int cur = 0;
  for (int tt = 0; tt < NT; ++tt) {
    if (tt + 1 < NT) {
      const int k0 = (tt + 1) << 6;
#pragma unroll
      for (int i = 0; i < 4; ++i) {
        const int s = (w << 2) + i;
        gload16(A + (size_t)(m0 + (s << 3) + grow) * K + k0 + gcol, &Al[cur ^ 1][s << 9]);
        gload16(Wt + (size_t)(n0 + (s << 3) + grow) * K + k0 + gcol, &Bl[cur ^ 1][s << 9]);
      }
    }
#pragma unroll
    for (int ks = 0; ks < 2; ++ks) {
      const int kof = (ks << 5) + ((lane >> 4) << 3);
      bf16x8 af[4], bfr[4];
#pragma unroll
      for (int i = 0; i < 4; ++i) af[i] = *(const bf16x8*)&Al[cur][(wr + (i << 4) + lm) * 64 + kof];
#pragma unroll
      for (int j = 0; j < 4; ++j) bfr[j] = *(const bf16x8*)&Bl[cur][(wc + (j << 4) + lm) * 64 + kof];
#pragma unroll
      for (int i = 0; i < 4; ++i)
#pragma unroll
        for (int j = 0; j < 4; ++j)
          acc[i][j] = __builtin_amdgcn_mfma_f32_16x16x32_bf16(af[i], bfr[j], acc[i][j], 0, 0, 0);
    }
    __syncthreads();
    cur ^= 1;
  }
  const int seg = n0 >> 9;                 // block-uniform: 0=q, 1=k, 2=v
  const int nloc = n0 & 511;
  const float* bsel = (seg == 0) ? bq : (seg == 1 ? bk : bv);
  float bb[4], uu[4], vv[4];
#pragma unroll
  for (int j = 0; j < 4; ++j) {
    const int col = nloc + wc + j * 16 + lm;
    bb[j] = bsel[col];
    if (seg == 0) { uu[j] = ub[col]; vv[j] = vb[col]; }
  }
  const int rbase = m0 + wr + ((lane >> 4) << 2);
  if (seg == 2) {
    const int bloc = m0 >> 9;
    const int sbase = rbase - (bloc << 9);
#pragma unroll
    for (int i = 0; i < 4; ++i) {
#pragma unroll
      for (int j = 0; j < 4; ++j) {
        const int col = nloc + wc + j * 16 + lm;
        ushort4 o;
        o.x = f2bf(acc[i][j][0] + bb[j]);
        o.y = f2bf(acc[i][j][1] + bb[j]);
        o.z = f2bf(acc[i][j][2] + bb[j]);
        o.w = f2bf(acc[i][j][3] + bb[j]);
        *(ushort4*)&vT[((size_t)((bloc << 9) + col)) * 512 + sbase + i * 16] = o;
      }
    }
    return;
  }
#pragma unroll
  for (int i = 0; i < 4; ++i) {
#pragma unroll
    for (int r = 0; r < 4; ++r) {
      const size_t row = (size_t)(rbase + i * 16 + r);
#pragma unroll
      for (int j = 0; j < 4; ++j) {
        const int col = nloc + wc + j * 16 + lm;
        const float v = acc[i][j][r] + bb[j];
        if (seg == 0) {
          qu[row * 512 + col] = f2bf(v + uu[j]);
          qv[row * 512 + col] = f2bf(v + vv[j]);
        } else {
          kbb[row * 512 + col] = f2bf(v);
        }
      }
    }
  }
}

// ---------------- pw1 + GLU fused ----------------------------------------------
__global__ __launch_bounds__(256) void gemm_glu(const ushort* __restrict__ A,
                                                const ushort* __restrict__ Wt,
                                                const float* __restrict__ bias,
                                                ushort* __restrict__ Cout,
                                                int M, int K) {
  __shared__ ushort Al[8192];
  __shared__ ushort Ba[8192];
  __shared__ ushort Bg[8192];
  const int t = threadIdx.x;
  const int lane = t & 63;
  const int w = t >> 6;
  const int wr = (w >> 1) << 6, wc = (w & 1) << 6;
  int bx = blockIdx.x, by = blockIdx.y;
  xcd_swz(bx, by);
  const int m0 = by << 7, n0 = bx << 7;
  const int lm = lane & 15;
  const int grow = lane >> 3;
  const int gcol = (lane & 7) << 3;
  const ushort* WtA = Wt;
  const ushort* WtG = Wt + (size_t)512 * 512;
  f32x4 acca[4][4], accg[4][4];
#pragma unroll
  for (int i = 0; i < 4; ++i)
#pragma unroll
    for (int j = 0; j < 4; ++j) { acca[i][j] = (f32x4)(0.f); accg[i][j] = (f32x4)(0.f); }
  const int NT = K >> 6;
  for (int tt = 0; tt < NT; ++tt) {
    const int k0 = tt << 6;
    if (tt) __syncthreads();
#pragma unroll
    for (int i = 0; i < 4; ++i) {
      const int s = (w << 2) + i;
      gload16(A + (size_t)(m0 + (s << 3) + grow) * K + k0 + gcol, &Al[s << 9]);
      gload16(WtA + (size_t)(n0 + (s << 3) + grow) * K + k0 + gcol, &Ba[s << 9]);
      gload16(WtG + (size_t)(n0 + (s << 3) + grow) * K + k0 + gcol, &Bg[s << 9]);
    }
    __syncthreads();
#pragma unroll
    for (int ks = 0; ks < 2; ++ks) {
      const int kof = (ks << 5) + ((lane >> 4) << 3);
      bf16x8 af[4], ba4[4], bg4[4];
#pragma unroll
      for (int i = 0; i < 4; ++i) af[i] = *(const bf16x8*)&Al[(wr + (i << 4) + lm) * 64 + kof];
#pragma unroll
      for (int j = 0; j < 4; ++j) {
        ba4[j] = *(const bf16x8*)&Ba[(wc + (j << 4) + lm) * 64 + kof];
        bg4[j] = *(const bf16x8*)&Bg[(wc + (j << 4) + lm) * 64 + kof];
      }
#pragma unroll
      for (int i = 0; i < 4; ++i)
#pragma unroll
        for (int j = 0; j < 4; ++j) {
          acca[i][j] = __builtin_amdgcn_mfma_f32_16x16x32_bf16(af[i], ba4[j], acca[i][j], 0, 0, 0);
          accg[i][j] = __builtin_amdgcn_mfma_f32_16x16x32_bf16(af[i], bg4[j], accg[i][j], 0, 0, 0);
        }
    }
  }
  float bba[4], bbg[4];
#pragma unroll
  for (int j = 0; j < 4; ++j) {
    const int col = n0 + wc + j * 16 + lm;
    bba[j] = bias[col];
    bbg[j] = bias[512 + col];
  }
  const int rbase = m0 + wr + ((lane >> 4) << 2);
#pragma unroll
  for (int i = 0; i < 4; ++i) {
#pragma unroll
    for (int r = 0; r < 4; ++r) {
      const size_t row = (size_t)(rbase + i * 16 + r);
#pragma unroll
      for (int j = 0; j < 4; ++j) {
        const int col = n0 + wc + j * 16 + lm;
        const float va = acca[i][j][r] + bba[j];
        const float vg = accg[i][j][r] + bbg[j];
        Cout[row * 512 + col] = f2bf(va * sigmf(vg));
      }
    }
  }
}

// ------------- Sinusoidal PE (bf16) ---------------------------------------------
__global__ void pe_kernel_bf16(ushort* __restrict__ pe) {
  const int pos = blockIdx.x, ii = threadIdx.x;
  const float ang = (float)pos * powf(10000.f, -(float)(2 * ii) / 512.f);
  pe[((size_t)pos << 9) + 2 * ii] = f2bf(sinf(ang));
  pe[((size_t)pos << 9) + 2 * ii + 1] = f2bf(cosf(ang));
}

// ------------- fused attention v4: direct-global B-frags, 3 barriers ------------
// block = (q-block 64) x (z = b*8+h). LDS: psL[65][520] = 67.6KB only.
__global__ __launch_bounds__(256) void attn_fused4(const ushort* __restrict__ qu,
                                                   const ushort* __restrict__ qv,
                                                   const ushort* __restrict__ kbb,
                                                   const ushort* __restrict__ ppb,
                                                   const ushort* __restrict__ vT,
                                                   float* __restrict__ attn,
                                                   ushort* __restrict__ ctx) {
  __shared__ ushort psL[65][520];
  const int t = threadIdx.x, lane = t & 63, w = t >> 6;
  const int z = blockIdx.y, b = z >> 3, h = z & 7;
  const int q0 = blockIdx.x << 6;
  const int lm = lane & 15, g = lane >> 4;
  const int lk = g << 3, fr4 = g << 2;

  // A-fragments from global (own q rows)
  const size_t qoff = ((size_t)((b << 9) + q0 + (w << 4) + lm)) * 512 + (h << 6);
  const bf16x8 av0 = *(const bf16x8*)&qv[qoff + lk];
  const bf16x8 av1 = *(const bf16x8*)&qv[qoff + lk + 32];
  const bf16x8 au0 = *(const bf16x8*)&qu[qoff + lk];
  const bf16x8 au1 = *(const bf16x8*)&qu[qoff + lk + 32];
  int er = q0 + 64 + lm;
  if (er > 511) er = 511;
  const size_t eoff = ((size_t)((b << 9) + er)) * 512 + (h << 6);
  const bf16x8 e0 = *(const bf16x8*)&qv[eoff + lk];
  const bf16x8 e1 = *(const bf16x8*)&qv[eoff + lk + 32];

  // ---- PS pass: psL[qq][j] = qv . pp^T, B-frags direct from global --------------
  const ushort* pb_ = ppb + (h << 6);
#pragma unroll
  for (int jt = 0; jt < 32; ++jt) {
    const ushort* pr = pb_ + (size_t)((jt << 4) + lm) * 512;
    const bf16x8 b0 = *(const bf16x8*)&pr[lk];
    const bf16x8 b1 = *(const bf16x8*)&pr[lk + 32];
    f32x4 a = (f32x4)(0.f);
    a = __builtin_amdgcn_mfma_f32_16x16x32_bf16(av0, b0, a, 0, 0, 0);
    a = __builtin_amdgcn_mfma_f32_16x16x32_bf16(av1, b1, a, 0, 0, 0);
#pragma unroll
    for (int r = 0; r < 4; ++r) psL[(w << 4) + fr4 + r][(jt << 4) + lm] = f2bf(a[r]);
    if ((jt & 3) == w) {  // boundary row q0+64: each wave covers 1/4 of j-tiles
      f32x4 e = (f32x4)(0.f);
      e = __builtin_amdgcn_mfma_f32_16x16x32_bf16(e0, b0, e, 0, 0, 0);
      e = __builtin_amdgcn_mfma_f32_16x16x32_bf16(e1, b1, e, 0, 0, 0);
      if (g == 0) psL[64][(jt << 4) + lm] = f2bf(e[0]);
    }
  }

  // ---- QK pass: no LDS, pure global-load + MFMA stream ---------------------------
  f32x4 acc[32];
#pragma unroll
  for (int i = 0; i < 32; ++i) acc[i] = (f32x4)(0.f);
  const ushort* kb_ = kbb + ((size_t)(b << 9)) * 512 + (h << 6);
#pragma unroll
  for (int ct = 0; ct < 32; ++ct) {
    const ushort* kr = kb_ + (size_t)((ct << 4) + lm) * 512;
    const bf16x8 b0 = *(const bf16x8*)&kr[lk];
    const bf16x8 b1 = *(const bf16x8*)&kr[lk + 32];
    acc[ct] = __builtin_amdgcn_mfma_f32_16x16x32_bf16(au0, b0, acc[ct], 0, 0, 0);
    acc[ct] = __builtin_amdgcn_mfma_f32_16x16x32_bf16(au1, b1, acc[ct], 0, 0, 0);
  }
  __syncthreads();  // psL complete (cross-wave rows needed by gather)

  // ---- rel-shift gather from psL + scale -----------------------------------------
  const float scale = 0.044194173824159216f;  // 1/sqrt(512)
  const int qb_ = q0 + (w << 4) + fr4;
#pragma unroll
  for (int ct = 0; ct < 32; ++ct) {
#pragma unroll
    for (int r = 0; r < 4; ++r) {
      const int q = qb_ + r;
      const int qq = q - q0;
      const int c = (ct << 4) + lm;
      float f;
      if (c <= q)          f = bf2f(psL[qq][c - q + 511]);
      else if (c == q + 1) f = 0.f;
      else                 f = bf2f(psL[qq + 1][c - q - 2]);
      acc[ct][r] = (acc[ct][r] + f) * scale;
    }
  }
  // ---- softmax --------------------------------------------------------------------
  float mx[4] = {-3.0e38f, -3.0e38f, -3.0e38f, -3.0e38f};
#pragma unroll
  for (int ct = 0; ct < 32; ++ct)
#pragma unroll
    for (int r = 0; r < 4; ++r) mx[r] = fmaxf(mx[r], acc[ct][r]);
#pragma unroll
  for (int o = 1; o < 16; o <<= 1)
#pragma unroll
    for (int r = 0; r < 4; ++r) mx[r] = fmaxf(mx[r], __shfl_xor(mx[r], o));
  float sme[4] = {0.f, 0.f, 0.f, 0.f};
#pragma unroll
  for (int ct = 0; ct < 32; ++ct)
#pragma unroll
    for (int r = 0; r < 4; ++r) {
      acc[ct][r] = __expf(acc[ct][r] - mx[r]);
      sme[r] += acc[ct][r];
    }
#pragma unroll
  for (int o = 1; o < 16; o <<= 1)
#pragma unroll
    for (int r = 0; r < 4; ++r) sme[r] += __shfl_xor(sme[r], o);
#pragma unroll
  for (int r = 0; r < 4; ++r) {
    const float inv = 1.f / sme[r];
#pragma unroll
    for (int ct = 0; ct < 32; ++ct) acc[ct][r] *= inv;
  }
  // ---- attn write (f32 output) ------------------------------------------------------
  float* arow = attn + ((size_t)((b << 3) + h) << 18);
#pragma unroll
  for (int ct = 0; ct < 32; ++ct)
#pragma unroll
    for (int r = 0; r < 4; ++r)
      arow[(size_t)(qb_ + r) * 512 + (ct << 4) + lm] = acc[ct][r];
  __syncthreads();  // all waves done reading psL -> safe to reuse as P buffer

  // ---- PV: ctx^T = V^T . P^T; P bounce reuses psL region, barrier-free inner ------
  ushort* Pl = &psL[0][0];  // reused as [64][72]; each wave touches only its 16 rows
  f32x4 acc2[4];
#pragma unroll
  for (int i = 0; i < 4; ++i) acc2[i] = (f32x4)(0.f);
  const ushort* vtb = vT + ((size_t)((b << 9) + (h << 6))) * 512;
#pragma unroll
  for (int ch = 0; ch < 8; ++ch) {
#pragma unroll
    for (int ctl = 0; ctl < 4; ++ctl) {
      const int ct = (ch << 2) + ctl;
#pragma unroll
      for (int r = 0; r < 4; ++r)
        Pl[((w << 4) + fr4 + r) * 72 + (ctl << 4) + lm] = f2bf(acc[ct][r]);
    }
#pragma unroll
    for (int ks = 0; ks < 2; ++ks) {
      const int kof = (ks << 5) + lk;
      const bf16x8 pbf = *(const bf16x8*)&Pl[((w << 4) + lm) * 72 + kof];
#pragma unroll
      for (int dt = 0; dt < 4; ++dt) {
        const bf16x8 va =
            *(const bf16x8*)&vtb[(size_t)((dt << 4) + lm) * 512 + (ch << 6) + kof];
        acc2[dt] = __builtin_amdgcn_mfma_f32_16x16x32_bf16(va, pbf, acc2[dt], 0, 0, 0);
      }
    }
  }
  const int qq2 = q0 + (w << 4) + lm;
#pragma unroll
  for (int dt = 0; dt < 4; ++dt) {
    ushort4 o;
    o.x = f2bf(acc2[dt][0]); o.y = f2bf(acc2[dt][1]);
    o.z = f2bf(acc2[dt][2]); o.w = f2bf(acc2[dt][3]);
    *(ushort4*)&ctx[((size_t)((b << 9) + qq2)) * 512 + (h << 6) + (dt << 4) + fr4] = o;
  }
}

// ------------- depthwise conv (K=31) + BN + swish, register sliding window ------
__global__ __launch_bounds__(256) void dwconv2(const ushort* __restrict__ in,
                                               const float* __restrict__ w,
                                               const float* __restrict__ bng,
                                               const float* __restrict__ bnb,
                                               const float* __restrict__ bnm,
                                               const float* __restrict__ bnv,
                                               ushort* __restrict__ out) {
  __shared__ float wl[31][128];
  const int t = threadIdx.x;
  const int dbase = blockIdx.x << 7;
  const int b = blockIdx.z;
  const int sb = (blockIdx.y << 6) + ((t >> 6) << 4);
  if (t < 128) {
    const float* ws = &w[(dbase + t) * 31];
#pragma unroll
    for (int k = 0; k < 31; ++k) wl[k][t] = ws[k];
  }
  __syncthreads();
  const int dl = (t & 63) << 1;
  const int d = dbase + dl;
  const size_t base = (((size_t)b) << 18) + d;
  float2 win[46];
#pragma unroll
  for (int i = 0; i < 46; ++i) {
    const int s = sb - 15 + i;
    if (s >= 0 && s < 512) {
      const ushort2 u = *(const ushort2*)&in[base + ((size_t)s << 9)];
      win[i].x = bf2f(u.x); win[i].y = bf2f(u.y);
    } else {
      win[i].x = 0.f; win[i].y = 0.f;
    }
  }
  float2 acc[16];
#pragma unroll
  for (int p = 0; p < 16; ++p) { acc[p].x = 0.f; acc[p].y = 0.f; }
#pragma unroll
  for (int k = 0; k < 31; ++k) {
    const float2 w2 = *(const float2*)&wl[k][dl];
#pragma unroll
    for (int p = 0; p < 16; ++p) {
      acc[p].x = fmaf(win[p + k].x, w2.x, acc[p].x);
      acc[p].y = fmaf(win[p + k].y, w2.y, acc[p].y);
    }
  }
  const float g0 = bng[d] * rsqrtf(bnv[d] + EPSF);
  const float g1 = bng[d + 1] * rsqrtf(bnv[d + 1] + EPSF);
  const float m0 = bnm[d], m1 = bnm[d + 1];
  const float bb0 = bnb[d], bb1 = bnb[d + 1];
#pragma unroll
  for (int p = 0; p < 16; ++p) {
    float v0 = (acc[p].x - m0) * g0 + bb0;
    float v1 = (acc[p].y - m1) * g1 + bb1;
    v0 = v0 * sigmf(v0);
    v1 = v1 * sigmf(v1);
    ushort2 o;
    o.x = f2bf(v0); o.y = f2bf(v1);
    *(ushort2*)&out[base + ((size_t)(sb + p) << 9)] = o;
  }
}

extern "C" void kernel_launch(void* const* d_in, const int* in_sizes, int n_in,
                              void* d_out, int out_size, void* d_ws, size_t ws_size,
                              hipStream_t stream) {
  const float* x      = (const float*)d_in[0];
  const float* ff1_g  = (const float*)d_in[1];
  const float* ff1_b  = (const float*)d_in[2];
  const float* ff1_w1 = (const float*)d_in[3];
  const float* ff1_b1 = (const float*)d_in[4];
  const float* ff1_w2 = (const float*)d_in[5];
  const float* ff1_b2 = (const float*)d_in[6];
  const float* attn_g = (const float*)d_in[7];
  const float* attn_b = (const float*)d_in[8];
  const float* wq     = (const float*)d_in[9];
  const float* bq     = (const float*)d_in[10];
  const float* wk     = (const float*)d_in[11];
  const float* bk     = (const float*)d_in[12];
  const float* wv     = (const float*)d_in[13];
  const float* bv     = (const float*)d_in[14];
  const float* wpos   = (const float*)d_in[15];
  const float* u_bias = (const float*)d_in[16];
  const float* v_bias = (const float*)d_in[17];
  const float* wo     = (const float*)d_in[18];
  const float* bo     = (const float*)d_in[19];
  const float* conv_g = (const float*)d_in[20];
  const float* conv_b = (const float*)d_in[21];
  const float* pw1_w  = (const float*)d_in[22];
  const float* pw1_b  = (const float*)d_in[23];
  const float* dw_w   = (const float*)d_in[24];
  const float* bn_g   = (const float*)d_in[25];
  const float* bn_b   = (const float*)d_in[26];
  const float* bn_m   = (const float*)d_in[27];
  const float* bn_v   = (const float*)d_in[28];
  const float* pw2_w  = (const float*)d_in[29];
  const float* pw2_b  = (const float*)d_in[30];
  const float* ff2_g  = (const float*)d_in[31];
  const float* ff2_b  = (const float*)d_in[32];
  const float* ff2_w1 = (const float*)d_in[33];
  const float* ff2_b1 = (const float*)d_in[34];
  const float* ff2_w2 = (const float*)d_in[35];
  const float* ff2_b2 = (const float*)d_in[36];
  const float* ln_g   = (const float*)d_in[37];
  const float* ln_b   = (const float*)d_in[38];

  float* out  = (float*)d_out;            // [B,S,D] f32
  float* attn = out + ND;                 // [B,H,S,S] f32

  // workspace: res ND f32 | ybf ND ush | big 4ND ush | vT+dwbf 2ND ush | wts | pe | pp
  float*  res  = (float*)d_ws;
  ushort* ybf  = (ushort*)(res + ND);
  float*  big  = (float*)(ybf + ND);             // 2*ND f32 region
  ushort* vT   = (ushort*)(big + 2 * ND);        // ND ushorts [b][col][s]
  ushort* dwbf = vT + ND;                        // ND ushorts
  ushort* wts  = dwbf + ND;                      // 6,291,456 ushorts
  ushort* pebf = wts + 6291456;                  // 262,144
  ushort* ppbf = pebf + 262144;                  // 262,144

  ushort* ffmid = (ushort*)big;
  ushort* qu    = (ushort*)big;
  ushort* qv    = qu + ND;
  ushort* kbb   = qv + ND;
  ushort* ctxbf = ybf;
  ushort* glubf = (ushort*)big;

  ushort* ff1w1t = wts;
  ushort* ff1w2t = wts + 1048576;
  ushort* wqt    = wts + 2097152;
  ushort* wkt    = wts + 2359296;
  ushort* wvt    = wts + 2621440;
  ushort* wot    = wts + 2883584;
  ushort* pw1t   = wts + 3145728;
  ushort* pw2t   = wts + 3670016;
  ushort* ff2w1t = wts + 3932160;
  ushort* ff2w2t = wts + 4980736;
  ushort* wpost  = wts + 6029312;

  const dim3 blk(256);

  // ---- weight prep: single merged transpose dispatch ----
  TpArgs ta;
  auto set = [&](int i, const float* s, ushort* d, int K, int N) {
    ta.src[i] = s; ta.dst[i] = d; ta.K[i] = K; ta.N[i] = N;
  };
  set(0, ff1_w1, ff1w1t, 512, 2048);
  set(1, ff1_w2, ff1w2t, 2048, 512);
  set(2, wq, wqt, 512, 512);
  set(3, wk, wkt, 512, 512);
  set(4, wv, wvt, 512, 512);
  set(5, wo, wot, 512, 512);
  set(6, wpos, wpost, 512, 512);
  set(7, pw1_w, pw1t, 512, 1024);
  set(8, pw2_w, pw2t, 512, 512);
  set(9, ff2_w1, ff2w1t, 512, 2048);
  set(10, ff2_w2, ff2w2t, 2048, 512);
  int tacc = 0;
  for (int i = 0; i < 11; ++i) { ta.base[i] = tacc; tacc += (ta.N[i] >> 5) * (ta.K[i] >> 5); }
  ta.base[11] = tacc;
  transpose_all<<<tacc, blk, 0, stream>>>(ta);
  pe_kernel_bf16<<<512, blk, 0, stream>>>(pebf);
  gemm_bf16<0, 0, 0, 1><<<dim3(4, 4), blk, 0, stream>>>(pebf, wpost, nullptr, nullptr, ppbf,
                                                        512, 512, 512);

  // ---- Macaron FF1: res = x + 0.5*FF(LN(x)) ----
  ln_bf16<<<NTOK / 4, blk, 0, stream>>>(x, ff1_g, ff1_b, ybf);
  gemm_bf16<1, 0, 1, 1><<<dim3(16, 128), blk, 0, stream>>>(ybf, ff1w1t, ff1_b1, nullptr, ffmid,
                                                           NTOK, 512, 2048);
  gemm_bf16<0, 2, 1, 0><<<dim3(4, 128), blk, 0, stream>>>(ffmid, ff1w2t, ff1_b2, x, res,
                                                          NTOK, 2048, 512);

  // ---- Attention ----
  ln_bf16<<<NTOK / 4, blk, 0, stream>>>(res, attn_g, attn_b, ybf);
  gemm_qkv<<<dim3(12, 128), blk, 0, stream>>>(ybf, wqt, bq, bk, bv, u_bias, v_bias,
                                              qu, qv, kbb, vT, NTOK, 512);
  attn_fused4<<<dim3(8, 256), blk, 0, stream>>>(qu, qv, kbb, ppbf, vT, attn, ctxbf);
  gemm_bf16<0, 1, 1, 0><<<dim3(4, 128), blk, 0, stream>>>(ctxbf, wot, bo, res, res,
                                                          NTOK, 512, 512);

  // ---- Conv module ----
  ln_bf16<<<NTOK / 4, blk, 0, stream>>>(res, conv_g, conv_b, ybf);
  gemm_glu<<<dim3(4, 128), blk, 0, stream>>>(ybf, pw1t, pw1_b, glubf, NTOK, 512);
  dwconv2<<<dim3(4, 8, 32), blk, 0, stream>>>(glubf, dw_w, bn_g, bn_b, bn_m, bn_v, dwbf);
  gemm_bf16<0, 1, 1, 0><<<dim3(4, 128), blk, 0, stream>>>(dwbf, pw2t, pw2_b, res, res,
                                                          NTOK, 512, 512);

  // ---- Macaron FF2 + final LN ----
  ln_bf16<<<NTOK / 4, blk, 0, stream>>>(res, ff2_g, ff2_b, ybf);
  gemm_bf16<1, 0, 1, 1><<<dim3(16, 128), blk, 0, stream>>>(ybf, ff2w1t, ff2_b1, nullptr, ffmid,
                                                           NTOK, 512, 2048);
  gemm_bf16<0, 2, 1, 0><<<dim3(4, 128), blk, 0, stream>>>(ffmid, ff2w2t, ff2_b2, res, res,
                                                          NTOK, 2048, 512);
  ln_f32<<<NTOK / 4, blk, 0, stream>>>(res, ln_g, ln_b, out);
}

// Round 8
// 805.090 us; speedup vs baseline: 1.1937x; 1.1937x over previous
//
#include <hip/hip_runtime.h>
#include <cstddef>
#include <cstdint>

#define EPSF 1e-5f

constexpr int BB = 32, SS = 512, DD = 512, HH = 8, DH = 64;
constexpr int NTOK = BB * SS;              // 16384 rows
constexpr size_t ND = (size_t)NTOK * DD;   // 8,388,608

typedef __attribute__((ext_vector_type(8))) short bf16x8;
typedef __attribute__((ext_vector_type(4))) float f32x4;

__device__ __forceinline__ float sigmf(float v) { return 1.f / (1.f + __expf(-v)); }

__device__ __forceinline__ ushort f2bf(float f) {
  union { float f; uint32_t u; } x{f};
  uint32_t r = x.u + 0x7FFF + ((x.u >> 16) & 1);
  return (ushort)(r >> 16);
}
__device__ __forceinline__ float bf2f(ushort u) {
  union { uint32_t u; float f; } x{(uint32_t)u << 16};
  return x.f;
}

__device__ __forceinline__ void gload16(const ushort* g, ushort* ldsbase) {
  __builtin_amdgcn_global_load_lds((const __attribute__((address_space(1))) void*)g,
                                   (__attribute__((address_space(3))) void*)ldsbase, 16, 0, 0);
}

// bijective XCD-chunk swizzle (m204); requires nwg % 8 == 0.
__device__ __forceinline__ void xcd_swz(int& bx, int& by) {
  const int gx = gridDim.x;
  const int nwg = gx * gridDim.y;
  const int cpx = nwg >> 3;
  int id = by * gx + bx;
  id = (id & 7) * cpx + (id >> 3);
  bx = id % gx;
  by = id / gx;
}

// ---------------- LayerNorm: one wave per row, f32 out --------------------------
__global__ __launch_bounds__(256) void ln_f32(const float* __restrict__ x,
                                              const float* __restrict__ g,
                                              const float* __restrict__ b,
                                              float* __restrict__ y) {
  const int lane = threadIdx.x & 63;
  const int row = blockIdx.x * 4 + (threadIdx.x >> 6);
  const float* xr = x + (size_t)row * 512;
  const float4 v0 = *(const float4*)&xr[lane << 2];
  const float4 v1 = *(const float4*)&xr[256 + (lane << 2)];
  float s = v0.x + v0.y + v0.z + v0.w + v1.x + v1.y + v1.z + v1.w;
#pragma unroll
  for (int o = 32; o > 0; o >>= 1) s += __shfl_xor(s, o);
  const float mean = s * (1.f / 512.f);
  float q = 0.f;
  q += (v0.x - mean) * (v0.x - mean); q += (v0.y - mean) * (v0.y - mean);
  q += (v0.z - mean) * (v0.z - mean); q += (v0.w - mean) * (v0.w - mean);
  q += (v1.x - mean) * (v1.x - mean); q += (v1.y - mean) * (v1.y - mean);
  q += (v1.z - mean) * (v1.z - mean); q += (v1.w - mean) * (v1.w - mean);
#pragma unroll
  for (int o = 32; o > 0; o >>= 1) q += __shfl_xor(q, o);
  const float rs = rsqrtf(q * (1.f / 512.f) + EPSF);
  const float4 g0 = *(const float4*)&g[lane << 2];
  const float4 g1 = *(const float4*)&g[256 + (lane << 2)];
  const float4 b0 = *(const float4*)&b[lane << 2];
  const float4 b1 = *(const float4*)&b[256 + (lane << 2)];
  float* yr = y + (size_t)row * 512;
  float4 o0, o1;
  o0.x = (v0.x - mean) * rs * g0.x + b0.x; o0.y = (v0.y - mean) * rs * g0.y + b0.y;
  o0.z = (v0.z - mean) * rs * g0.z + b0.z; o0.w = (v0.w - mean) * rs * g0.w + b0.w;
  o1.x = (v1.x - mean) * rs * g1.x + b1.x; o1.y = (v1.y - mean) * rs * g1.y + b1.y;
  o1.z = (v1.z - mean) * rs * g1.z + b1.z; o1.w = (v1.w - mean) * rs * g1.w + b1.w;
  *(float4*)&yr[lane << 2] = o0;
  *(float4*)&yr[256 + (lane << 2)] = o1;
}

// ---------------- LayerNorm writing bf16 ----------------------------------------
__global__ __launch_bounds__(256) void ln_bf16(const float* __restrict__ x,
                                               const float* __restrict__ g,
                                               const float* __restrict__ b,
                                               ushort* __restrict__ y) {
  const int lane = threadIdx.x & 63;
  const int row = blockIdx.x * 4 + (threadIdx.x >> 6);
  const float* xr = x + (size_t)row * 512;
  const float4 v0 = *(const float4*)&xr[lane << 2];
  const float4 v1 = *(const float4*)&xr[256 + (lane << 2)];
  float s = v0.x + v0.y + v0.z + v0.w + v1.x + v1.y + v1.z + v1.w;
#pragma unroll
  for (int o = 32; o > 0; o >>= 1) s += __shfl_xor(s, o);
  const float mean = s * (1.f / 512.f);
  float q = 0.f;
  q += (v0.x - mean) * (v0.x - mean); q += (v0.y - mean) * (v0.y - mean);
  q += (v0.z - mean) * (v0.z - mean); q += (v0.w - mean) * (v0.w - mean);
  q += (v1.x - mean) * (v1.x - mean); q += (v1.y - mean) * (v1.y - mean);
  q += (v1.z - mean) * (v1.z - mean); q += (v1.w - mean) * (v1.w - mean);
#pragma unroll
  for (int o = 32; o > 0; o >>= 1) q += __shfl_xor(q, o);
  const float rs = rsqrtf(q * (1.f / 512.f) + EPSF);
  const float4 g0 = *(const float4*)&g[lane << 2];
  const float4 g1 = *(const float4*)&g[256 + (lane << 2)];
  const float4 b0 = *(const float4*)&b[lane << 2];
  const float4 b1 = *(const float4*)&b[256 + (lane << 2)];
  ushort* yr = y + (size_t)row * 512;
  ushort4 o0, o1;
  o0.x = f2bf((v0.x - mean) * rs * g0.x + b0.x); o0.y = f2bf((v0.y - mean) * rs * g0.y + b0.y);
  o0.z = f2bf((v0.z - mean) * rs * g0.z + b0.z); o0.w = f2bf((v0.w - mean) * rs * g0.w + b0.w);
  o1.x = f2bf((v1.x - mean) * rs * g1.x + b1.x); o1.y = f2bf((v1.y - mean) * rs * g1.y + b1.y);
  o1.z = f2bf((v1.z - mean) * rs * g1.z + b1.z); o1.w = f2bf((v1.w - mean) * rs * g1.w + b1.w);
  *(ushort4*)&yr[lane << 2] = o0;
  *(ushort4*)&yr[256 + (lane << 2)] = o1;
}

// ---------------- merged weight transpose: 11 segments, one dispatch ------------
struct TpArgs {
  const float* src[11];
  ushort* dst[11];
  int K[11];
  int N[11];
  int base[12];
};

__global__ __launch_bounds__(256) void transpose_all(TpArgs a) {
  __shared__ float tile[32][33];
  int s = 0;
  const int bid = blockIdx.x;
  while (s < 10 && bid >= a.base[s + 1]) ++s;
  const int r = bid - a.base[s];
  const int K = a.K[s], N = a.N[s];
  const int ntx = N >> 5;
  const int n0 = (r % ntx) << 5;
  const int k0 = (r / ntx) << 5;
  const float* in = a.src[s];
  ushort* out = a.dst[s];
  const int tx = threadIdx.x & 31, ty = threadIdx.x >> 5;
#pragma unroll
  for (int i = 0; i < 32; i += 8)
    tile[ty + i][tx] = in[(size_t)(k0 + ty + i) * N + n0 + tx];
  __syncthreads();
#pragma unroll
  for (int i = 0; i < 32; i += 8)
    out[(size_t)(n0 + ty + i) * K + k0 + tx] = f2bf(tile[tx][ty + i]);
}

// ---------------- bf16 MFMA GEMM, T3-minimum 2-phase double-buffer --------------
template <int ACT, int RES, int HB, int OBF>
__global__ __launch_bounds__(256) void gemm_bf16(const ushort* __restrict__ A,
                                                 const ushort* __restrict__ Wt,
                                                 const float* __restrict__ bias,
                                                 const float* __restrict__ res,
                                                 void* __restrict__ Cv,
                                                 int M, int K, int N) {
  __shared__ ushort Al[2][8192];
  __shared__ ushort Bl[2][8192];
  const int t = threadIdx.x;
  const int lane = t & 63;
  const int w = t >> 6;
  const int wr = (w >> 1) << 6, wc = (w & 1) << 6;
  int bx = blockIdx.x, by = blockIdx.y;
  xcd_swz(bx, by);
  const int m0 = by << 7, n0 = bx << 7;
  const int lm = lane & 15;
  const int grow = lane >> 3;
  const int gcol = (lane & 7) << 3;

  f32x4 acc[4][4];
#pragma unroll
  for (int i = 0; i < 4; ++i)
#pragma unroll
    for (int j = 0; j < 4; ++j) acc[i][j] = (f32x4)(0.f);

  const int NT = K >> 6;
#pragma unroll
  for (int i = 0; i < 4; ++i) {
    const int s = (w << 2) + i;
    gload16(A + (size_t)(m0 + (s << 3) + grow) * K + gcol, &Al[0][s << 9]);
    gload16(Wt + (size_t)(n0 + (s << 3) + grow) * K + gcol, &Bl[0][s << 9]);
  }
  __syncthreads();
  int cur = 0;
  for (int tt = 0; tt < NT; ++tt) {
    if (tt + 1 < NT) {
      const int k0 = (tt + 1) << 6;
#pragma unroll
      for (int i = 0; i < 4; ++i) {
        const int s = (w << 2) + i;
        gload16(A + (size_t)(m0 + (s << 3) + grow) * K + k0 + gcol, &Al[cur ^ 1][s << 9]);
        gload16(Wt + (size_t)(n0 + (s << 3) + grow) * K + k0 + gcol, &Bl[cur ^ 1][s << 9]);
      }
    }
#pragma unroll
    for (int ks = 0; ks < 2; ++ks) {
      const int kof = (ks << 5) + ((lane >> 4) << 3);
      bf16x8 af[4], bfr[4];
#pragma unroll
      for (int i = 0; i < 4; ++i) af[i] = *(const bf16x8*)&Al[cur][(wr + (i << 4) + lm) * 64 + kof];
#pragma unroll
      for (int j = 0; j < 4; ++j) bfr[j] = *(const bf16x8*)&Bl[cur][(wc + (j << 4) + lm) * 64 + kof];
#pragma unroll
      for (int i = 0; i < 4; ++i)
#pragma unroll
        for (int j = 0; j < 4; ++j)
          acc[i][j] = __builtin_amdgcn_mfma_f32_16x16x32_bf16(af[i], bfr[j], acc[i][j], 0, 0, 0);
    }
    __syncthreads();
    cur ^= 1;
  }

  float bb[4] = {0.f, 0.f, 0.f, 0.f};
  if (HB) {
#pragma unroll
    for (int j = 0; j < 4; ++j) bb[j] = bias[n0 + wc + j * 16 + lm];
  }
  const int rbase = m0 + wr + ((lane >> 4) << 2);
#pragma unroll
  for (int i = 0; i < 4; ++i) {
#pragma unroll
    for (int r = 0; r < 4; ++r) {
      const size_t row = (size_t)(rbase + i * 16 + r);
#pragma unroll
      for (int j = 0; j < 4; ++j) {
        const int col = n0 + wc + j * 16 + lm;
        float v = acc[i][j][r] + bb[j];
        if (ACT == 1) v = v * sigmf(v);
        if (RES == 1) v += res[row * N + col];
        else if (RES == 2) v = res[row * N + col] + 0.5f * v;
        if (OBF) ((ushort*)Cv)[row * N + col] = f2bf(v);
        else ((float*)Cv)[row * N + col] = v;
      }
    }
  }
}

// ---------------- merged QKV projection: N=1536, routed epilogue ----------------
__global__ __launch_bounds__(256) void gemm_qkv(const ushort* __restrict__ A,
                                                const ushort* __restrict__ Wt,
                                                const float* __restrict__ bq,
                                                const float* __restrict__ bk,
                                                const float* __restrict__ bv,
                                                const float* __restrict__ ub,
                                                const float* __restrict__ vb,
                                                ushort* __restrict__ qu,
                                                ushort* __restrict__ qv,
                                                ushort* __restrict__ kbb,
                                                ushort* __restrict__ vT,
                                                int M, int K) {
  __shared__ ushort Al[2][8192];
  __shared__ ushort Bl[2][8192];
  const int t = threadIdx.x;
  const int lane = t & 63;
  const int w = t >> 6;
  const int wr = (w >> 1) << 6, wc = (w & 1) << 6;
  int bx = blockIdx.x, by = blockIdx.y;
  xcd_swz(bx, by);
  const int m0 = by << 7, n0 = bx << 7;
  const int lm = lane & 15;
  const int grow = lane >> 3;
  const int gcol = (lane & 7) << 3;
  f32x4 acc[4][4];
#pragma unroll
  for (int i = 0; i < 4; ++i)
#pragma unroll
    for (int j = 0; j < 4; ++j) acc[i][j] = (f32x4)(0.f);
  const int NT = K >> 6;
#pragma unroll
  for (int i = 0; i < 4; ++i) {
    const int s = (w << 2) + i;
    gload16(A + (size_t)(m0 + (s << 3) + grow) * K + gcol, &Al[0][s << 9]);
    gload16(Wt + (size_t)(n0 + (s << 3) + grow) * K + gcol, &Bl[0][s << 9]);
  }
  __syncthreads();
  int cur = 0;
  for (int tt = 0; tt < NT; ++tt) {
    if (tt + 1 < NT) {
      const int k0 = (tt + 1) << 6;
#pragma unroll
      for (int i = 0; i < 4; ++i) {
        const int s = (w << 2) + i;
        gload16(A + (size_t)(m0 + (s << 3) + grow) * K + k0 + gcol, &Al[cur ^ 1][s << 9]);
        gload16(Wt + (size_t)(n0 + (s << 3) + grow) * K + k0 + gcol, &Bl[cur ^ 1][s << 9]);
      }
    }
#pragma unroll
    for (int ks = 0; ks < 2; ++ks) {
      const int kof = (ks << 5) + ((lane >> 4) << 3);
      bf16x8 af[4], bfr[4];
#pragma unroll
      for (int i = 0; i < 4; ++i) af[i] = *(const bf16x8*)&Al[cur][(wr + (i << 4) + lm) * 64 + kof];
#pragma unroll
      for (int j = 0; j < 4; ++j) bfr[j] = *(const bf16x8*)&Bl[cur][(wc + (j << 4) + lm) * 64 + kof];
#pragma unroll
      for (int i = 0; i < 4; ++i)
#pragma unroll
        for (int j = 0; j < 4; ++j)
          acc[i][j] = __builtin_amdgcn_mfma_f32_16x16x32_bf16(af[i], bfr[j], acc[i][j], 0, 0, 0);
    }
    __syncthreads();
    cur ^= 1;
  }
  const int seg = n0 >> 9;                 // block-uniform: 0=q, 1=k, 2=v
  const int nloc = n0 & 511;
  const float* bsel = (seg == 0) ? bq : (seg == 1 ? bk : bv);
  float bb[4], uu[4], vv[4];
#pragma unroll
  for (int j = 0; j < 4; ++j) {
    const int col = nloc + wc + j * 16 + lm;
    bb[j] = bsel[col];
    if (seg == 0) { uu[j] = ub[col]; vv[j] = vb[col]; }
  }
  const int rbase = m0 + wr + ((lane >> 4) << 2);
  if (seg == 2) {
    const int bloc = m0 >> 9;
    const int sbase = rbase - (bloc << 9);
#pragma unroll
    for (int i = 0; i < 4; ++i) {
#pragma unroll
      for (int j = 0; j < 4; ++j) {
        const int col = nloc + wc + j * 16 + lm;
        ushort4 o;
        o.x = f2bf(acc[i][j][0] + bb[j]);
        o.y = f2bf(acc[i][j][1] + bb[j]);
        o.z = f2bf(acc[i][j][2] + bb[j]);
        o.w = f2bf(acc[i][j][3] + bb[j]);
        *(ushort4*)&vT[((size_t)((bloc << 9) + col)) * 512 + sbase + i * 16] = o;
      }
    }
    return;
  }
#pragma unroll
  for (int i = 0; i < 4; ++i) {
#pragma unroll
    for (int r = 0; r < 4; ++r) {
      const size_t row = (size_t)(rbase + i * 16 + r);
#pragma unroll
      for (int j = 0; j < 4; ++j) {
        const int col = nloc + wc + j * 16 + lm;
        const float v = acc[i][j][r] + bb[j];
        if (seg == 0) {
          qu[row * 512 + col] = f2bf(v + uu[j]);
          qv[row * 512 + col] = f2bf(v + vv[j]);
        } else {
          kbb[row * 512 + col] = f2bf(v);
        }
      }
    }
  }
}

// ---------------- pw1 + GLU fused ----------------------------------------------
__global__ __launch_bounds__(256) void gemm_glu(const ushort* __restrict__ A,
                                                const ushort* __restrict__ Wt,
                                                const float* __restrict__ bias,
                                                ushort* __restrict__ Cout,
                                                int M, int K) {
  __shared__ ushort Al[8192];
  __shared__ ushort Ba[8192];
  __shared__ ushort Bg[8192];
  const int t = threadIdx.x;
  const int lane = t & 63;
  const int w = t >> 6;
  const int wr = (w >> 1) << 6, wc = (w & 1) << 6;
  int bx = blockIdx.x, by = blockIdx.y;
  xcd_swz(bx, by);
  const int m0 = by << 7, n0 = bx << 7;
  const int lm = lane & 15;
  const int grow = lane >> 3;
  const int gcol = (lane & 7) << 3;
  const ushort* WtA = Wt;
  const ushort* WtG = Wt + (size_t)512 * 512;
  f32x4 acca[4][4], accg[4][4];
#pragma unroll
  for (int i = 0; i < 4; ++i)
#pragma unroll
    for (int j = 0; j < 4; ++j) { acca[i][j] = (f32x4)(0.f); accg[i][j] = (f32x4)(0.f); }
  const int NT = K >> 6;
  for (int tt = 0; tt < NT; ++tt) {
    const int k0 = tt << 6;
    if (tt) __syncthreads();
#pragma unroll
    for (int i = 0; i < 4; ++i) {
      const int s = (w << 2) + i;
      gload16(A + (size_t)(m0 + (s << 3) + grow) * K + k0 + gcol, &Al[s << 9]);
      gload16(WtA + (size_t)(n0 + (s << 3) + grow) * K + k0 + gcol, &Ba[s << 9]);
      gload16(WtG + (size_t)(n0 + (s << 3) + grow) * K + k0 + gcol, &Bg[s << 9]);
    }
    __syncthreads();
#pragma unroll
    for (int ks = 0; ks < 2; ++ks) {
      const int kof = (ks << 5) + ((lane >> 4) << 3);
      bf16x8 af[4], ba4[4], bg4[4];
#pragma unroll
      for (int i = 0; i < 4; ++i) af[i] = *(const bf16x8*)&Al[(wr + (i << 4) + lm) * 64 + kof];
#pragma unroll
      for (int j = 0; j < 4; ++j) {
        ba4[j] = *(const bf16x8*)&Ba[(wc + (j << 4) + lm) * 64 + kof];
        bg4[j] = *(const bf16x8*)&Bg[(wc + (j << 4) + lm) * 64 + kof];
      }
#pragma unroll
      for (int i = 0; i < 4; ++i)
#pragma unroll
        for (int j = 0; j < 4; ++j) {
          acca[i][j] = __builtin_amdgcn_mfma_f32_16x16x32_bf16(af[i], ba4[j], acca[i][j], 0, 0, 0);
          accg[i][j] = __builtin_amdgcn_mfma_f32_16x16x32_bf16(af[i], bg4[j], accg[i][j], 0, 0, 0);
        }
    }
  }
  float bba[4], bbg[4];
#pragma unroll
  for (int j = 0; j < 4; ++j) {
    const int col = n0 + wc + j * 16 + lm;
    bba[j] = bias[col];
    bbg[j] = bias[512 + col];
  }
  const int rbase = m0 + wr + ((lane >> 4) << 2);
#pragma unroll
  for (int i = 0; i < 4; ++i) {
#pragma unroll
    for (int r = 0; r < 4; ++r) {
      const size_t row = (size_t)(rbase + i * 16 + r);
#pragma unroll
      for (int j = 0; j < 4; ++j) {
        const int col = n0 + wc + j * 16 + lm;
        const float va = acca[i][j][r] + bba[j];
        const float vg = accg[i][j][r] + bbg[j];
        Cout[row * 512 + col] = f2bf(va * sigmf(vg));
      }
    }
  }
}

// ------------- Sinusoidal PE (bf16) ---------------------------------------------
__global__ void pe_kernel_bf16(ushort* __restrict__ pe) {
  const int pos = blockIdx.x, ii = threadIdx.x;
  const float ang = (float)pos * powf(10000.f, -(float)(2 * ii) / 512.f);
  pe[((size_t)pos << 9) + 2 * ii] = f2bf(sinf(ang));
  pe[((size_t)pos << 9) + 2 * ii + 1] = f2bf(cosf(ang));
}

// ------------- fused attention v5: coalesced staging + prefetch + XCD grouping --
// block = (q-block 64) x (z = b*8+h), z-grouped per XCD via xcd_swz.
// LDS: psL[65][520] (67.6KB) + stage[64][72] (9.2KB).
__global__ __launch_bounds__(256) void attn_fused5(const ushort* __restrict__ qu,
                                                   const ushort* __restrict__ qv,
                                                   const ushort* __restrict__ kbb,
                                                   const ushort* __restrict__ ppb,
                                                   const ushort* __restrict__ vT,
                                                   float* __restrict__ attn,
                                                   ushort* __restrict__ ctx) {
  __shared__ ushort psL[65][520];
  __shared__ ushort stage[64][72];
  const int t = threadIdx.x, lane = t & 63, w = t >> 6;
  int bx = blockIdx.x, by = blockIdx.y;
  xcd_swz(bx, by);                 // same-z q-blocks -> same XCD (K/V L2 reuse)
  const int z = by, b = z >> 3, h = z & 7;
  const int q0 = bx << 6;
  const int lm = lane & 15, g = lane >> 4;
  const int lk = g << 3, fr4 = g << 2;
  const int srow = t >> 2, scol = (t & 3) << 4;   // coalesced stage mapping

  // A-fragments from global (own q rows)
  const size_t qoff = ((size_t)((b << 9) + q0 + (w << 4) + lm)) * 512 + (h << 6);
  const bf16x8 av0 = *(const bf16x8*)&qv[qoff + lk];
  const bf16x8 av1 = *(const bf16x8*)&qv[qoff + lk + 32];
  const bf16x8 au0 = *(const bf16x8*)&qu[qoff + lk];
  const bf16x8 au1 = *(const bf16x8*)&qu[qoff + lk + 32];
  int er = q0 + 64 + lm;
  if (er > 511) er = 511;
  const size_t eoff = ((size_t)((b << 9) + er)) * 512 + (h << 6);
  const bf16x8 e0 = *(const bf16x8*)&qv[eoff + lk];
  const bf16x8 e1 = *(const bf16x8*)&qv[eoff + lk + 32];

  // ---- PS pass: rotate-prefetch staged pp tiles ---------------------------------
  const ushort* pb_ = ppb + (h << 6);
  bf16x8 r0 = *(const bf16x8*)&pb_[(size_t)srow * 512 + scol];
  bf16x8 r1 = *(const bf16x8*)&pb_[(size_t)srow * 512 + scol + 8];
#pragma unroll
  for (int tile = 0; tile < 8; ++tile) {
    __syncthreads();                      // prev tile's MFMA reads done
    *(bf16x8*)&stage[srow][scol] = r0;
    *(bf16x8*)&stage[srow][scol + 8] = r1;
    if (tile < 7) {                       // prefetch next tile (hides under MFMA)
      r0 = *(const bf16x8*)&pb_[(size_t)((tile + 1) * 64 + srow) * 512 + scol];
      r1 = *(const bf16x8*)&pb_[(size_t)((tile + 1) * 64 + srow) * 512 + scol + 8];
    }
    __syncthreads();
#pragma unroll
    for (int ctl = 0; ctl < 4; ++ctl) {
      const bf16x8 b0 = *(const bf16x8*)&stage[(ctl << 4) + lm][lk];
      const bf16x8 b1 = *(const bf16x8*)&stage[(ctl << 4) + lm][lk + 32];
      f32x4 a = (f32x4)(0.f);
      a = __builtin_amdgcn_mfma_f32_16x16x32_bf16(av0, b0, a, 0, 0, 0);
      a = __builtin_amdgcn_mfma_f32_16x16x32_bf16(av1, b1, a, 0, 0, 0);
      const int col = (tile << 6) + (ctl << 4) + lm;
#pragma unroll
      for (int r = 0; r < 4; ++r) psL[(w << 4) + fr4 + r][col] = f2bf(a[r]);
      if (ctl == w) {                     // boundary row q0+64, wave-partitioned
        f32x4 e = (f32x4)(0.f);
        e = __builtin_amdgcn_mfma_f32_16x16x32_bf16(e0, b0, e, 0, 0, 0);
        e = __builtin_amdgcn_mfma_f32_16x16x32_bf16(e1, b1, e, 0, 0, 0);
        if (g == 0) psL[64][col] = f2bf(e[0]);
      }
    }
  }

  // ---- QK pass: same rotate-prefetch pattern on K --------------------------------
  const ushort* kb_ = kbb + ((size_t)(b << 9)) * 512 + (h << 6);
  r0 = *(const bf16x8*)&kb_[(size_t)srow * 512 + scol];
  r1 = *(const bf16x8*)&kb_[(size_t)srow * 512 + scol + 8];
  f32x4 acc[32];
#pragma unroll
  for (int i = 0; i < 32; ++i) acc[i] = (f32x4)(0.f);
#pragma unroll
  for (int tile = 0; tile < 8; ++tile) {
    __syncthreads();
    *(bf16x8*)&stage[srow][scol] = r0;
    *(bf16x8*)&stage[srow][scol + 8] = r1;
    if (tile < 7) {
      r0 = *(const bf16x8*)&kb_[(size_t)((tile + 1) * 64 + srow) * 512 + scol];
      r1 = *(const bf16x8*)&kb_[(size_t)((tile + 1) * 64 + srow) * 512 + scol + 8];
    }
    __syncthreads();
#pragma unroll
    for (int ctl = 0; ctl < 4; ++ctl) {
      const int ct = (tile << 2) + ctl;
      const bf16x8 b0 = *(const bf16x8*)&stage[(ctl << 4) + lm][lk];
      const bf16x8 b1 = *(const bf16x8*)&stage[(ctl << 4) + lm][lk + 32];
      acc[ct] = __builtin_amdgcn_mfma_f32_16x16x32_bf16(au0, b0, acc[ct], 0, 0, 0);
      acc[ct] = __builtin_amdgcn_mfma_f32_16x16x32_bf16(au1, b1, acc[ct], 0, 0, 0);
    }
  }

  // ---- rel-shift gather from psL + scale ------------------------------------------
  const float scale = 0.044194173824159216f;  // 1/sqrt(512)
  const int qb_ = q0 + (w << 4) + fr4;
#pragma unroll
  for (int ct = 0; ct < 32; ++ct) {
#pragma unroll
    for (int r = 0; r < 4; ++r) {
      const int q = qb_ + r;
      const int qq = q - q0;
      const int c = (ct << 4) + lm;
      float f;
      if (c <= q)          f = bf2f(psL[qq][c - q + 511]);
      else if (c == q + 1) f = 0.f;
      else                 f = bf2f(psL[qq + 1][c - q - 2]);
      acc[ct][r] = (acc[ct][r] + f) * scale;
    }
  }
  // ---- softmax --------------------------------------------------------------------
  float mx[4] = {-3.0e38f, -3.0e38f, -3.0e38f, -3.0e38f};
#pragma unroll
  for (int ct = 0; ct < 32; ++ct)
#pragma unroll
    for (int r = 0; r < 4; ++r) mx[r] = fmaxf(mx[r], acc[ct][r]);
#pragma unroll
  for (int o = 1; o < 16; o <<= 1)
#pragma unroll
    for (int r = 0; r < 4; ++r) mx[r] = fmaxf(mx[r], __shfl_xor(mx[r], o));
  float sme[4] = {0.f, 0.f, 0.f, 0.f};
#pragma unroll
  for (int ct = 0; ct < 32; ++ct)
#pragma unroll
    for (int r = 0; r < 4; ++r) {
      acc[ct][r] = __expf(acc[ct][r] - mx[r]);
      sme[r] += acc[ct][r];
    }
#pragma unroll
  for (int o = 1; o < 16; o <<= 1)
#pragma unroll
    for (int r = 0; r < 4; ++r) sme[r] += __shfl_xor(sme[r], o);
#pragma unroll
  for (int r = 0; r < 4; ++r) {
    const float inv = 1.f / sme[r];
#pragma unroll
    for (int ct = 0; ct < 32; ++ct) acc[ct][r] *= inv;
  }
  __syncthreads();  // all psL gather reads done -> safe to reuse psL as P buffer

  // ---- PV + coalesced attn-write, 8 chunks of 64 c --------------------------------
  ushort* Pl = &psL[0][0];  // reused as [64][72]
  const ushort* vtb = vT + ((size_t)((b << 9) + (h << 6))) * 512;
  float* abase = attn + ((size_t)z << 18);
  f32x4 acc2[4];
#pragma unroll
  for (int i = 0; i < 4; ++i) acc2[i] = (f32x4)(0.f);
#pragma unroll
  for (int ch = 0; ch < 8; ++ch) {
    // a: P(acc) -> Pl (own 16 rows per wave)
#pragma unroll
    for (int ctl = 0; ctl < 4; ++ctl) {
      const int ct = (ch << 2) + ctl;
#pragma unroll
      for (int r = 0; r < 4; ++r)
        Pl[((w << 4) + fr4 + r) * 72 + (ctl << 4) + lm] = f2bf(acc[ct][r]);
    }
    // b: V-chunk -> regs (coalesced rows)
    const bf16x8 v0 = *(const bf16x8*)&vtb[(size_t)srow * 512 + (ch << 6) + scol];
    const bf16x8 v1 = *(const bf16x8*)&vtb[(size_t)srow * 512 + (ch << 6) + scol + 8];
    __syncthreads();                      // Pl complete; prev stage reads done
    // d: V regs -> stage
    *(bf16x8*)&stage[srow][scol] = v0;
    *(bf16x8*)&stage[srow][scol + 8] = v1;
    // e: attn write from Pl (coalesced float4 stores; values bf16-rounded)
    {
      const ushort* ps = &Pl[srow * 72 + scol];
      float* ar = abase + (size_t)(q0 + srow) * 512 + (ch << 6) + scol;
#pragma unroll
      for (int k4 = 0; k4 < 4; ++k4) {
        float4 o;
        o.x = bf2f(ps[k4 * 4 + 0]);
        o.y = bf2f(ps[k4 * 4 + 1]);
        o.z = bf2f(ps[k4 * 4 + 2]);
        o.w = bf2f(ps[k4 * 4 + 3]);
        *(float4*)&ar[k4 * 4] = o;
      }
    }
    __syncthreads();                      // stage complete; Pl reads done
    // g: PV MFMA
#pragma unroll
    for (int ks = 0; ks < 2; ++ks) {
      const int kof = (ks << 5) + lk;
      const bf16x8 pbf = *(const bf16x8*)&Pl[((w << 4) + lm) * 72 + kof];
#pragma unroll
      for (int dt = 0; dt < 4; ++dt) {
        const bf16x8 va = *(const bf16x8*)&stage[(dt << 4) + lm][kof];
        acc2[dt] = __builtin_amdgcn_mfma_f32_16x16x32_bf16(va, pbf, acc2[dt], 0, 0, 0);
      }
    }
  }
  const int qq2 = q0 + (w << 4) + lm;
#pragma unroll
  for (int dt = 0; dt < 4; ++dt) {
    ushort4 o;
    o.x = f2bf(acc2[dt][0]); o.y = f2bf(acc2[dt][1]);
    o.z = f2bf(acc2[dt][2]); o.w = f2bf(acc2[dt][3]);
    *(ushort4*)&ctx[((size_t)((b << 9) + qq2)) * 512 + (h << 6) + (dt << 4) + fr4] = o;
  }
}

// ------------- depthwise conv (K=31) + BN + swish, register sliding window ------
__global__ __launch_bounds__(256) void dwconv2(const ushort* __restrict__ in,
                                               const float* __restrict__ w,
                                               const float* __restrict__ bng,
                                               const float* __restrict__ bnb,
                                               const float* __restrict__ bnm,
                                               const float* __restrict__ bnv,
                                               ushort* __restrict__ out) {
  __shared__ float wl[31][128];
  const int t = threadIdx.x;
  const int dbase = blockIdx.x << 7;
  const int b = blockIdx.z;
  const int sb = (blockIdx.y << 6) + ((t >> 6) << 4);
  if (t < 128) {
    const float* ws = &w[(dbase + t) * 31];
#pragma unroll
    for (int k = 0; k < 31; ++k) wl[k][t] = ws[k];
  }
  __syncthreads();
  const int dl = (t & 63) << 1;
  const int d = dbase + dl;
  const size_t base = (((size_t)b) << 18) + d;
  float2 win[46];
#pragma unroll
  for (int i = 0; i < 46; ++i) {
    const int s = sb - 15 + i;
    if (s >= 0 && s < 512) {
      const ushort2 u = *(const ushort2*)&in[base + ((size_t)s << 9)];
      win[i].x = bf2f(u.x); win[i].y = bf2f(u.y);
    } else {
      win[i].x = 0.f; win[i].y = 0.f;
    }
  }
  float2 acc[16];
#pragma unroll
  for (int p = 0; p < 16; ++p) { acc[p].x = 0.f; acc[p].y = 0.f; }
#pragma unroll
  for (int k = 0; k < 31; ++k) {
    const float2 w2 = *(const float2*)&wl[k][dl];
#pragma unroll
    for (int p = 0; p < 16; ++p) {
      acc[p].x = fmaf(win[p + k].x, w2.x, acc[p].x);
      acc[p].y = fmaf(win[p + k].y, w2.y, acc[p].y);
    }
  }
  const float g0 = bng[d] * rsqrtf(bnv[d] + EPSF);
  const float g1 = bng[d + 1] * rsqrtf(bnv[d + 1] + EPSF);
  const float m0 = bnm[d], m1 = bnm[d + 1];
  const float bb0 = bnb[d], bb1 = bnb[d + 1];
#pragma unroll
  for (int p = 0; p < 16; ++p) {
    float v0 = (acc[p].x - m0) * g0 + bb0;
    float v1 = (acc[p].y - m1) * g1 + bb1;
    v0 = v0 * sigmf(v0);
    v1 = v1 * sigmf(v1);
    ushort2 o;
    o.x = f2bf(v0); o.y = f2bf(v1);
    *(ushort2*)&out[base + ((size_t)(sb + p) << 9)] = o;
  }
}

extern "C" void kernel_launch(void* const* d_in, const int* in_sizes, int n_in,
                              void* d_out, int out_size, void* d_ws, size_t ws_size,
                              hipStream_t stream) {
  const float* x      = (const float*)d_in[0];
  const float* ff1_g  = (const float*)d_in[1];
  const float* ff1_b  = (const float*)d_in[2];
  const float* ff1_w1 = (const float*)d_in[3];
  const float* ff1_b1 = (const float*)d_in[4];
  const float* ff1_w2 = (const float*)d_in[5];
  const float* ff1_b2 = (const float*)d_in[6];
  const float* attn_g = (const float*)d_in[7];
  const float* attn_b = (const float*)d_in[8];
  const float* wq     = (const float*)d_in[9];
  const float* bq     = (const float*)d_in[10];
  const float* wk     = (const float*)d_in[11];
  const float* bk     = (const float*)d_in[12];
  const float* wv     = (const float*)d_in[13];
  const float* bv     = (const float*)d_in[14];
  const float* wpos   = (const float*)d_in[15];
  const float* u_bias = (const float*)d_in[16];
  const float* v_bias = (const float*)d_in[17];
  const float* wo     = (const float*)d_in[18];
  const float* bo     = (const float*)d_in[19];
  const float* conv_g = (const float*)d_in[20];
  const float* conv_b = (const float*)d_in[21];
  const float* pw1_w  = (const float*)d_in[22];
  const float* pw1_b  = (const float*)d_in[23];
  const float* dw_w   = (const float*)d_in[24];
  const float* bn_g   = (const float*)d_in[25];
  const float* bn_b   = (const float*)d_in[26];
  const float* bn_m   = (const float*)d_in[27];
  const float* bn_v   = (const float*)d_in[28];
  const float* pw2_w  = (const float*)d_in[29];
  const float* pw2_b  = (const float*)d_in[30];
  const float* ff2_g  = (const float*)d_in[31];
  const float* ff2_b  = (const float*)d_in[32];
  const float* ff2_w1 = (const float*)d_in[33];
  const float* ff2_b1 = (const float*)d_in[34];
  const float* ff2_w2 = (const float*)d_in[35];
  const float* ff2_b2 = (const float*)d_in[36];
  const float* ln_g   = (const float*)d_in[37];
  const float* ln_b   = (const float*)d_in[38];

  float* out  = (float*)d_out;            // [B,S,D] f32
  float* attn = out + ND;                 // [B,H,S,S] f32

  float*  res  = (float*)d_ws;
  ushort* ybf  = (ushort*)(res + ND);
  float*  big  = (float*)(ybf + ND);             // 2*ND f32 region
  ushort* vT   = (ushort*)(big + 2 * ND);        // ND ushorts [b][col][s]
  ushort* dwbf = vT + ND;                        // ND ushorts
  ushort* wts  = dwbf + ND;                      // 6,291,456 ushorts
  ushort* pebf = wts + 6291456;                  // 262,144
  ushort* ppbf = pebf + 262144;                  // 262,144

  ushort* ffmid = (ushort*)big;
  ushort* qu    = (ushort*)big;
  ushort* qv    = qu + ND;
  ushort* kbb   = qv + ND;
  ushort* ctxbf = ybf;
  ushort* glubf = (ushort*)big;

  ushort* ff1w1t = wts;
  ushort* ff1w2t = wts + 1048576;
  ushort* wqt    = wts + 2097152;
  ushort* wkt    = wts + 2359296;
  ushort* wvt    = wts + 2621440;
  ushort* wot    = wts + 2883584;
  ushort* pw1t   = wts + 3145728;
  ushort* pw2t   = wts + 3670016;
  ushort* ff2w1t = wts + 3932160;
  ushort* ff2w2t = wts + 4980736;
  ushort* wpost  = wts + 6029312;

  const dim3 blk(256);

  // ---- weight prep: single merged transpose dispatch ----
  TpArgs ta;
  auto set = [&](int i, const float* s, ushort* d, int K, int N) {
    ta.src[i] = s; ta.dst[i] = d; ta.K[i] = K; ta.N[i] = N;
  };
  set(0, ff1_w1, ff1w1t, 512, 2048);
  set(1, ff1_w2, ff1w2t, 2048, 512);
  set(2, wq, wqt, 512, 512);
  set(3, wk, wkt, 512, 512);
  set(4, wv, wvt, 512, 512);
  set(5, wo, wot, 512, 512);
  set(6, wpos, wpost, 512, 512);
  set(7, pw1_w, pw1t, 512, 1024);
  set(8, pw2_w, pw2t, 512, 512);
  set(9, ff2_w1, ff2w1t, 512, 2048);
  set(10, ff2_w2, ff2w2t, 2048, 512);
  int tacc = 0;
  for (int i = 0; i < 11; ++i) { ta.base[i] = tacc; tacc += (ta.N[i] >> 5) * (ta.K[i] >> 5); }
  ta.base[11] = tacc;
  transpose_all<<<tacc, blk, 0, stream>>>(ta);
  pe_kernel_bf16<<<512, blk, 0, stream>>>(pebf);
  gemm_bf16<0, 0, 0, 1><<<dim3(4, 4), blk, 0, stream>>>(pebf, wpost, nullptr, nullptr, ppbf,
                                                        512, 512, 512);

  // ---- Macaron FF1: res = x + 0.5*FF(LN(x)) ----
  ln_bf16<<<NTOK / 4, blk, 0, stream>>>(x, ff1_g, ff1_b, ybf);
  gemm_bf16<1, 0, 1, 1><<<dim3(16, 128), blk, 0, stream>>>(ybf, ff1w1t, ff1_b1, nullptr, ffmid,
                                                           NTOK, 512, 2048);
  gemm_bf16<0, 2, 1, 0><<<dim3(4, 128), blk, 0, stream>>>(ffmid, ff1w2t, ff1_b2, x, res,
                                                          NTOK, 2048, 512);

  // ---- Attention ----
  ln_bf16<<<NTOK / 4, blk, 0, stream>>>(res, attn_g, attn_b, ybf);
  gemm_qkv<<<dim3(12, 128), blk, 0, stream>>>(ybf, wqt, bq, bk, bv, u_bias, v_bias,
                                              qu, qv, kbb, vT, NTOK, 512);
  attn_fused5<<<dim3(8, 256), blk, 0, stream>>>(qu, qv, kbb, ppbf, vT, attn, ctxbf);
  gemm_bf16<0, 1, 1, 0><<<dim3(4, 128), blk, 0, stream>>>(ctxbf, wot, bo, res, res,
                                                          NTOK, 512, 512);

  // ---- Conv module ----
  ln_bf16<<<NTOK / 4, blk, 0, stream>>>(res, conv_g, conv_b, ybf);
  gemm_glu<<<dim3(4, 128), blk, 0, stream>>>(ybf, pw1t, pw1_b, glubf, NTOK, 512);
  dwconv2<<<dim3(4, 8, 32), blk, 0, stream>>>(glubf, dw_w, bn_g, bn_b, bn_m, bn_v, dwbf);
  gemm_bf16<0, 1, 1, 0><<<dim3(4, 128), blk, 0, stream>>>(dwbf, pw2t, pw2_b, res, res,
                                                          NTOK, 512, 512);

  // ---- Macaron FF2 + final LN ----
  ln_bf16<<<NTOK / 4, blk, 0, stream>>>(res, ff2_g, ff2_b, ybf);
  gemm_bf16<1, 0, 1, 1><<<dim3(16, 128), blk, 0, stream>>>(ybf, ff2w1t, ff2_b1, nullptr, ffmid,
                                                           NTOK, 512, 2048);
  gemm_bf16<0, 2, 1, 0><<<dim3(4, 128), blk, 0, stream>>>(ffmid, ff2w2t, ff2_b2, res, res,
                                                          NTOK, 2048, 512);
  ln_f32<<<NTOK / 4, blk, 0, stream>>>(res, ln_g, ln_b, out);
}

// Round 9
// 733.498 us; speedup vs baseline: 1.3102x; 1.0976x over previous
//
#include <hip/hip_runtime.h>
#include <cstddef>
#include <cstdint>

#define EPSF 1e-5f

constexpr int BB = 32, SS = 512, DD = 512, HH = 8, DH = 64;
constexpr int NTOK = BB * SS;              // 16384 rows
constexpr size_t ND = (size_t)NTOK * DD;   // 8,388,608

typedef __attribute__((ext_vector_type(8))) short bf16x8;
typedef __attribute__((ext_vector_type(4))) float f32x4;

__device__ __forceinline__ float sigmf(float v) { return 1.f / (1.f + __expf(-v)); }

__device__ __forceinline__ ushort f2bf(float f) {
  union { float f; uint32_t u; } x{f};
  uint32_t r = x.u + 0x7FFF + ((x.u >> 16) & 1);
  return (ushort)(r >> 16);
}
__device__ __forceinline__ float bf2f(ushort u) {
  union { uint32_t u; float f; } x{(uint32_t)u << 16};
  return x.f;
}

__device__ __forceinline__ void gload16(const ushort* g, ushort* ldsbase) {
  __builtin_amdgcn_global_load_lds((const __attribute__((address_space(1))) void*)g,
                                   (__attribute__((address_space(3))) void*)ldsbase, 16, 0, 0);
}

// bijective XCD-chunk swizzle (m204); requires nwg % 8 == 0.
__device__ __forceinline__ void xcd_swz(int& bx, int& by) {
  const int gx = gridDim.x;
  const int nwg = gx * gridDim.y;
  const int cpx = nwg >> 3;
  int id = by * gx + bx;
  id = (id & 7) * cpx + (id >> 3);
  bx = id % gx;
  by = id / gx;
}

// ---------------- LayerNorm: one wave per row, f32 out --------------------------
__global__ __launch_bounds__(256) void ln_f32(const float* __restrict__ x,
                                              const float* __restrict__ g,
                                              const float* __restrict__ b,
                                              float* __restrict__ y) {
  const int lane = threadIdx.x & 63;
  const int row = blockIdx.x * 4 + (threadIdx.x >> 6);
  const float* xr = x + (size_t)row * 512;
  const float4 v0 = *(const float4*)&xr[lane << 2];
  const float4 v1 = *(const float4*)&xr[256 + (lane << 2)];
  float s = v0.x + v0.y + v0.z + v0.w + v1.x + v1.y + v1.z + v1.w;
#pragma unroll
  for (int o = 32; o > 0; o >>= 1) s += __shfl_xor(s, o);
  const float mean = s * (1.f / 512.f);
  float q = 0.f;
  q += (v0.x - mean) * (v0.x - mean); q += (v0.y - mean) * (v0.y - mean);
  q += (v0.z - mean) * (v0.z - mean); q += (v0.w - mean) * (v0.w - mean);
  q += (v1.x - mean) * (v1.x - mean); q += (v1.y - mean) * (v1.y - mean);
  q += (v1.z - mean) * (v1.z - mean); q += (v1.w - mean) * (v1.w - mean);
#pragma unroll
  for (int o = 32; o > 0; o >>= 1) q += __shfl_xor(q, o);
  const float rs = rsqrtf(q * (1.f / 512.f) + EPSF);
  const float4 g0 = *(const float4*)&g[lane << 2];
  const float4 g1 = *(const float4*)&g[256 + (lane << 2)];
  const float4 b0 = *(const float4*)&b[lane << 2];
  const float4 b1 = *(const float4*)&b[256 + (lane << 2)];
  float* yr = y + (size_t)row * 512;
  float4 o0, o1;
  o0.x = (v0.x - mean) * rs * g0.x + b0.x; o0.y = (v0.y - mean) * rs * g0.y + b0.y;
  o0.z = (v0.z - mean) * rs * g0.z + b0.z; o0.w = (v0.w - mean) * rs * g0.w + b0.w;
  o1.x = (v1.x - mean) * rs * g1.x + b1.x; o1.y = (v1.y - mean) * rs * g1.y + b1.y;
  o1.z = (v1.z - mean) * rs * g1.z + b1.z; o1.w = (v1.w - mean) * rs * g1.w + b1.w;
  *(float4*)&yr[lane << 2] = o0;
  *(float4*)&yr[256 + (lane << 2)] = o1;
}

// ---------------- LayerNorm writing bf16 ----------------------------------------
__global__ __launch_bounds__(256) void ln_bf16(const float* __restrict__ x,
                                               const float* __restrict__ g,
                                               const float* __restrict__ b,
                                               ushort* __restrict__ y) {
  const int lane = threadIdx.x & 63;
  const int row = blockIdx.x * 4 + (threadIdx.x >> 6);
  const float* xr = x + (size_t)row * 512;
  const float4 v0 = *(const float4*)&xr[lane << 2];
  const float4 v1 = *(const float4*)&xr[256 + (lane << 2)];
  float s = v0.x + v0.y + v0.z + v0.w + v1.x + v1.y + v1.z + v1.w;
#pragma unroll
  for (int o = 32; o > 0; o >>= 1) s += __shfl_xor(s, o);
  const float mean = s * (1.f / 512.f);
  float q = 0.f;
  q += (v0.x - mean) * (v0.x - mean); q += (v0.y - mean) * (v0.y - mean);
  q += (v0.z - mean) * (v0.z - mean); q += (v0.w - mean) * (v0.w - mean);
  q += (v1.x - mean) * (v1.x - mean); q += (v1.y - mean) * (v1.y - mean);
  q += (v1.z - mean) * (v1.z - mean); q += (v1.w - mean) * (v1.w - mean);
#pragma unroll
  for (int o = 32; o > 0; o >>= 1) q += __shfl_xor(q, o);
  const float rs = rsqrtf(q * (1.f / 512.f) + EPSF);
  const float4 g0 = *(const float4*)&g[lane << 2];
  const float4 g1 = *(const float4*)&g[256 + (lane << 2)];
  const float4 b0 = *(const float4*)&b[lane << 2];
  const float4 b1 = *(const float4*)&b[256 + (lane << 2)];
  ushort* yr = y + (size_t)row * 512;
  ushort4 o0, o1;
  o0.x = f2bf((v0.x - mean) * rs * g0.x + b0.x); o0.y = f2bf((v0.y - mean) * rs * g0.y + b0.y);
  o0.z = f2bf((v0.z - mean) * rs * g0.z + b0.z); o0.w = f2bf((v0.w - mean) * rs * g0.w + b0.w);
  o1.x = f2bf((v1.x - mean) * rs * g1.x + b1.x); o1.y = f2bf((v1.y - mean) * rs * g1.y + b1.y);
  o1.z = f2bf((v1.z - mean) * rs * g1.z + b1.z); o1.w = f2bf((v1.w - mean) * rs * g1.w + b1.w);
  *(ushort4*)&yr[lane << 2] = o0;
  *(ushort4*)&yr[256 + (lane << 2)] = o1;
}

// ---------------- merged weight transpose: 11 segments, one dispatch ------------
struct TpArgs {
  const float* src[11];
  ushort* dst[11];
  int K[11];
  int N[11];
  int base[12];
};

__global__ __launch_bounds__(256) void transpose_all(TpArgs a) {
  __shared__ float tile[32][33];
  int s = 0;
  const int bid = blockIdx.x;
  while (s < 10 && bid >= a.base[s + 1]) ++s;
  const int r = bid - a.base[s];
  const int K = a.K[s], N = a.N[s];
  const int ntx = N >> 5;
  const int n0 = (r % ntx) << 5;
  const int k0 = (r / ntx) << 5;
  const float* in = a.src[s];
  ushort* out = a.dst[s];
  const int tx = threadIdx.x & 31, ty = threadIdx.x >> 5;
#pragma unroll
  for (int i = 0; i < 32; i += 8)
    tile[ty + i][tx] = in[(size_t)(k0 + ty + i) * N + n0 + tx];
  __syncthreads();
#pragma unroll
  for (int i = 0; i < 32; i += 8)
    out[(size_t)(n0 + ty + i) * K + k0 + tx] = f2bf(tile[tx][ty + i]);
}

// ---------------- bf16 MFMA GEMM, T3-minimum 2-phase double-buffer --------------
template <int ACT, int RES, int HB, int OBF>
__global__ __launch_bounds__(256) void gemm_bf16(const ushort* __restrict__ A,
                                                 const ushort* __restrict__ Wt,
                                                 const float* __restrict__ bias,
                                                 const float* __restrict__ res,
                                                 void* __restrict__ Cv,
                                                 int M, int K, int N) {
  __shared__ ushort Al[2][8192];
  __shared__ ushort Bl[2][8192];
  const int t = threadIdx.x;
  const int lane = t & 63;
  const int w = t >> 6;
  const int wr = (w >> 1) << 6, wc = (w & 1) << 6;
  int bx = blockIdx.x, by = blockIdx.y;
  xcd_swz(bx, by);
  const int m0 = by << 7, n0 = bx << 7;
  const int lm = lane & 15;
  const int grow = lane >> 3;
  const int gcol = (lane & 7) << 3;

  f32x4 acc[4][4];
#pragma unroll
  for (int i = 0; i < 4; ++i)
#pragma unroll
    for (int j = 0; j < 4; ++j) acc[i][j] = (f32x4)(0.f);

  const int NT = K >> 6;
#pragma unroll
  for (int i = 0; i < 4; ++i) {
    const int s = (w << 2) + i;
    gload16(A + (size_t)(m0 + (s << 3) + grow) * K + gcol, &Al[0][s << 9]);
    gload16(Wt + (size_t)(n0 + (s << 3) + grow) * K + gcol, &Bl[0][s << 9]);
  }
  __syncthreads();
  int cur = 0;
  for (int tt = 0; tt < NT; ++tt) {
    if (tt + 1 < NT) {
      const int k0 = (tt + 1) << 6;
#pragma unroll
      for (int i = 0; i < 4; ++i) {
        const int s = (w << 2) + i;
        gload16(A + (size_t)(m0 + (s << 3) + grow) * K + k0 + gcol, &Al[cur ^ 1][s << 9]);
        gload16(Wt + (size_t)(n0 + (s << 3) + grow) * K + k0 + gcol, &Bl[cur ^ 1][s << 9]);
      }
    }
#pragma unroll
    for (int ks = 0; ks < 2; ++ks) {
      const int kof = (ks << 5) + ((lane >> 4) << 3);
      bf16x8 af[4], bfr[4];
#pragma unroll
      for (int i = 0; i < 4; ++i) af[i] = *(const bf16x8*)&Al[cur][(wr + (i << 4) + lm) * 64 + kof];
#pragma unroll
      for (int j = 0; j < 4; ++j) bfr[j] = *(const bf16x8*)&Bl[cur][(wc + (j << 4) + lm) * 64 + kof];
#pragma unroll
      for (int i = 0; i < 4; ++i)
#pragma unroll
        for (int j = 0; j < 4; ++j)
          acc[i][j] = __builtin_amdgcn_mfma_f32_16x16x32_bf16(af[i], bfr[j], acc[i][j], 0, 0, 0);
    }
    __syncthreads();
    cur ^= 1;
  }

  float bb[4] = {0.f, 0.f, 0.f, 0.f};
  if (HB) {
#pragma unroll
    for (int j = 0; j < 4; ++j) bb[j] = bias[n0 + wc + j * 16 + lm];
  }
  const int rbase = m0 + wr + ((lane >> 4) << 2);
#pragma unroll
  for (int i = 0; i < 4; ++i) {
#pragma unroll
    for (int r = 0; r < 4; ++r) {
      const size_t row = (size_t)(rbase + i * 16 + r);
#pragma unroll
      for (int j = 0; j < 4; ++j) {
        const int col = n0 + wc + j * 16 + lm;
        float v = acc[i][j][r] + bb[j];
        if (ACT == 1) v = v * sigmf(v);
        if (RES == 1) v += res[row * N + col];
        else if (RES == 2) v = res[row * N + col] + 0.5f * v;
        if (OBF) ((ushort*)Cv)[row * N + col] = f2bf(v);
        else ((float*)Cv)[row * N + col] = v;
      }
    }
  }
}

// ---------------- merged QKV projection: N=1536, routed epilogue ----------------
__global__ __launch_bounds__(256) void gemm_qkv(const ushort* __restrict__ A,
                                                const ushort* __restrict__ Wt,
                                                const float* __restrict__ bq,
                                                const float* __restrict__ bk,
                                                const float* __restrict__ bv,
                                                const float* __restrict__ ub,
                                                const float* __restrict__ vb,
                                                ushort* __restrict__ qu,
                                                ushort* __restrict__ qv,
                                                ushort* __restrict__ kbb,
                                                ushort* __restrict__ vT,
                                                int M, int K) {
  __shared__ ushort Al[2][8192];
  __shared__ ushort Bl[2][8192];
  const int t = threadIdx.x;
  const int lane = t & 63;
  const int w = t >> 6;
  const int wr = (w >> 1) << 6, wc = (w & 1) << 6;
  int bx = blockIdx.x, by = blockIdx.y;
  xcd_swz(bx, by);
  const int m0 = by << 7, n0 = bx << 7;
  const int lm = lane & 15;
  const int grow = lane >> 3;
  const int gcol = (lane & 7) << 3;
  f32x4 acc[4][4];
#pragma unroll
  for (int i = 0; i < 4; ++i)
#pragma unroll
    for (int j = 0; j < 4; ++j) acc[i][j] = (f32x4)(0.f);
  const int NT = K >> 6;
#pragma unroll
  for (int i = 0; i < 4; ++i) {
    const int s = (w << 2) + i;
    gload16(A + (size_t)(m0 + (s << 3) + grow) * K + gcol, &Al[0][s << 9]);
    gload16(Wt + (size_t)(n0 + (s << 3) + grow) * K + gcol, &Bl[0][s << 9]);
  }
  __syncthreads();
  int cur = 0;
  for (int tt = 0; tt < NT; ++tt) {
    if (tt + 1 < NT) {
      const int k0 = (tt + 1) << 6;
#pragma unroll
      for (int i = 0; i < 4; ++i) {
        const int s = (w << 2) + i;
        gload16(A + (size_t)(m0 + (s << 3) + grow) * K + k0 + gcol, &Al[cur ^ 1][s << 9]);
        gload16(Wt + (size_t)(n0 + (s << 3) + grow) * K + k0 + gcol, &Bl[cur ^ 1][s << 9]);
      }
    }
#pragma unroll
    for (int ks = 0; ks < 2; ++ks) {
      const int kof = (ks << 5) + ((lane >> 4) << 3);
      bf16x8 af[4], bfr[4];
#pragma unroll
      for (int i = 0; i < 4; ++i) af[i] = *(const bf16x8*)&Al[cur][(wr + (i << 4) + lm) * 64 + kof];
#pragma unroll
      for (int j = 0; j < 4; ++j) bfr[j] = *(const bf16x8*)&Bl[cur][(wc + (j << 4) + lm) * 64 + kof];
#pragma unroll
      for (int i = 0; i < 4; ++i)
#pragma unroll
        for (int j = 0; j < 4; ++j)
          acc[i][j] = __builtin_amdgcn_mfma_f32_16x16x32_bf16(af[i], bfr[j], acc[i][j], 0, 0, 0);
    }
    __syncthreads();
    cur ^= 1;
  }
  const int seg = n0 >> 9;                 // block-uniform: 0=q, 1=k, 2=v
  const int nloc = n0 & 511;
  const float* bsel = (seg == 0) ? bq : (seg == 1 ? bk : bv);
  float bb[4], uu[4], vv[4];
#pragma unroll
  for (int j = 0; j < 4; ++j) {
    const int col = nloc + wc + j * 16 + lm;
    bb[j] = bsel[col];
    if (seg == 0) { uu[j] = ub[col]; vv[j] = vb[col]; }
  }
  const int rbase = m0 + wr + ((lane >> 4) << 2);
  if (seg == 2) {
    const int bloc = m0 >> 9;
    const int sbase = rbase - (bloc << 9);
#pragma unroll
    for (int i = 0; i < 4; ++i) {
#pragma unroll
      for (int j = 0; j < 4; ++j) {
        const int col = nloc + wc + j * 16 + lm;
        ushort4 o;
        o.x = f2bf(acc[i][j][0] + bb[j]);
        o.y = f2bf(acc[i][j][1] + bb[j]);
        o.z = f2bf(acc[i][j][2] + bb[j]);
        o.w = f2bf(acc[i][j][3] + bb[j]);
        *(ushort4*)&vT[((size_t)((bloc << 9) + col)) * 512 + sbase + i * 16] = o;
      }
    }
    return;
  }
#pragma unroll
  for (int i = 0; i < 4; ++i) {
#pragma unroll
    for (int r = 0; r < 4; ++r) {
      const size_t row = (size_t)(rbase + i * 16 + r);
#pragma unroll
      for (int j = 0; j < 4; ++j) {
        const int col = nloc + wc + j * 16 + lm;
        const float v = acc[i][j][r] + bb[j];
        if (seg == 0) {
          qu[row * 512 + col] = f2bf(v + uu[j]);
          qv[row * 512 + col] = f2bf(v + vv[j]);
        } else {
          kbb[row * 512 + col] = f2bf(v);
        }
      }
    }
  }
}

// ---------------- pw1 + GLU fused ----------------------------------------------
__global__ __launch_bounds__(256) void gemm_glu(const ushort* __restrict__ A,
                                                const ushort* __restrict__ Wt,
                                                const float* __restrict__ bias,
                                                ushort* __restrict__ Cout,
                                                int M, int K) {
  __shared__ ushort Al[8192];
  __shared__ ushort Ba[8192];
  __shared__ ushort Bg[8192];
  const int t = threadIdx.x;
  const int lane = t & 63;
  const int w = t >> 6;
  const int wr = (w >> 1) << 6, wc = (w & 1) << 6;
  int bx = blockIdx.x, by = blockIdx.y;
  xcd_swz(bx, by);
  const int m0 = by << 7, n0 = bx << 7;
  const int lm = lane & 15;
  const int grow = lane >> 3;
  const int gcol = (lane & 7) << 3;
  const ushort* WtA = Wt;
  const ushort* WtG = Wt + (size_t)512 * 512;
  f32x4 acca[4][4], accg[4][4];
#pragma unroll
  for (int i = 0; i < 4; ++i)
#pragma unroll
    for (int j = 0; j < 4; ++j) { acca[i][j] = (f32x4)(0.f); accg[i][j] = (f32x4)(0.f); }
  const int NT = K >> 6;
  for (int tt = 0; tt < NT; ++tt) {
    const int k0 = tt << 6;
    if (tt) __syncthreads();
#pragma unroll
    for (int i = 0; i < 4; ++i) {
      const int s = (w << 2) + i;
      gload16(A + (size_t)(m0 + (s << 3) + grow) * K + k0 + gcol, &Al[s << 9]);
      gload16(WtA + (size_t)(n0 + (s << 3) + grow) * K + k0 + gcol, &Ba[s << 9]);
      gload16(WtG + (size_t)(n0 + (s << 3) + grow) * K + k0 + gcol, &Bg[s << 9]);
    }
    __syncthreads();
#pragma unroll
    for (int ks = 0; ks < 2; ++ks) {
      const int kof = (ks << 5) + ((lane >> 4) << 3);
      bf16x8 af[4], ba4[4], bg4[4];
#pragma unroll
      for (int i = 0; i < 4; ++i) af[i] = *(const bf16x8*)&Al[(wr + (i << 4) + lm) * 64 + kof];
#pragma unroll
      for (int j = 0; j < 4; ++j) {
        ba4[j] = *(const bf16x8*)&Ba[(wc + (j << 4) + lm) * 64 + kof];
        bg4[j] = *(const bf16x8*)&Bg[(wc + (j << 4) + lm) * 64 + kof];
      }
#pragma unroll
      for (int i = 0; i < 4; ++i)
#pragma unroll
        for (int j = 0; j < 4; ++j) {
          acca[i][j] = __builtin_amdgcn_mfma_f32_16x16x32_bf16(af[i], ba4[j], acca[i][j], 0, 0, 0);
          accg[i][j] = __builtin_amdgcn_mfma_f32_16x16x32_bf16(af[i], bg4[j], accg[i][j], 0, 0, 0);
        }
    }
  }
  float bba[4], bbg[4];
#pragma unroll
  for (int j = 0; j < 4; ++j) {
    const int col = n0 + wc + j * 16 + lm;
    bba[j] = bias[col];
    bbg[j] = bias[512 + col];
  }
  const int rbase = m0 + wr + ((lane >> 4) << 2);
#pragma unroll
  for (int i = 0; i < 4; ++i) {
#pragma unroll
    for (int r = 0; r < 4; ++r) {
      const size_t row = (size_t)(rbase + i * 16 + r);
#pragma unroll
      for (int j = 0; j < 4; ++j) {
        const int col = n0 + wc + j * 16 + lm;
        const float va = acca[i][j][r] + bba[j];
        const float vg = accg[i][j][r] + bbg[j];
        Cout[row * 512 + col] = f2bf(va * sigmf(vg));
      }
    }
  }
}

// ------------- Sinusoidal PE (bf16) ---------------------------------------------
__global__ void pe_kernel_bf16(ushort* __restrict__ pe) {
  const int pos = blockIdx.x, ii = threadIdx.x;
  const float ang = (float)pos * powf(10000.f, -(float)(2 * ii) / 512.f);
  pe[((size_t)pos << 9) + 2 * ii] = f2bf(sinf(ang));
  pe[((size_t)pos << 9) + 2 * ii + 1] = f2bf(cosf(ang));
}

// ------------- fused attention v6: QBLK=32, 2 bands x 2 col-halves, small LDS ---
// grid (16, 256). LDS ~44.6KB -> 2-3 blocks/CU (vs v5's 1).
__global__ __launch_bounds__(256, 3) void attn_fused6(const ushort* __restrict__ qu,
                                                      const ushort* __restrict__ qv,
                                                      const ushort* __restrict__ kbb,
                                                      const ushort* __restrict__ ppb,
                                                      const ushort* __restrict__ vT,
                                                      float* __restrict__ attn,
                                                      ushort* __restrict__ ctx) {
  __shared__ ushort psL[33][520];      // 34,320 B: PS rows q0..q0+32, all 512 j
  __shared__ union StU {
    ushort k2[2][32][72];              // K/pp staging per col-half
    ushort v2[2][64][40];              // V staging per col-half
    float scr[4][32];                  // softmax cross-half scratch
    float scrC[2][64][16];             // PV partial combine [band][d][q]
  } su;
  const int t = threadIdx.x, lane = t & 63, w = t >> 6;
  int bx = blockIdx.x, by = blockIdx.y;
  xcd_swz(bx, by);                     // 16 q-blocks of a z land on same XCD
  const int z = by, b = z >> 3, hh = z & 7;
  const int q0 = bx << 5;
  const int band = w >> 1, half = w & 1;
  const int lm = lane & 15, g = lane >> 4;
  const int lk = g << 3, fr4 = g << 2;
  const int C0 = half << 8;

  // A-fragments (own 16 q-rows)
  const size_t qoff = ((size_t)((b << 9) + q0 + (band << 4) + lm)) * 512 + (hh << 6);
  const bf16x8 av0 = *(const bf16x8*)&qv[qoff + lk];
  const bf16x8 av1 = *(const bf16x8*)&qv[qoff + lk + 32];
  const bf16x8 au0 = *(const bf16x8*)&qu[qoff + lk];
  const bf16x8 au1 = *(const bf16x8*)&qu[qoff + lk + 32];
  int er = q0 + 32 + lm;
  if (er > 511) er = 511;
  const size_t eoff = ((size_t)((b << 9) + er)) * 512 + (hh << 6);
  const bf16x8 e0 = *(const bf16x8*)&qv[eoff + lk];
  const bf16x8 e1 = *(const bf16x8*)&qv[eoff + lk + 32];

  // staging map for k2: 64 rows (2 halves x 32) x 64 cols; thread: row=t>>2, 16 cols
  const int srow = t >> 2, scg = (t & 3) << 4;
  const int sh = srow >> 5, sr = srow & 31;

  // ======== PS pass: psL[qq][j] = qv . pp^T ========
  {
    const ushort* pb_ = ppb + (hh << 6);
    bf16x8 r0 = *(const bf16x8*)&pb_[(size_t)((sh << 8) + sr) * 512 + scg];
    bf16x8 r1 = *(const bf16x8*)&pb_[(size_t)((sh << 8) + sr) * 512 + scg + 8];
#pragma unroll
    for (int it = 0; it < 8; ++it) {
      __syncthreads();
      *(bf16x8*)&su.k2[sh][sr][scg] = r0;
      *(bf16x8*)&su.k2[sh][sr][scg + 8] = r1;
      if (it < 7) {
        const size_t off = (size_t)((sh << 8) + ((it + 1) << 5) + sr) * 512 + scg;
        r0 = *(const bf16x8*)&pb_[off];
        r1 = *(const bf16x8*)&pb_[off + 8];
      }
      __syncthreads();
#pragma unroll
      for (int ctl = 0; ctl < 2; ++ctl) {
        const bf16x8 b0 = *(const bf16x8*)&su.k2[half][(ctl << 4) + lm][lk];
        const bf16x8 b1 = *(const bf16x8*)&su.k2[half][(ctl << 4) + lm][32 + lk];
        f32x4 a = (f32x4)(0.f);
        a = __builtin_amdgcn_mfma_f32_16x16x32_bf16(av0, b0, a, 0, 0, 0);
        a = __builtin_amdgcn_mfma_f32_16x16x32_bf16(av1, b1, a, 0, 0, 0);
        const int col = C0 + (it << 5) + (ctl << 4) + lm;
#pragma unroll
        for (int r = 0; r < 4; ++r) psL[(band << 4) + fr4 + r][col] = f2bf(a[r]);
        if (ctl == band) {  // boundary row q0+32, split between bands
          f32x4 e = (f32x4)(0.f);
          e = __builtin_amdgcn_mfma_f32_16x16x32_bf16(e0, b0, e, 0, 0, 0);
          e = __builtin_amdgcn_mfma_f32_16x16x32_bf16(e1, b1, e, 0, 0, 0);
          if (g == 0) psL[32][col] = f2bf(e[0]);
        }
      }
    }
  }

  // ======== QK pass ========
  f32x4 acc[16];
#pragma unroll
  for (int i = 0; i < 16; ++i) acc[i] = (f32x4)(0.f);
  {
    const ushort* kb_ = kbb + ((size_t)(b << 9)) * 512 + (hh << 6);
    bf16x8 r0 = *(const bf16x8*)&kb_[(size_t)((sh << 8) + sr) * 512 + scg];
    bf16x8 r1 = *(const bf16x8*)&kb_[(size_t)((sh << 8) + sr) * 512 + scg + 8];
#pragma unroll
    for (int it = 0; it < 8; ++it) {
      __syncthreads();
      *(bf16x8*)&su.k2[sh][sr][scg] = r0;
      *(bf16x8*)&su.k2[sh][sr][scg + 8] = r1;
      if (it < 7) {
        const size_t off = (size_t)((sh << 8) + ((it + 1) << 5) + sr) * 512 + scg;
        r0 = *(const bf16x8*)&kb_[off];
        r1 = *(const bf16x8*)&kb_[off + 8];
      }
      __syncthreads();
#pragma unroll
      for (int ctl = 0; ctl < 2; ++ctl) {
        const int lct = (it << 1) + ctl;
        const bf16x8 b0 = *(const bf16x8*)&su.k2[half][(ctl << 4) + lm][lk];
        const bf16x8 b1 = *(const bf16x8*)&su.k2[half][(ctl << 4) + lm][32 + lk];
        acc[lct] = __builtin_amdgcn_mfma_f32_16x16x32_bf16(au0, b0, acc[lct], 0, 0, 0);
        acc[lct] = __builtin_amdgcn_mfma_f32_16x16x32_bf16(au1, b1, acc[lct], 0, 0, 0);
      }
    }
  }
  __syncthreads();  // psL complete, k2 reads complete

  // ======== rel-shift gather + scale ========
  const float scale = 0.044194173824159216f;  // 1/sqrt(512)
  const int qq0 = (band << 4) + fr4;
#pragma unroll
  for (int lct = 0; lct < 16; ++lct) {
#pragma unroll
    for (int r = 0; r < 4; ++r) {
      const int qq = qq0 + r;
      const int q = q0 + qq;
      const int c = C0 + (lct << 4) + lm;
      float f;
      if (c <= q)          f = bf2f(psL[qq][c - q + 511]);
      else if (c == q + 1) f = 0.f;
      else                 f = bf2f(psL[qq + 1][c - q - 2]);
      acc[lct][r] = (acc[lct][r] + f) * scale;
    }
  }

  // ======== softmax (intra-wave over lm; cross-half via scr) ========
  float mx[4] = {-3.0e38f, -3.0e38f, -3.0e38f, -3.0e38f};
#pragma unroll
  for (int lct = 0; lct < 16; ++lct)
#pragma unroll
    for (int r = 0; r < 4; ++r) mx[r] = fmaxf(mx[r], acc[lct][r]);
#pragma unroll
  for (int o = 1; o < 16; o <<= 1)
#pragma unroll
    for (int r = 0; r < 4; ++r) mx[r] = fmaxf(mx[r], __shfl_xor(mx[r], o));
  if (lm == 0) {
#pragma unroll
    for (int r = 0; r < 4; ++r) su.scr[half][qq0 + r] = mx[r];
  }
  __syncthreads();
#pragma unroll
  for (int r = 0; r < 4; ++r) mx[r] = fmaxf(mx[r], su.scr[half ^ 1][qq0 + r]);
  float sme[4] = {0.f, 0.f, 0.f, 0.f};
#pragma unroll
  for (int lct = 0; lct < 16; ++lct)
#pragma unroll
    for (int r = 0; r < 4; ++r) {
      acc[lct][r] = __expf(acc[lct][r] - mx[r]);
      sme[r] += acc[lct][r];
    }
#pragma unroll
  for (int o = 1; o < 16; o <<= 1)
#pragma unroll
    for (int r = 0; r < 4; ++r) sme[r] += __shfl_xor(sme[r], o);
  if (lm == 0) {
#pragma unroll
    for (int r = 0; r < 4; ++r) su.scr[2 + half][qq0 + r] = sme[r];
  }
  __syncthreads();
#pragma unroll
  for (int r = 0; r < 4; ++r) {
    const float inv = 1.f / (sme[r] + su.scr[2 + (half ^ 1)][qq0 + r]);
#pragma unroll
    for (int lct = 0; lct < 16; ++lct) acc[lct][r] *= inv;
  }
  __syncthreads();  // all psL gather reads done -> safe to carve Pl from psL

  // ======== PV + coalesced attn write: 8 chunks of 32 c per half ========
  ushort* Pl = (ushort*)&psL[0][0] + ((band << 1) | half) * 704;  // [16][44]
  const ushort* vtb = vT + ((size_t)((b << 9) + (hh << 6))) * 512;
  const int vrow = t >> 1, vc = (t & 1) << 4;
  const int vh = vrow >> 6, vd = vrow & 63;
  float* abase = attn + ((size_t)z << 18);
  f32x4 acc2[4];
#pragma unroll
  for (int i = 0; i < 4; ++i) acc2[i] = (f32x4)(0.f);
  bf16x8 p0 = *(const bf16x8*)&vtb[(size_t)vd * 512 + (vh << 8) + vc];
  bf16x8 p1 = *(const bf16x8*)&vtb[(size_t)vd * 512 + (vh << 8) + vc + 8];
#pragma unroll
  for (int ch = 0; ch < 8; ++ch) {
    // P chunk -> Pl (wave-private)
#pragma unroll
    for (int ctl = 0; ctl < 2; ++ctl) {
      const int lct = (ch << 1) + ctl;
#pragma unroll
      for (int r = 0; r < 4; ++r)
        Pl[(fr4 + r) * 44 + (ctl << 4) + lm] = f2bf(acc[lct][r]);
    }
    __syncthreads();  // prev v2 reads done
    *(bf16x8*)&su.v2[vh][vd][vc] = p0;
    *(bf16x8*)&su.v2[vh][vd][vc + 8] = p1;
    if (ch < 7) {
      const size_t off = (size_t)vd * 512 + (vh << 8) + ((ch + 1) << 5) + vc;
      p0 = *(const bf16x8*)&vtb[off];
      p1 = *(const bf16x8*)&vtb[off + 8];
    }
    // attn write from Pl (float4, coalesced within rows)
    {
      const int row = lane >> 2, colg = (lane & 3) << 3;
      const ushort* ps = Pl + row * 44 + colg;
      float* ar = abase + (size_t)(q0 + (band << 4) + row) * 512 + C0 + (ch << 5) + colg;
      float4 o0, o1;
      o0.x = bf2f(ps[0]); o0.y = bf2f(ps[1]); o0.z = bf2f(ps[2]); o0.w = bf2f(ps[3]);
      o1.x = bf2f(ps[4]); o1.y = bf2f(ps[5]); o1.z = bf2f(ps[6]); o1.w = bf2f(ps[7]);
      *(float4*)&ar[0] = o0;
      *(float4*)&ar[4] = o1;
    }
    __syncthreads();  // v2 ready
#pragma unroll
    for (int dt = 0; dt < 4; ++dt) {
      const bf16x8 va = *(const bf16x8*)&su.v2[half][(dt << 4) + lm][lk];
      const bf16x8 pbf = *(const bf16x8*)&Pl[lm * 44 + lk];
      acc2[dt] = __builtin_amdgcn_mfma_f32_16x16x32_bf16(va, pbf, acc2[dt], 0, 0, 0);
    }
  }
  // combine col-half partials via scrC, then write ctx
  __syncthreads();
  if (half == 1) {
#pragma unroll
    for (int dt = 0; dt < 4; ++dt)
#pragma unroll
      for (int r = 0; r < 4; ++r)
        su.scrC[band][(dt << 4) + fr4 + r][lm] = acc2[dt][r];
  }
  __syncthreads();
  if (half == 0) {
    const int qq2 = q0 + (band << 4) + lm;
#pragma unroll
    for (int dt = 0; dt < 4; ++dt) {
      ushort4 o;
      o.x = f2bf(acc2[dt][0] + su.scrC[band][(dt << 4) + fr4 + 0][lm]);
      o.y = f2bf(acc2[dt][1] + su.scrC[band][(dt << 4) + fr4 + 1][lm]);
      o.z = f2bf(acc2[dt][2] + su.scrC[band][(dt << 4) + fr4 + 2][lm]);
      o.w = f2bf(acc2[dt][3] + su.scrC[band][(dt << 4) + fr4 + 3][lm]);
      *(ushort4*)&ctx[((size_t)((b << 9) + qq2)) * 512 + (hh << 6) + (dt << 4) + fr4] = o;
    }
  }
}

// ------------- depthwise conv (K=31) + BN + swish, register sliding window ------
__global__ __launch_bounds__(256) void dwconv2(const ushort* __restrict__ in,
                                               const float* __restrict__ w,
                                               const float* __restrict__ bng,
                                               const float* __restrict__ bnb,
                                               const float* __restrict__ bnm,
                                               const float* __restrict__ bnv,
                                               ushort* __restrict__ out) {
  __shared__ float wl[31][128];
  const int t = threadIdx.x;
  const int dbase = blockIdx.x << 7;
  const int b = blockIdx.z;
  const int sb = (blockIdx.y << 6) + ((t >> 6) << 4);
  if (t < 128) {
    const float* ws = &w[(dbase + t) * 31];
#pragma unroll
    for (int k = 0; k < 31; ++k) wl[k][t] = ws[k];
  }
  __syncthreads();
  const int dl = (t & 63) << 1;
  const int d = dbase + dl;
  const size_t base = (((size_t)b) << 18) + d;
  float2 win[46];
#pragma unroll
  for (int i = 0; i < 46; ++i) {
    const int s = sb - 15 + i;
    if (s >= 0 && s < 512) {
      const ushort2 u = *(const ushort2*)&in[base + ((size_t)s << 9)];
      win[i].x = bf2f(u.x); win[i].y = bf2f(u.y);
    } else {
      win[i].x = 0.f; win[i].y = 0.f;
    }
  }
  float2 acc[16];
#pragma unroll
  for (int p = 0; p < 16; ++p) { acc[p].x = 0.f; acc[p].y = 0.f; }
#pragma unroll
  for (int k = 0; k < 31; ++k) {
    const float2 w2 = *(const float2*)&wl[k][dl];
#pragma unroll
    for (int p = 0; p < 16; ++p) {
      acc[p].x = fmaf(win[p + k].x, w2.x, acc[p].x);
      acc[p].y = fmaf(win[p + k].y, w2.y, acc[p].y);
    }
  }
  const float g0 = bng[d] * rsqrtf(bnv[d] + EPSF);
  const float g1 = bng[d + 1] * rsqrtf(bnv[d + 1] + EPSF);
  const float m0 = bnm[d], m1 = bnm[d + 1];
  const float bb0 = bnb[d], bb1 = bnb[d + 1];
#pragma unroll
  for (int p = 0; p < 16; ++p) {
    float v0 = (acc[p].x - m0) * g0 + bb0;
    float v1 = (acc[p].y - m1) * g1 + bb1;
    v0 = v0 * sigmf(v0);
    v1 = v1 * sigmf(v1);
    ushort2 o;
    o.x = f2bf(v0); o.y = f2bf(v1);
    *(ushort2*)&out[base + ((size_t)(sb + p) << 9)] = o;
  }
}

extern "C" void kernel_launch(void* const* d_in, const int* in_sizes, int n_in,
                              void* d_out, int out_size, void* d_ws, size_t ws_size,
                              hipStream_t stream) {
  const float* x      = (const float*)d_in[0];
  const float* ff1_g  = (const float*)d_in[1];
  const float* ff1_b  = (const float*)d_in[2];
  const float* ff1_w1 = (const float*)d_in[3];
  const float* ff1_b1 = (const float*)d_in[4];
  const float* ff1_w2 = (const float*)d_in[5];
  const float* ff1_b2 = (const float*)d_in[6];
  const float* attn_g = (const float*)d_in[7];
  const float* attn_b = (const float*)d_in[8];
  const float* wq     = (const float*)d_in[9];
  const float* bq     = (const float*)d_in[10];
  const float* wk     = (const float*)d_in[11];
  const float* bk     = (const float*)d_in[12];
  const float* wv     = (const float*)d_in[13];
  const float* bv     = (const float*)d_in[14];
  const float* wpos   = (const float*)d_in[15];
  const float* u_bias = (const float*)d_in[16];
  const float* v_bias = (const float*)d_in[17];
  const float* wo     = (const float*)d_in[18];
  const float* bo     = (const float*)d_in[19];
  const float* conv_g = (const float*)d_in[20];
  const float* conv_b = (const float*)d_in[21];
  const float* pw1_w  = (const float*)d_in[22];
  const float* pw1_b  = (const float*)d_in[23];
  const float* dw_w   = (const float*)d_in[24];
  const float* bn_g   = (const float*)d_in[25];
  const float* bn_b   = (const float*)d_in[26];
  const float* bn_m   = (const float*)d_in[27];
  const float* bn_v   = (const float*)d_in[28];
  const float* pw2_w  = (const float*)d_in[29];
  const float* pw2_b  = (const float*)d_in[30];
  const float* ff2_g  = (const float*)d_in[31];
  const float* ff2_b  = (const float*)d_in[32];
  const float* ff2_w1 = (const float*)d_in[33];
  const float* ff2_b1 = (const float*)d_in[34];
  const float* ff2_w2 = (const float*)d_in[35];
  const float* ff2_b2 = (const float*)d_in[36];
  const float* ln_g   = (const float*)d_in[37];
  const float* ln_b   = (const float*)d_in[38];

  float* out  = (float*)d_out;            // [B,S,D] f32
  float* attn = out + ND;                 // [B,H,S,S] f32

  float*  res  = (float*)d_ws;
  ushort* ybf  = (ushort*)(res + ND);
  float*  big  = (float*)(ybf + ND);             // 2*ND f32 region
  ushort* vT   = (ushort*)(big + 2 * ND);        // ND ushorts [b][col][s]
  ushort* dwbf = vT + ND;                        // ND ushorts
  ushort* wts  = dwbf + ND;                      // 6,291,456 ushorts
  ushort* pebf = wts + 6291456;                  // 262,144
  ushort* ppbf = pebf + 262144;                  // 262,144

  ushort* ffmid = (ushort*)big;
  ushort* qu    = (ushort*)big;
  ushort* qv    = qu + ND;
  ushort* kbb   = qv + ND;
  ushort* ctxbf = ybf;
  ushort* glubf = (ushort*)big;

  ushort* ff1w1t = wts;
  ushort* ff1w2t = wts + 1048576;
  ushort* wqt    = wts + 2097152;
  ushort* wkt    = wts + 2359296;
  ushort* wvt    = wts + 2621440;
  ushort* wot    = wts + 2883584;
  ushort* pw1t   = wts + 3145728;
  ushort* pw2t   = wts + 3670016;
  ushort* ff2w1t = wts + 3932160;
  ushort* ff2w2t = wts + 4980736;
  ushort* wpost  = wts + 6029312;

  const dim3 blk(256);

  // ---- weight prep: single merged transpose dispatch ----
  TpArgs ta;
  auto set = [&](int i, const float* s, ushort* d, int K, int N) {
    ta.src[i] = s; ta.dst[i] = d; ta.K[i] = K; ta.N[i] = N;
  };
  set(0, ff1_w1, ff1w1t, 512, 2048);
  set(1, ff1_w2, ff1w2t, 2048, 512);
  set(2, wq, wqt, 512, 512);
  set(3, wk, wkt, 512, 512);
  set(4, wv, wvt, 512, 512);
  set(5, wo, wot, 512, 512);
  set(6, wpos, wpost, 512, 512);
  set(7, pw1_w, pw1t, 512, 1024);
  set(8, pw2_w, pw2t, 512, 512);
  set(9, ff2_w1, ff2w1t, 512, 2048);
  set(10, ff2_w2, ff2w2t, 2048, 512);
  int tacc = 0;
  for (int i = 0; i < 11; ++i) { ta.base[i] = tacc; tacc += (ta.N[i] >> 5) * (ta.K[i] >> 5); }
  ta.base[11] = tacc;
  transpose_all<<<tacc, blk, 0, stream>>>(ta);
  pe_kernel_bf16<<<512, blk, 0, stream>>>(pebf);
  gemm_bf16<0, 0, 0, 1><<<dim3(4, 4), blk, 0, stream>>>(pebf, wpost, nullptr, nullptr, ppbf,
                                                        512, 512, 512);

  // ---- Macaron FF1: res = x + 0.5*FF(LN(x)) ----
  ln_bf16<<<NTOK / 4, blk, 0, stream>>>(x, ff1_g, ff1_b, ybf);
  gemm_bf16<1, 0, 1, 1><<<dim3(16, 128), blk, 0, stream>>>(ybf, ff1w1t, ff1_b1, nullptr, ffmid,
                                                           NTOK, 512, 2048);
  gemm_bf16<0, 2, 1, 0><<<dim3(4, 128), blk, 0, stream>>>(ffmid, ff1w2t, ff1_b2, x, res,
                                                          NTOK, 2048, 512);

  // ---- Attention ----
  ln_bf16<<<NTOK / 4, blk, 0, stream>>>(res, attn_g, attn_b, ybf);
  gemm_qkv<<<dim3(12, 128), blk, 0, stream>>>(ybf, wqt, bq, bk, bv, u_bias, v_bias,
                                              qu, qv, kbb, vT, NTOK, 512);
  attn_fused6<<<dim3(16, 256), blk, 0, stream>>>(qu, qv, kbb, ppbf, vT, attn, ctxbf);
  gemm_bf16<0, 1, 1, 0><<<dim3(4, 128), blk, 0, stream>>>(ctxbf, wot, bo, res, res,
                                                          NTOK, 512, 512);

  // ---- Conv module ----
  ln_bf16<<<NTOK / 4, blk, 0, stream>>>(res, conv_g, conv_b, ybf);
  gemm_glu<<<dim3(4, 128), blk, 0, stream>>>(ybf, pw1t, pw1_b, glubf, NTOK, 512);
  dwconv2<<<dim3(4, 8, 32), blk, 0, stream>>>(glubf, dw_w, bn_g, bn_b, bn_m, bn_v, dwbf);
  gemm_bf16<0, 1, 1, 0><<<dim3(4, 128), blk, 0, stream>>>(dwbf, pw2t, pw2_b, res, res,
                                                          NTOK, 512, 512);

  // ---- Macaron FF2 + final LN ----
  ln_bf16<<<NTOK / 4, blk, 0, stream>>>(res, ff2_g, ff2_b, ybf);
  gemm_bf16<1, 0, 1, 1><<<dim3(16, 128), blk, 0, stream>>>(ybf, ff2w1t, ff2_b1, nullptr, ffmid,
                                                           NTOK, 512, 2048);
  gemm_bf16<0, 2, 1, 0><<<dim3(4, 128), blk, 0, stream>>>(ffmid, ff2w2t, ff2_b2, res, res,
                                                          NTOK, 2048, 512);
  ln_f32<<<NTOK / 4, blk, 0, stream>>>(res, ln_g, ln_b, out);
}

// Round 10
// 730.404 us; speedup vs baseline: 1.3158x; 1.0042x over previous
//
#include <hip/hip_runtime.h>
#include <cstddef>
#include <cstdint>

#define EPSF 1e-5f

constexpr int BB = 32, SS = 512, DD = 512, HH = 8, DH = 64;
constexpr int NTOK = BB * SS;              // 16384 rows
constexpr size_t ND = (size_t)NTOK * DD;   // 8,388,608

typedef __attribute__((ext_vector_type(8))) short bf16x8;
typedef __attribute__((ext_vector_type(4))) float f32x4;

__device__ __forceinline__ float sigmf(float v) { return 1.f / (1.f + __expf(-v)); }

__device__ __forceinline__ ushort f2bf(float f) {
  union { float f; uint32_t u; } x{f};
  uint32_t r = x.u + 0x7FFF + ((x.u >> 16) & 1);
  return (ushort)(r >> 16);
}
__device__ __forceinline__ float bf2f(ushort u) {
  union { uint32_t u; float f; } x{(uint32_t)u << 16};
  return x.f;
}

__device__ __forceinline__ void gload16(const ushort* g, ushort* ldsbase) {
  __builtin_amdgcn_global_load_lds((const __attribute__((address_space(1))) void*)g,
                                   (__attribute__((address_space(3))) void*)ldsbase, 16, 0, 0);
}

// bijective XCD-chunk swizzle (m204); requires nwg % 8 == 0.
__device__ __forceinline__ void xcd_swz(int& bx, int& by) {
  const int gx = gridDim.x;
  const int nwg = gx * gridDim.y;
  const int cpx = nwg >> 3;
  int id = by * gx + bx;
  id = (id & 7) * cpx + (id >> 3);
  bx = id % gx;
  by = id / gx;
}

// ---------------- LayerNorm: one wave per row, f32 out --------------------------
__global__ __launch_bounds__(256) void ln_f32(const float* __restrict__ x,
                                              const float* __restrict__ g,
                                              const float* __restrict__ b,
                                              float* __restrict__ y) {
  const int lane = threadIdx.x & 63;
  const int row = blockIdx.x * 4 + (threadIdx.x >> 6);
  const float* xr = x + (size_t)row * 512;
  const float4 v0 = *(const float4*)&xr[lane << 2];
  const float4 v1 = *(const float4*)&xr[256 + (lane << 2)];
  float s = v0.x + v0.y + v0.z + v0.w + v1.x + v1.y + v1.z + v1.w;
#pragma unroll
  for (int o = 32; o > 0; o >>= 1) s += __shfl_xor(s, o);
  const float mean = s * (1.f / 512.f);
  float q = 0.f;
  q += (v0.x - mean) * (v0.x - mean); q += (v0.y - mean) * (v0.y - mean);
  q += (v0.z - mean) * (v0.z - mean); q += (v0.w - mean) * (v0.w - mean);
  q += (v1.x - mean) * (v1.x - mean); q += (v1.y - mean) * (v1.y - mean);
  q += (v1.z - mean) * (v1.z - mean); q += (v1.w - mean) * (v1.w - mean);
#pragma unroll
  for (int o = 32; o > 0; o >>= 1) q += __shfl_xor(q, o);
  const float rs = rsqrtf(q * (1.f / 512.f) + EPSF);
  const float4 g0 = *(const float4*)&g[lane << 2];
  const float4 g1 = *(const float4*)&g[256 + (lane << 2)];
  const float4 b0 = *(const float4*)&b[lane << 2];
  const float4 b1 = *(const float4*)&b[256 + (lane << 2)];
  float* yr = y + (size_t)row * 512;
  float4 o0, o1;
  o0.x = (v0.x - mean) * rs * g0.x + b0.x; o0.y = (v0.y - mean) * rs * g0.y + b0.y;
  o0.z = (v0.z - mean) * rs * g0.z + b0.z; o0.w = (v0.w - mean) * rs * g0.w + b0.w;
  o1.x = (v1.x - mean) * rs * g1.x + b1.x; o1.y = (v1.y - mean) * rs * g1.y + b1.y;
  o1.z = (v1.z - mean) * rs * g1.z + b1.z; o1.w = (v1.w - mean) * rs * g1.w + b1.w;
  *(float4*)&yr[lane << 2] = o0;
  *(float4*)&yr[256 + (lane << 2)] = o1;
}

// ---------------- LayerNorm writing bf16 ----------------------------------------
__global__ __launch_bounds__(256) void ln_bf16(const float* __restrict__ x,
                                               const float* __restrict__ g,
                                               const float* __restrict__ b,
                                               ushort* __restrict__ y) {
  const int lane = threadIdx.x & 63;
  const int row = blockIdx.x * 4 + (threadIdx.x >> 6);
  const float* xr = x + (size_t)row * 512;
  const float4 v0 = *(const float4*)&xr[lane << 2];
  const float4 v1 = *(const float4*)&xr[256 + (lane << 2)];
  float s = v0.x + v0.y + v0.z + v0.w + v1.x + v1.y + v1.z + v1.w;
#pragma unroll
  for (int o = 32; o > 0; o >>= 1) s += __shfl_xor(s, o);
  const float mean = s * (1.f / 512.f);
  float q = 0.f;
  q += (v0.x - mean) * (v0.x - mean); q += (v0.y - mean) * (v0.y - mean);
  q += (v0.z - mean) * (v0.z - mean); q += (v0.w - mean) * (v0.w - mean);
  q += (v1.x - mean) * (v1.x - mean); q += (v1.y - mean) * (v1.y - mean);
  q += (v1.z - mean) * (v1.z - mean); q += (v1.w - mean) * (v1.w - mean);
#pragma unroll
  for (int o = 32; o > 0; o >>= 1) q += __shfl_xor(q, o);
  const float rs = rsqrtf(q * (1.f / 512.f) + EPSF);
  const float4 g0 = *(const float4*)&g[lane << 2];
  const float4 g1 = *(const float4*)&g[256 + (lane << 2)];
  const float4 b0 = *(const float4*)&b[lane << 2];
  const float4 b1 = *(const float4*)&b[256 + (lane << 2)];
  ushort* yr = y + (size_t)row * 512;
  ushort4 o0, o1;
  o0.x = f2bf((v0.x - mean) * rs * g0.x + b0.x); o0.y = f2bf((v0.y - mean) * rs * g0.y + b0.y);
  o0.z = f2bf((v0.z - mean) * rs * g0.z + b0.z); o0.w = f2bf((v0.w - mean) * rs * g0.w + b0.w);
  o1.x = f2bf((v1.x - mean) * rs * g1.x + b1.x); o1.y = f2bf((v1.y - mean) * rs * g1.y + b1.y);
  o1.z = f2bf((v1.z - mean) * rs * g1.z + b1.z); o1.w = f2bf((v1.w - mean) * rs * g1.w + b1.w);
  *(ushort4*)&yr[lane << 2] = o0;
  *(ushort4*)&yr[256 + (lane << 2)] = o1;
}

// ---------------- merged weight transpose: 11 segments, one dispatch ------------
struct TpArgs {
  const float* src[11];
  ushort* dst[11];
  int K[11];
  int N[11];
  int base[12];
};

__global__ __launch_bounds__(256) void transpose_all(TpArgs a) {
  __shared__ float tile[32][33];
  int s = 0;
  const int bid = blockIdx.x;
  while (s < 10 && bid >= a.base[s + 1]) ++s;
  const int r = bid - a.base[s];
  const int K = a.K[s], N = a.N[s];
  const int ntx = N >> 5;
  const int n0 = (r % ntx) << 5;
  const int k0 = (r / ntx) << 5;
  const float* in = a.src[s];
  ushort* out = a.dst[s];
  const int tx = threadIdx.x & 31, ty = threadIdx.x >> 5;
#pragma unroll
  for (int i = 0; i < 32; i += 8)
    tile[ty + i][tx] = in[(size_t)(k0 + ty + i) * N + n0 + tx];
  __syncthreads();
#pragma unroll
  for (int i = 0; i < 32; i += 8)
    out[(size_t)(n0 + ty + i) * K + k0 + tx] = f2bf(tile[tx][ty + i]);
}

// ---------------- bf16 MFMA GEMM, T3-minimum 2-phase double-buffer --------------
template <int ACT, int RES, int HB, int OBF>
__global__ __launch_bounds__(256) void gemm_bf16(const ushort* __restrict__ A,
                                                 const ushort* __restrict__ Wt,
                                                 const float* __restrict__ bias,
                                                 const float* __restrict__ res,
                                                 void* __restrict__ Cv,
                                                 int M, int K, int N) {
  __shared__ ushort Al[2][8192];
  __shared__ ushort Bl[2][8192];
  const int t = threadIdx.x;
  const int lane = t & 63;
  const int w = t >> 6;
  const int wr = (w >> 1) << 6, wc = (w & 1) << 6;
  int bx = blockIdx.x, by = blockIdx.y;
  xcd_swz(bx, by);
  const int m0 = by << 7, n0 = bx << 7;
  const int lm = lane & 15;
  const int grow = lane >> 3;
  const int gcol = (lane & 7) << 3;

  f32x4 acc[4][4];
#pragma unroll
  for (int i = 0; i < 4; ++i)
#pragma unroll
    for (int j = 0; j < 4; ++j) acc[i][j] = (f32x4)(0.f);

  const int NT = K >> 6;
#pragma unroll
  for (int i = 0; i < 4; ++i) {
    const int s = (w << 2) + i;
    gload16(A + (size_t)(m0 + (s << 3) + grow) * K + gcol, &Al[0][s << 9]);
    gload16(Wt + (size_t)(n0 + (s << 3) + grow) * K + gcol, &Bl[0][s << 9]);
  }
  __syncthreads();
  int cur = 0;
  for (int tt = 0; tt < NT; ++tt) {
    if (tt + 1 < NT) {
      const int k0 = (tt + 1) << 6;
#pragma unroll
      for (int i = 0; i < 4; ++i) {
        const int s = (w << 2) + i;
        gload16(A + (size_t)(m0 + (s << 3) + grow) * K + k0 + gcol, &Al[cur ^ 1][s << 9]);
        gload16(Wt + (size_t)(n0 + (s << 3) + grow) * K + k0 + gcol, &Bl[cur ^ 1][s << 9]);
      }
    }
#pragma unroll
    for (int ks = 0; ks < 2; ++ks) {
      const int kof = (ks << 5) + ((lane >> 4) << 3);
      bf16x8 af[4], bfr[4];
#pragma unroll
      for (int i = 0; i < 4; ++i) af[i] = *(const bf16x8*)&Al[cur][(wr + (i << 4) + lm) * 64 + kof];
#pragma unroll
      for (int j = 0; j < 4; ++j) bfr[j] = *(const bf16x8*)&Bl[cur][(wc + (j << 4) + lm) * 64 + kof];
#pragma unroll
      for (int i = 0; i < 4; ++i)
#pragma unroll
        for (int j = 0; j < 4; ++j)
          acc[i][j] = __builtin_amdgcn_mfma_f32_16x16x32_bf16(af[i], bfr[j], acc[i][j], 0, 0, 0);
    }
    __syncthreads();
    cur ^= 1;
  }

  float bb[4] = {0.f, 0.f, 0.f, 0.f};
  if (HB) {
#pragma unroll
    for (int j = 0; j < 4; ++j) bb[j] = bias[n0 + wc + j * 16 + lm];
  }
  const int rbase = m0 + wr + ((lane >> 4) << 2);
#pragma unroll
  for (int i = 0; i < 4; ++i) {
#pragma unroll
    for (int r = 0; r < 4; ++r) {
      const size_t row = (size_t)(rbase + i * 16 + r);
#pragma unroll
      for (int j = 0; j < 4; ++j) {
        const int col = n0 + wc + j * 16 + lm;
        float v = acc[i][j][r] + bb[j];
        if (ACT == 1) v = v * sigmf(v);
        if (RES == 1) v += res[row * N + col];
        else if (RES == 2) v = res[row * N + col] + 0.5f * v;
        if (OBF) ((ushort*)Cv)[row * N + col] = f2bf(v);
        else ((float*)Cv)[row * N + col] = v;
      }
    }
  }
}

// ---------------- merged QKV projection: N=1536, routed epilogue ----------------
__global__ __launch_bounds__(256) void gemm_qkv(const ushort* __restrict__ A,
                                                const ushort* __restrict__ Wt,
                                                const float* __restrict__ bq,
                                                const float* __restrict__ bk,
                                                const float* __restrict__ bv,
                                                const float* __restrict__ ub,
                                                const float* __restrict__ vb,
                                                ushort* __restrict__ qu,
                                                ushort* __restrict__ qv,
                                                ushort* __restrict__ kbb,
                                                ushort* __restrict__ vT,
                                                int M, int K) {
  __shared__ ushort Al[2][8192];
  __shared__ ushort Bl[2][8192];
  const int t = threadIdx.x;
  const int lane = t & 63;
  const int w = t >> 6;
  const int wr = (w >> 1) << 6, wc = (w & 1) << 6;
  int bx = blockIdx.x, by = blockIdx.y;
  xcd_swz(bx, by);
  const int m0 = by << 7, n0 = bx << 7;
  const int lm = lane & 15;
  const int grow = lane >> 3;
  const int gcol = (lane & 7) << 3;
  f32x4 acc[4][4];
#pragma unroll
  for (int i = 0; i < 4; ++i)
#pragma unroll
    for (int j = 0; j < 4; ++j) acc[i][j] = (f32x4)(0.f);
  const int NT = K >> 6;
#pragma unroll
  for (int i = 0; i < 4; ++i) {
    const int s = (w << 2) + i;
    gload16(A + (size_t)(m0 + (s << 3) + grow) * K + gcol, &Al[0][s << 9]);
    gload16(Wt + (size_t)(n0 + (s << 3) + grow) * K + gcol, &Bl[0][s << 9]);
  }
  __syncthreads();
  int cur = 0;
  for (int tt = 0; tt < NT; ++tt) {
    if (tt + 1 < NT) {
      const int k0 = (tt + 1) << 6;
#pragma unroll
      for (int i = 0; i < 4; ++i) {
        const int s = (w << 2) + i;
        gload16(A + (size_t)(m0 + (s << 3) + grow) * K + k0 + gcol, &Al[cur ^ 1][s << 9]);
        gload16(Wt + (size_t)(n0 + (s << 3) + grow) * K + k0 + gcol, &Bl[cur ^ 1][s << 9]);
      }
    }
#pragma unroll
    for (int ks = 0; ks < 2; ++ks) {
      const int kof = (ks << 5) + ((lane >> 4) << 3);
      bf16x8 af[4], bfr[4];
#pragma unroll
      for (int i = 0; i < 4; ++i) af[i] = *(const bf16x8*)&Al[cur][(wr + (i << 4) + lm) * 64 + kof];
#pragma unroll
      for (int j = 0; j < 4; ++j) bfr[j] = *(const bf16x8*)&Bl[cur][(wc + (j << 4) + lm) * 64 + kof];
#pragma unroll
      for (int i = 0; i < 4; ++i)
#pragma unroll
        for (int j = 0; j < 4; ++j)
          acc[i][j] = __builtin_amdgcn_mfma_f32_16x16x32_bf16(af[i], bfr[j], acc[i][j], 0, 0, 0);
    }
    __syncthreads();
    cur ^= 1;
  }
  const int seg = n0 >> 9;                 // block-uniform: 0=q, 1=k, 2=v
  const int nloc = n0 & 511;
  const float* bsel = (seg == 0) ? bq : (seg == 1 ? bk : bv);
  float bb[4], uu[4], vv[4];
#pragma unroll
  for (int j = 0; j < 4; ++j) {
    const int col = nloc + wc + j * 16 + lm;
    bb[j] = bsel[col];
    if (seg == 0) { uu[j] = ub[col]; vv[j] = vb[col]; }
  }
  const int rbase = m0 + wr + ((lane >> 4) << 2);
  if (seg == 2) {
    const int bloc = m0 >> 9;
    const int sbase = rbase - (bloc << 9);
#pragma unroll
    for (int i = 0; i < 4; ++i) {
#pragma unroll
      for (int j = 0; j < 4; ++j) {
        const int col = nloc + wc + j * 16 + lm;
        ushort4 o;
        o.x = f2bf(acc[i][j][0] + bb[j]);
        o.y = f2bf(acc[i][j][1] + bb[j]);
        o.z = f2bf(acc[i][j][2] + bb[j]);
        o.w = f2bf(acc[i][j][3] + bb[j]);
        *(ushort4*)&vT[((size_t)((bloc << 9) + col)) * 512 + sbase + i * 16] = o;
      }
    }
    return;
  }
#pragma unroll
  for (int i = 0; i < 4; ++i) {
#pragma unroll
    for (int r = 0; r < 4; ++r) {
      const size_t row = (size_t)(rbase + i * 16 + r);
#pragma unroll
      for (int j = 0; j < 4; ++j) {
        const int col = nloc + wc + j * 16 + lm;
        const float v = acc[i][j][r] + bb[j];
        if (seg == 0) {
          qu[row * 512 + col] = f2bf(v + uu[j]);
          qv[row * 512 + col] = f2bf(v + vv[j]);
        } else {
          kbb[row * 512 + col] = f2bf(v);
        }
      }
    }
  }
}

// ---------------- pw1 + GLU fused ----------------------------------------------
__global__ __launch_bounds__(256) void gemm_glu(const ushort* __restrict__ A,
                                                const ushort* __restrict__ Wt,
                                                const float* __restrict__ bias,
                                                ushort* __restrict__ Cout,
                                                int M, int K) {
  __shared__ ushort Al[8192];
  __shared__ ushort Ba[8192];
  __shared__ ushort Bg[8192];
  const int t = threadIdx.x;
  const int lane = t & 63;
  const int w = t >> 6;
  const int wr = (w >> 1) << 6, wc = (w & 1) << 6;
  int bx = blockIdx.x, by = blockIdx.y;
  xcd_swz(bx, by);
  const int m0 = by << 7, n0 = bx << 7;
  const int lm = lane & 15;
  const int grow = lane >> 3;
  const int gcol = (lane & 7) << 3;
  const ushort* WtA = Wt;
  const ushort* WtG = Wt + (size_t)512 * 512;
  f32x4 acca[4][4], accg[4][4];
#pragma unroll
  for (int i = 0; i < 4; ++i)
#pragma unroll
    for (int j = 0; j < 4; ++j) { acca[i][j] = (f32x4)(0.f); accg[i][j] = (f32x4)(0.f); }
  const int NT = K >> 6;
  for (int tt = 0; tt < NT; ++tt) {
    const int k0 = tt << 6;
    if (tt) __syncthreads();
#pragma unroll
    for (int i = 0; i < 4; ++i) {
      const int s = (w << 2) + i;
      gload16(A + (size_t)(m0 + (s << 3) + grow) * K + k0 + gcol, &Al[s << 9]);
      gload16(WtA + (size_t)(n0 + (s << 3) + grow) * K + k0 + gcol, &Ba[s << 9]);
      gload16(WtG + (size_t)(n0 + (s << 3) + grow) * K + k0 + gcol, &Bg[s << 9]);
    }
    __syncthreads();
#pragma unroll
    for (int ks = 0; ks < 2; ++ks) {
      const int kof = (ks << 5) + ((lane >> 4) << 3);
      bf16x8 af[4], ba4[4], bg4[4];
#pragma unroll
      for (int i = 0; i < 4; ++i) af[i] = *(const bf16x8*)&Al[(wr + (i << 4) + lm) * 64 + kof];
#pragma unroll
      for (int j = 0; j < 4; ++j) {
        ba4[j] = *(const bf16x8*)&Ba[(wc + (j << 4) + lm) * 64 + kof];
        bg4[j] = *(const bf16x8*)&Bg[(wc + (j << 4) + lm) * 64 + kof];
      }
#pragma unroll
      for (int i = 0; i < 4; ++i)
#pragma unroll
        for (int j = 0; j < 4; ++j) {
          acca[i][j] = __builtin_amdgcn_mfma_f32_16x16x32_bf16(af[i], ba4[j], acca[i][j], 0, 0, 0);
          accg[i][j] = __builtin_amdgcn_mfma_f32_16x16x32_bf16(af[i], bg4[j], accg[i][j], 0, 0, 0);
        }
    }
  }
  float bba[4], bbg[4];
#pragma unroll
  for (int j = 0; j < 4; ++j) {
    const int col = n0 + wc + j * 16 + lm;
    bba[j] = bias[col];
    bbg[j] = bias[512 + col];
  }
  const int rbase = m0 + wr + ((lane >> 4) << 2);
#pragma unroll
  for (int i = 0; i < 4; ++i) {
#pragma unroll
    for (int r = 0; r < 4; ++r) {
      const size_t row = (size_t)(rbase + i * 16 + r);
#pragma unroll
      for (int j = 0; j < 4; ++j) {
        const int col = n0 + wc + j * 16 + lm;
        const float va = acca[i][j][r] + bba[j];
        const float vg = accg[i][j][r] + bbg[j];
        Cout[row * 512 + col] = f2bf(va * sigmf(vg));
      }
    }
  }
}

// ------------- Sinusoidal PE (bf16) ---------------------------------------------
__global__ void pe_kernel_bf16(ushort* __restrict__ pe) {
  const int pos = blockIdx.x, ii = threadIdx.x;
  const float ang = (float)pos * powf(10000.f, -(float)(2 * ii) / 512.f);
  pe[((size_t)pos << 9) + 2 * ii] = f2bf(sinf(ang));
  pe[((size_t)pos << 9) + 2 * ii + 1] = f2bf(cosf(ang));
}

// ------------- fused attention v7: merged PS+QK staging (half the barriers) -----
// grid (16, 256). LDS = psL 34.3KB + pk 18.4KB = 52.7KB -> 3 blocks/CU.
__global__ __launch_bounds__(256, 3) void attn_fused7(const ushort* __restrict__ qu,
                                                      const ushort* __restrict__ qv,
                                                      const ushort* __restrict__ kbb,
                                                      const ushort* __restrict__ ppb,
                                                      const ushort* __restrict__ vT,
                                                      float* __restrict__ attn,
                                                      ushort* __restrict__ ctx) {
  __shared__ ushort psL[33][520];      // 34,320 B: PS rows q0..q0+32, all 512 j
  __shared__ union StU {
    struct { ushort p[2][32][72]; ushort k[2][32][72]; } pk;  // 18,432 B
    ushort v2[2][64][40];              // V staging per col-half
    float scr[4][32];                  // softmax cross-half scratch
    float scrC[2][64][16];             // PV partial combine [band][d][q]
  } su;
  const int t = threadIdx.x, lane = t & 63, w = t >> 6;
  int bx = blockIdx.x, by = blockIdx.y;
  xcd_swz(bx, by);                     // 16 q-blocks of a z land on same XCD
  const int z = by, b = z >> 3, hh = z & 7;
  const int q0 = bx << 5;
  const int band = w >> 1, half = w & 1;
  const int lm = lane & 15, g = lane >> 4;
  const int lk = g << 3, fr4 = g << 2;
  const int C0 = half << 8;

  // A-fragments (own 16 q-rows)
  const size_t qoff = ((size_t)((b << 9) + q0 + (band << 4) + lm)) * 512 + (hh << 6);
  const bf16x8 av0 = *(const bf16x8*)&qv[qoff + lk];
  const bf16x8 av1 = *(const bf16x8*)&qv[qoff + lk + 32];
  const bf16x8 au0 = *(const bf16x8*)&qu[qoff + lk];
  const bf16x8 au1 = *(const bf16x8*)&qu[qoff + lk + 32];
  int er = q0 + 32 + lm;
  if (er > 511) er = 511;
  const size_t eoff = ((size_t)((b << 9) + er)) * 512 + (hh << 6);
  const bf16x8 e0 = *(const bf16x8*)&qv[eoff + lk];
  const bf16x8 e1 = *(const bf16x8*)&qv[eoff + lk + 32];

  // staging map: 64 rows (2 halves x 32) x 64 cols per array; thread: row=t>>2
  const int srow = t >> 2, scg = (t & 3) << 4;
  const int sh = srow >> 5, sr = srow & 31;

  // ======== merged PS + QK pass: stage pp-tile AND K-tile per iteration ========
  f32x4 acc[16];
#pragma unroll
  for (int i = 0; i < 16; ++i) acc[i] = (f32x4)(0.f);
  {
    const ushort* pb_ = ppb + (hh << 6);
    const ushort* kb_ = kbb + ((size_t)(b << 9)) * 512 + (hh << 6);
    const size_t off0 = (size_t)((sh << 8) + sr) * 512 + scg;
    bf16x8 rp0 = *(const bf16x8*)&pb_[off0];
    bf16x8 rp1 = *(const bf16x8*)&pb_[off0 + 8];
    bf16x8 rk0 = *(const bf16x8*)&kb_[off0];
    bf16x8 rk1 = *(const bf16x8*)&kb_[off0 + 8];
#pragma unroll
    for (int it = 0; it < 8; ++it) {
      __syncthreads();                      // prev tile's MFMA reads done
      *(bf16x8*)&su.pk.p[sh][sr][scg] = rp0;
      *(bf16x8*)&su.pk.p[sh][sr][scg + 8] = rp1;
      *(bf16x8*)&su.pk.k[sh][sr][scg] = rk0;
      *(bf16x8*)&su.pk.k[sh][sr][scg + 8] = rk1;
      if (it < 7) {                         // prefetch next tile (hides under MFMA)
        const size_t off = (size_t)((sh << 8) + ((it + 1) << 5) + sr) * 512 + scg;
        rp0 = *(const bf16x8*)&pb_[off];
        rp1 = *(const bf16x8*)&pb_[off + 8];
        rk0 = *(const bf16x8*)&kb_[off];
        rk1 = *(const bf16x8*)&kb_[off + 8];
      }
      __syncthreads();
#pragma unroll
      for (int ctl = 0; ctl < 2; ++ctl) {
        // PS
        {
          const bf16x8 b0 = *(const bf16x8*)&su.pk.p[half][(ctl << 4) + lm][lk];
          const bf16x8 b1 = *(const bf16x8*)&su.pk.p[half][(ctl << 4) + lm][32 + lk];
          f32x4 a = (f32x4)(0.f);
          a = __builtin_amdgcn_mfma_f32_16x16x32_bf16(av0, b0, a, 0, 0, 0);
          a = __builtin_amdgcn_mfma_f32_16x16x32_bf16(av1, b1, a, 0, 0, 0);
          const int col = C0 + (it << 5) + (ctl << 4) + lm;
#pragma unroll
          for (int r = 0; r < 4; ++r) psL[(band << 4) + fr4 + r][col] = f2bf(a[r]);
          if (ctl == band) {  // boundary row q0+32, split between bands
            f32x4 e = (f32x4)(0.f);
            e = __builtin_amdgcn_mfma_f32_16x16x32_bf16(e0, b0, e, 0, 0, 0);
            e = __builtin_amdgcn_mfma_f32_16x16x32_bf16(e1, b1, e, 0, 0, 0);
            if (g == 0) psL[32][col] = f2bf(e[0]);
          }
        }
        // QK
        {
          const int lct = (it << 1) + ctl;
          const bf16x8 b0 = *(const bf16x8*)&su.pk.k[half][(ctl << 4) + lm][lk];
          const bf16x8 b1 = *(const bf16x8*)&su.pk.k[half][(ctl << 4) + lm][32 + lk];
          acc[lct] = __builtin_amdgcn_mfma_f32_16x16x32_bf16(au0, b0, acc[lct], 0, 0, 0);
          acc[lct] = __builtin_amdgcn_mfma_f32_16x16x32_bf16(au1, b1, acc[lct], 0, 0, 0);
        }
      }
    }
  }
  __syncthreads();  // psL complete, pk reads complete

  // ======== rel-shift gather + scale ========
  const float scale = 0.044194173824159216f;  // 1/sqrt(512)
  const int qq0 = (band << 4) + fr4;
#pragma unroll
  for (int lct = 0; lct < 16; ++lct) {
#pragma unroll
    for (int r = 0; r < 4; ++r) {
      const int qq = qq0 + r;
      const int q = q0 + qq;
      const int c = C0 + (lct << 4) + lm;
      float f;
      if (c <= q)          f = bf2f(psL[qq][c - q + 511]);
      else if (c == q + 1) f = 0.f;
      else                 f = bf2f(psL[qq + 1][c - q - 2]);
      acc[lct][r] = (acc[lct][r] + f) * scale;
    }
  }

  // ======== softmax (intra-wave over lm; cross-half via scr) ========
  float mx[4] = {-3.0e38f, -3.0e38f, -3.0e38f, -3.0e38f};
#pragma unroll
  for (int lct = 0; lct < 16; ++lct)
#pragma unroll
    for (int r = 0; r < 4; ++r) mx[r] = fmaxf(mx[r], acc[lct][r]);
#pragma unroll
  for (int o = 1; o < 16; o <<= 1)
#pragma unroll
    for (int r = 0; r < 4; ++r) mx[r] = fmaxf(mx[r], __shfl_xor(mx[r], o));
  if (lm == 0) {
#pragma unroll
    for (int r = 0; r < 4; ++r) su.scr[half][qq0 + r] = mx[r];
  }
  __syncthreads();
#pragma unroll
  for (int r = 0; r < 4; ++r) mx[r] = fmaxf(mx[r], su.scr[half ^ 1][qq0 + r]);
  float sme[4] = {0.f, 0.f, 0.f, 0.f};
#pragma unroll
  for (int lct = 0; lct < 16; ++lct)
#pragma unroll
    for (int r = 0; r < 4; ++r) {
      acc[lct][r] = __expf(acc[lct][r] - mx[r]);
      sme[r] += acc[lct][r];
    }
#pragma unroll
  for (int o = 1; o < 16; o <<= 1)
#pragma unroll
    for (int r = 0; r < 4; ++r) sme[r] += __shfl_xor(sme[r], o);
  if (lm == 0) {
#pragma unroll
    for (int r = 0; r < 4; ++r) su.scr[2 + half][qq0 + r] = sme[r];
  }
  __syncthreads();
#pragma unroll
  for (int r = 0; r < 4; ++r) {
    const float inv = 1.f / (sme[r] + su.scr[2 + (half ^ 1)][qq0 + r]);
#pragma unroll
    for (int lct = 0; lct < 16; ++lct) acc[lct][r] *= inv;
  }
  __syncthreads();  // all psL gather reads done -> safe to carve Pl from psL

  // ======== PV + coalesced attn write: 8 chunks of 32 c per half ========
  ushort* Pl = (ushort*)&psL[0][0] + ((band << 1) | half) * 704;  // [16][44]
  const ushort* vtb = vT + ((size_t)((b << 9) + (hh << 6))) * 512;
  const int vrow = t >> 1, vc = (t & 1) << 4;
  const int vh = vrow >> 6, vd = vrow & 63;
  float* abase = attn + ((size_t)z << 18);
  f32x4 acc2[4];
#pragma unroll
  for (int i = 0; i < 4; ++i) acc2[i] = (f32x4)(0.f);
  bf16x8 p0 = *(const bf16x8*)&vtb[(size_t)vd * 512 + (vh << 8) + vc];
  bf16x8 p1 = *(const bf16x8*)&vtb[(size_t)vd * 512 + (vh << 8) + vc + 8];
#pragma unroll
  for (int ch = 0; ch < 8; ++ch) {
    // P chunk -> Pl (wave-private)
#pragma unroll
    for (int ctl = 0; ctl < 2; ++ctl) {
      const int lct = (ch << 1) + ctl;
#pragma unroll
      for (int r = 0; r < 4; ++r)
        Pl[(fr4 + r) * 44 + (ctl << 4) + lm] = f2bf(acc[lct][r]);
    }
    __syncthreads();  // prev v2 reads done
    *(bf16x8*)&su.v2[vh][vd][vc] = p0;
    *(bf16x8*)&su.v2[vh][vd][vc + 8] = p1;
    if (ch < 7) {
      const size_t off = (size_t)vd * 512 + (vh << 8) + ((ch + 1) << 5) + vc;
      p0 = *(const bf16x8*)&vtb[off];
      p1 = *(const bf16x8*)&vtb[off + 8];
    }
    // attn write from Pl (float4, coalesced within rows)
    {
      const int row = lane >> 2, colg = (lane & 3) << 3;
      const ushort* ps = Pl + row * 44 + colg;
      float* ar = abase + (size_t)(q0 + (band << 4) + row) * 512 + C0 + (ch << 5) + colg;
      float4 o0, o1;
      o0.x = bf2f(ps[0]); o0.y = bf2f(ps[1]); o0.z = bf2f(ps[2]); o0.w = bf2f(ps[3]);
      o1.x = bf2f(ps[4]); o1.y = bf2f(ps[5]); o1.z = bf2f(ps[6]); o1.w = bf2f(ps[7]);
      *(float4*)&ar[0] = o0;
      *(float4*)&ar[4] = o1;
    }
    __syncthreads();  // v2 ready
#pragma unroll
    for (int dt = 0; dt < 4; ++dt) {
      const bf16x8 va = *(const bf16x8*)&su.v2[half][(dt << 4) + lm][lk];
      const bf16x8 pbf = *(const bf16x8*)&Pl[lm * 44 + lk];
      acc2[dt] = __builtin_amdgcn_mfma_f32_16x16x32_bf16(va, pbf, acc2[dt], 0, 0, 0);
    }
  }
  // combine col-half partials via scrC, then write ctx
  __syncthreads();
  if (half == 1) {
#pragma unroll
    for (int dt = 0; dt < 4; ++dt)
#pragma unroll
      for (int r = 0; r < 4; ++r)
        su.scrC[band][(dt << 4) + fr4 + r][lm] = acc2[dt][r];
  }
  __syncthreads();
  if (half == 0) {
    const int qq2 = q0 + (band << 4) + lm;
#pragma unroll
    for (int dt = 0; dt < 4; ++dt) {
      ushort4 o;
      o.x = f2bf(acc2[dt][0] + su.scrC[band][(dt << 4) + fr4 + 0][lm]);
      o.y = f2bf(acc2[dt][1] + su.scrC[band][(dt << 4) + fr4 + 1][lm]);
      o.z = f2bf(acc2[dt][2] + su.scrC[band][(dt << 4) + fr4 + 2][lm]);
      o.w = f2bf(acc2[dt][3] + su.scrC[band][(dt << 4) + fr4 + 3][lm]);
      *(ushort4*)&ctx[((size_t)((b << 9) + qq2)) * 512 + (hh << 6) + (dt << 4) + fr4] = o;
    }
  }
}

// ------------- depthwise conv (K=31) + BN + swish, register sliding window ------
__global__ __launch_bounds__(256) void dwconv2(const ushort* __restrict__ in,
                                               const float* __restrict__ w,
                                               const float* __restrict__ bng,
                                               const float* __restrict__ bnb,
                                               const float* __restrict__ bnm,
                                               const float* __restrict__ bnv,
                                               ushort* __restrict__ out) {
  __shared__ float wl[31][128];
  const int t = threadIdx.x;
  const int dbase = blockIdx.x << 7;
  const int b = blockIdx.z;
  const int sb = (blockIdx.y << 6) + ((t >> 6) << 4);
  if (t < 128) {
    const float* ws = &w[(dbase + t) * 31];
#pragma unroll
    for (int k = 0; k < 31; ++k) wl[k][t] = ws[k];
  }
  __syncthreads();
  const int dl = (t & 63) << 1;
  const int d = dbase + dl;
  const size_t base = (((size_t)b) << 18) + d;
  float2 win[46];
#pragma unroll
  for (int i = 0; i < 46; ++i) {
    const int s = sb - 15 + i;
    if (s >= 0 && s < 512) {
      const ushort2 u = *(const ushort2*)&in[base + ((size_t)s << 9)];
      win[i].x = bf2f(u.x); win[i].y = bf2f(u.y);
    } else {
      win[i].x = 0.f; win[i].y = 0.f;
    }
  }
  float2 acc[16];
#pragma unroll
  for (int p = 0; p < 16; ++p) { acc[p].x = 0.f; acc[p].y = 0.f; }
#pragma unroll
  for (int k = 0; k < 31; ++k) {
    const float2 w2 = *(const float2*)&wl[k][dl];
#pragma unroll
    for (int p = 0; p < 16; ++p) {
      acc[p].x = fmaf(win[p + k].x, w2.x, acc[p].x);
      acc[p].y = fmaf(win[p + k].y, w2.y, acc[p].y);
    }
  }
  const float g0 = bng[d] * rsqrtf(bnv[d] + EPSF);
  const float g1 = bng[d + 1] * rsqrtf(bnv[d + 1] + EPSF);
  const float m0 = bnm[d], m1 = bnm[d + 1];
  const float bb0 = bnb[d], bb1 = bnb[d + 1];
#pragma unroll
  for (int p = 0; p < 16; ++p) {
    float v0 = (acc[p].x - m0) * g0 + bb0;
    float v1 = (acc[p].y - m1) * g1 + bb1;
    v0 = v0 * sigmf(v0);
    v1 = v1 * sigmf(v1);
    ushort2 o;
    o.x = f2bf(v0); o.y = f2bf(v1);
    *(ushort2*)&out[base + ((size_t)(sb + p) << 9)] = o;
  }
}

extern "C" void kernel_launch(void* const* d_in, const int* in_sizes, int n_in,
                              void* d_out, int out_size, void* d_ws, size_t ws_size,
                              hipStream_t stream) {
  const float* x      = (const float*)d_in[0];
  const float* ff1_g  = (const float*)d_in[1];
  const float* ff1_b  = (const float*)d_in[2];
  const float* ff1_w1 = (const float*)d_in[3];
  const float* ff1_b1 = (const float*)d_in[4];
  const float* ff1_w2 = (const float*)d_in[5];
  const float* ff1_b2 = (const float*)d_in[6];
  const float* attn_g = (const float*)d_in[7];
  const float* attn_b = (const float*)d_in[8];
  const float* wq     = (const float*)d_in[9];
  const float* bq     = (const float*)d_in[10];
  const float* wk     = (const float*)d_in[11];
  const float* bk     = (const float*)d_in[12];
  const float* wv     = (const float*)d_in[13];
  const float* bv     = (const float*)d_in[14];
  const float* wpos   = (const float*)d_in[15];
  const float* u_bias = (const float*)d_in[16];
  const float* v_bias = (const float*)d_in[17];
  const float* wo     = (const float*)d_in[18];
  const float* bo     = (const float*)d_in[19];
  const float* conv_g = (const float*)d_in[20];
  const float* conv_b = (const float*)d_in[21];
  const float* pw1_w  = (const float*)d_in[22];
  const float* pw1_b  = (const float*)d_in[23];
  const float* dw_w   = (const float*)d_in[24];
  const float* bn_g   = (const float*)d_in[25];
  const float* bn_b   = (const float*)d_in[26];
  const float* bn_m   = (const float*)d_in[27];
  const float* bn_v   = (const float*)d_in[28];
  const float* pw2_w  = (const float*)d_in[29];
  const float* pw2_b  = (const float*)d_in[30];
  const float* ff2_g  = (const float*)d_in[31];
  const float* ff2_b  = (const float*)d_in[32];
  const float* ff2_w1 = (const float*)d_in[33];
  const float* ff2_b1 = (const float*)d_in[34];
  const float* ff2_w2 = (const float*)d_in[35];
  const float* ff2_b2 = (const float*)d_in[36];
  const float* ln_g   = (const float*)d_in[37];
  const float* ln_b   = (const float*)d_in[38];

  float* out  = (float*)d_out;            // [B,S,D] f32
  float* attn = out + ND;                 // [B,H,S,S] f32

  float*  res  = (float*)d_ws;
  ushort* ybf  = (ushort*)(res + ND);
  float*  big  = (float*)(ybf + ND);             // 2*ND f32 region
  ushort* vT   = (ushort*)(big + 2 * ND);        // ND ushorts [b][col][s]
  ushort* dwbf = vT + ND;                        // ND ushorts
  ushort* wts  = dwbf + ND;                      // 6,291,456 ushorts
  ushort* pebf = wts + 6291456;                  // 262,144
  ushort* ppbf = pebf + 262144;                  // 262,144

  ushort* ffmid = (ushort*)big;
  ushort* qu    = (ushort*)big;
  ushort* qv    = qu + ND;
  ushort* kbb   = qv + ND;
  ushort* ctxbf = ybf;
  ushort* glubf = (ushort*)big;

  ushort* ff1w1t = wts;
  ushort* ff1w2t = wts + 1048576;
  ushort* wqt    = wts + 2097152;
  ushort* wkt    = wts + 2359296;
  ushort* wvt    = wts + 2621440;
  ushort* wot    = wts + 2883584;
  ushort* pw1t   = wts + 3145728;
  ushort* pw2t   = wts + 3670016;
  ushort* ff2w1t = wts + 3932160;
  ushort* ff2w2t = wts + 4980736;
  ushort* wpost  = wts + 6029312;

  const dim3 blk(256);

  // ---- weight prep: single merged transpose dispatch ----
  TpArgs ta;
  auto set = [&](int i, const float* s, ushort* d, int K, int N) {
    ta.src[i] = s; ta.dst[i] = d; ta.K[i] = K; ta.N[i] = N;
  };
  set(0, ff1_w1, ff1w1t, 512, 2048);
  set(1, ff1_w2, ff1w2t, 2048, 512);
  set(2, wq, wqt, 512, 512);
  set(3, wk, wkt, 512, 512);
  set(4, wv, wvt, 512, 512);
  set(5, wo, wot, 512, 512);
  set(6, wpos, wpost, 512, 512);
  set(7, pw1_w, pw1t, 512, 1024);
  set(8, pw2_w, pw2t, 512, 512);
  set(9, ff2_w1, ff2w1t, 512, 2048);
  set(10, ff2_w2, ff2w2t, 2048, 512);
  int tacc = 0;
  for (int i = 0; i < 11; ++i) { ta.base[i] = tacc; tacc += (ta.N[i] >> 5) * (ta.K[i] >> 5); }
  ta.base[11] = tacc;
  transpose_all<<<tacc, blk, 0, stream>>>(ta);
  pe_kernel_bf16<<<512, blk, 0, stream>>>(pebf);
  gemm_bf16<0, 0, 0, 1><<<dim3(4, 4), blk, 0, stream>>>(pebf, wpost, nullptr, nullptr, ppbf,
                                                        512, 512, 512);

  // ---- Macaron FF1: res = x + 0.5*FF(LN(x)) ----
  ln_bf16<<<NTOK / 4, blk, 0, stream>>>(x, ff1_g, ff1_b, ybf);
  gemm_bf16<1, 0, 1, 1><<<dim3(16, 128), blk, 0, stream>>>(ybf, ff1w1t, ff1_b1, nullptr, ffmid,
                                                           NTOK, 512, 2048);
  gemm_bf16<0, 2, 1, 0><<<dim3(4, 128), blk, 0, stream>>>(ffmid, ff1w2t, ff1_b2, x, res,
                                                          NTOK, 2048, 512);

  // ---- Attention ----
  ln_bf16<<<NTOK / 4, blk, 0, stream>>>(res, attn_g, attn_b, ybf);
  gemm_qkv<<<dim3(12, 128), blk, 0, stream>>>(ybf, wqt, bq, bk, bv, u_bias, v_bias,
                                              qu, qv, kbb, vT, NTOK, 512);
  attn_fused7<<<dim3(16, 256), blk, 0, stream>>>(qu, qv, kbb, ppbf, vT, attn, ctxbf);
  gemm_bf16<0, 1, 1, 0><<<dim3(4, 128), blk, 0, stream>>>(ctxbf, wot, bo, res, res,
                                                          NTOK, 512, 512);

  // ---- Conv module ----
  ln_bf16<<<NTOK / 4, blk, 0, stream>>>(res, conv_g, conv_b, ybf);
  gemm_glu<<<dim3(4, 128), blk, 0, stream>>>(ybf, pw1t, pw1_b, glubf, NTOK, 512);
  dwconv2<<<dim3(4, 8, 32), blk, 0, stream>>>(glubf, dw_w, bn_g, bn_b, bn_m, bn_v, dwbf);
  gemm_bf16<0, 1, 1, 0><<<dim3(4, 128), blk, 0, stream>>>(dwbf, pw2t, pw2_b, res, res,
                                                          NTOK, 512, 512);

  // ---- Macaron FF2 + final LN ----
  ln_bf16<<<NTOK / 4, blk, 0, stream>>>(res, ff2_g, ff2_b, ybf);
  gemm_bf16<1, 0, 1, 1><<<dim3(16, 128), blk, 0, stream>>>(ybf, ff2w1t, ff2_b1, nullptr, ffmid,
                                                           NTOK, 512, 2048);
  gemm_bf16<0, 2, 1, 0><<<dim3(4, 128), blk, 0, stream>>>(ffmid, ff2w2t, ff2_b2, res, res,
                                                          NTOK, 2048, 512);
  ln_f32<<<NTOK / 4, blk, 0, stream>>>(res, ln_g, ln_b, out);
}

// Round 11
// 718.632 us; speedup vs baseline: 1.3373x; 1.0164x over previous
//
#include <hip/hip_runtime.h>
#include <cstddef>
#include <cstdint>

#define EPSF 1e-5f

constexpr int BB = 32, SS = 512, DD = 512, HH = 8, DH = 64;
constexpr int NTOK = BB * SS;              // 16384 rows
constexpr size_t ND = (size_t)NTOK * DD;   // 8,388,608

typedef __attribute__((ext_vector_type(8))) short bf16x8;
typedef __attribute__((ext_vector_type(4))) float f32x4;

__device__ __forceinline__ float sigmf(float v) { return 1.f / (1.f + __expf(-v)); }

__device__ __forceinline__ ushort f2bf(float f) {
  union { float f; uint32_t u; } x{f};
  uint32_t r = x.u + 0x7FFF + ((x.u >> 16) & 1);
  return (ushort)(r >> 16);
}
__device__ __forceinline__ float bf2f(ushort u) {
  union { uint32_t u; float f; } x{(uint32_t)u << 16};
  return x.f;
}

__device__ __forceinline__ void gload16(const ushort* g, ushort* ldsbase) {
  __builtin_amdgcn_global_load_lds((const __attribute__((address_space(1))) void*)g,
                                   (__attribute__((address_space(3))) void*)ldsbase, 16, 0, 0);
}

// bijective XCD-chunk swizzle (m204); requires nwg % 8 == 0.
__device__ __forceinline__ void xcd_swz(int& bx, int& by) {
  const int gx = gridDim.x;
  const int nwg = gx * gridDim.y;
  const int cpx = nwg >> 3;
  int id = by * gx + bx;
  id = (id & 7) * cpx + (id >> 3);
  bx = id % gx;
  by = id / gx;
}

// psl index swizzle: XOR bits 4-5 with bits 11-12 (bits 11-12 unmodified -> bijective)
__device__ __forceinline__ int pswz(int idx) {
  return idx ^ (((idx >> 11) & 3) << 4);
}

// ---------------- LayerNorm: one wave per row, f32 out --------------------------
__global__ __launch_bounds__(256) void ln_f32(const float* __restrict__ x,
                                              const float* __restrict__ g,
                                              const float* __restrict__ b,
                                              float* __restrict__ y) {
  const int lane = threadIdx.x & 63;
  const int row = blockIdx.x * 4 + (threadIdx.x >> 6);
  const float* xr = x + (size_t)row * 512;
  const float4 v0 = *(const float4*)&xr[lane << 2];
  const float4 v1 = *(const float4*)&xr[256 + (lane << 2)];
  float s = v0.x + v0.y + v0.z + v0.w + v1.x + v1.y + v1.z + v1.w;
#pragma unroll
  for (int o = 32; o > 0; o >>= 1) s += __shfl_xor(s, o);
  const float mean = s * (1.f / 512.f);
  float q = 0.f;
  q += (v0.x - mean) * (v0.x - mean); q += (v0.y - mean) * (v0.y - mean);
  q += (v0.z - mean) * (v0.z - mean); q += (v0.w - mean) * (v0.w - mean);
  q += (v1.x - mean) * (v1.x - mean); q += (v1.y - mean) * (v1.y - mean);
  q += (v1.z - mean) * (v1.z - mean); q += (v1.w - mean) * (v1.w - mean);
#pragma unroll
  for (int o = 32; o > 0; o >>= 1) q += __shfl_xor(q, o);
  const float rs = rsqrtf(q * (1.f / 512.f) + EPSF);
  const float4 g0 = *(const float4*)&g[lane << 2];
  const float4 g1 = *(const float4*)&g[256 + (lane << 2)];
  const float4 b0 = *(const float4*)&b[lane << 2];
  const float4 b1 = *(const float4*)&b[256 + (lane << 2)];
  float* yr = y + (size_t)row * 512;
  float4 o0, o1;
  o0.x = (v0.x - mean) * rs * g0.x + b0.x; o0.y = (v0.y - mean) * rs * g0.y + b0.y;
  o0.z = (v0.z - mean) * rs * g0.z + b0.z; o0.w = (v0.w - mean) * rs * g0.w + b0.w;
  o1.x = (v1.x - mean) * rs * g1.x + b1.x; o1.y = (v1.y - mean) * rs * g1.y + b1.y;
  o1.z = (v1.z - mean) * rs * g1.z + b1.z; o1.w = (v1.w - mean) * rs * g1.w + b1.w;
  *(float4*)&yr[lane << 2] = o0;
  *(float4*)&yr[256 + (lane << 2)] = o1;
}

// ---------------- LayerNorm writing bf16 ----------------------------------------
__global__ __launch_bounds__(256) void ln_bf16(const float* __restrict__ x,
                                               const float* __restrict__ g,
                                               const float* __restrict__ b,
                                               ushort* __restrict__ y) {
  const int lane = threadIdx.x & 63;
  const int row = blockIdx.x * 4 + (threadIdx.x >> 6);
  const float* xr = x + (size_t)row * 512;
  const float4 v0 = *(const float4*)&xr[lane << 2];
  const float4 v1 = *(const float4*)&xr[256 + (lane << 2)];
  float s = v0.x + v0.y + v0.z + v0.w + v1.x + v1.y + v1.z + v1.w;
#pragma unroll
  for (int o = 32; o > 0; o >>= 1) s += __shfl_xor(s, o);
  const float mean = s * (1.f / 512.f);
  float q = 0.f;
  q += (v0.x - mean) * (v0.x - mean); q += (v0.y - mean) * (v0.y - mean);
  q += (v0.z - mean) * (v0.z - mean); q += (v0.w - mean) * (v0.w - mean);
  q += (v1.x - mean) * (v1.x - mean); q += (v1.y - mean) * (v1.y - mean);
  q += (v1.z - mean) * (v1.z - mean); q += (v1.w - mean) * (v1.w - mean);
#pragma unroll
  for (int o = 32; o > 0; o >>= 1) q += __shfl_xor(q, o);
  const float rs = rsqrtf(q * (1.f / 512.f) + EPSF);
  const float4 g0 = *(const float4*)&g[lane << 2];
  const float4 g1 = *(const float4*)&g[256 + (lane << 2)];
  const float4 b0 = *(const float4*)&b[lane << 2];
  const float4 b1 = *(const float4*)&b[256 + (lane << 2)];
  ushort* yr = y + (size_t)row * 512;
  ushort4 o0, o1;
  o0.x = f2bf((v0.x - mean) * rs * g0.x + b0.x); o0.y = f2bf((v0.y - mean) * rs * g0.y + b0.y);
  o0.z = f2bf((v0.z - mean) * rs * g0.z + b0.z); o0.w = f2bf((v0.w - mean) * rs * g0.w + b0.w);
  o1.x = f2bf((v1.x - mean) * rs * g1.x + b1.x); o1.y = f2bf((v1.y - mean) * rs * g1.y + b1.y);
  o1.z = f2bf((v1.z - mean) * rs * g1.z + b1.z); o1.w = f2bf((v1.w - mean) * rs * g1.w + b1.w);
  *(ushort4*)&yr[lane << 2] = o0;
  *(ushort4*)&yr[256 + (lane << 2)] = o1;
}

// ---------------- merged weight transpose: 11 segments, one dispatch ------------
struct TpArgs {
  const float* src[11];
  ushort* dst[11];
  int K[11];
  int N[11];
  int base[12];
};

__global__ __launch_bounds__(256) void transpose_all(TpArgs a) {
  __shared__ float tile[32][33];
  int s = 0;
  const int bid = blockIdx.x;
  while (s < 10 && bid >= a.base[s + 1]) ++s;
  const int r = bid - a.base[s];
  const int K = a.K[s], N = a.N[s];
  const int ntx = N >> 5;
  const int n0 = (r % ntx) << 5;
  const int k0 = (r / ntx) << 5;
  const float* in = a.src[s];
  ushort* out = a.dst[s];
  const int tx = threadIdx.x & 31, ty = threadIdx.x >> 5;
#pragma unroll
  for (int i = 0; i < 32; i += 8)
    tile[ty + i][tx] = in[(size_t)(k0 + ty + i) * N + n0 + tx];
  __syncthreads();
#pragma unroll
  for (int i = 0; i < 32; i += 8)
    out[(size_t)(n0 + ty + i) * K + k0 + tx] = f2bf(tile[tx][ty + i]);
}

// ---------------- bf16 MFMA GEMM, T3-minimum 2-phase double-buffer --------------
template <int ACT, int RES, int HB, int OBF>
__global__ __launch_bounds__(256) void gemm_bf16(const ushort* __restrict__ A,
                                                 const ushort* __restrict__ Wt,
                                                 const float* __restrict__ bias,
                                                 const float* __restrict__ res,
                                                 void* __restrict__ Cv,
                                                 int M, int K, int N) {
  __shared__ ushort Al[2][8192];
  __shared__ ushort Bl[2][8192];
  const int t = threadIdx.x;
  const int lane = t & 63;
  const int w = t >> 6;
  const int wr = (w >> 1) << 6, wc = (w & 1) << 6;
  int bx = blockIdx.x, by = blockIdx.y;
  xcd_swz(bx, by);
  const int m0 = by << 7, n0 = bx << 7;
  const int lm = lane & 15;
  const int grow = lane >> 3;
  const int gcol = (lane & 7) << 3;

  f32x4 acc[4][4];
#pragma unroll
  for (int i = 0; i < 4; ++i)
#pragma unroll
    for (int j = 0; j < 4; ++j) acc[i][j] = (f32x4)(0.f);

  const int NT = K >> 6;
#pragma unroll
  for (int i = 0; i < 4; ++i) {
    const int s = (w << 2) + i;
    gload16(A + (size_t)(m0 + (s << 3) + grow) * K + gcol, &Al[0][s << 9]);
    gload16(Wt + (size_t)(n0 + (s << 3) + grow) * K + gcol, &Bl[0][s << 9]);
  }
  __syncthreads();
  int cur = 0;
  for (int tt = 0; tt < NT; ++tt) {
    if (tt + 1 < NT) {
      const int k0 = (tt + 1) << 6;
#pragma unroll
      for (int i = 0; i < 4; ++i) {
        const int s = (w << 2) + i;
        gload16(A + (size_t)(m0 + (s << 3) + grow) * K + k0 + gcol, &Al[cur ^ 1][s << 9]);
        gload16(Wt + (size_t)(n0 + (s << 3) + grow) * K + k0 + gcol, &Bl[cur ^ 1][s << 9]);
      }
    }
#pragma unroll
    for (int ks = 0; ks < 2; ++ks) {
      const int kof = (ks << 5) + ((lane >> 4) << 3);
      bf16x8 af[4], bfr[4];
#pragma unroll
      for (int i = 0; i < 4; ++i) af[i] = *(const bf16x8*)&Al[cur][(wr + (i << 4) + lm) * 64 + kof];
#pragma unroll
      for (int j = 0; j < 4; ++j) bfr[j] = *(const bf16x8*)&Bl[cur][(wc + (j << 4) + lm) * 64 + kof];
#pragma unroll
      for (int i = 0; i < 4; ++i)
#pragma unroll
        for (int j = 0; j < 4; ++j)
          acc[i][j] = __builtin_amdgcn_mfma_f32_16x16x32_bf16(af[i], bfr[j], acc[i][j], 0, 0, 0);
    }
    __syncthreads();
    cur ^= 1;
  }

  float bb[4] = {0.f, 0.f, 0.f, 0.f};
  if (HB) {
#pragma unroll
    for (int j = 0; j < 4; ++j) bb[j] = bias[n0 + wc + j * 16 + lm];
  }
  const int rbase = m0 + wr + ((lane >> 4) << 2);
#pragma unroll
  for (int i = 0; i < 4; ++i) {
#pragma unroll
    for (int r = 0; r < 4; ++r) {
      const size_t row = (size_t)(rbase + i * 16 + r);
#pragma unroll
      for (int j = 0; j < 4; ++j) {
        const int col = n0 + wc + j * 16 + lm;
        float v = acc[i][j][r] + bb[j];
        if (ACT == 1) v = v * sigmf(v);
        if (RES == 1) v += res[row * N + col];
        else if (RES == 2) v = res[row * N + col] + 0.5f * v;
        if (OBF) ((ushort*)Cv)[row * N + col] = f2bf(v);
        else ((float*)Cv)[row * N + col] = v;
      }
    }
  }
}

// ---------------- merged QKV projection: N=1536, routed epilogue ----------------
__global__ __launch_bounds__(256) void gemm_qkv(const ushort* __restrict__ A,
                                                const ushort* __restrict__ Wt,
                                                const float* __restrict__ bq,
                                                const float* __restrict__ bk,
                                                const float* __restrict__ bv,
                                                const float* __restrict__ ub,
                                                const float* __restrict__ vb,
                                                ushort* __restrict__ qu,
                                                ushort* __restrict__ qv,
                                                ushort* __restrict__ kbb,
                                                ushort* __restrict__ vT,
                                                int M, int K) {
  __shared__ ushort Al[2][8192];
  __shared__ ushort Bl[2][8192];
  const int t = threadIdx.x;
  const int lane = t & 63;
  const int w = t >> 6;
  const int wr = (w >> 1) << 6, wc = (w & 1) << 6;
  int bx = blockIdx.x, by = blockIdx.y;
  xcd_swz(bx, by);
  const int m0 = by << 7, n0 = bx << 7;
  const int lm = lane & 15;
  const int grow = lane >> 3;
  const int gcol = (lane & 7) << 3;
  f32x4 acc[4][4];
#pragma unroll
  for (int i = 0; i < 4; ++i)
#pragma unroll
    for (int j = 0; j < 4; ++j) acc[i][j] = (f32x4)(0.f);
  const int NT = K >> 6;
#pragma unroll
  for (int i = 0; i < 4; ++i) {
    const int s = (w << 2) + i;
    gload16(A + (size_t)(m0 + (s << 3) + grow) * K + gcol, &Al[0][s << 9]);
    gload16(Wt + (size_t)(n0 + (s << 3) + grow) * K + gcol, &Bl[0][s << 9]);
  }
  __syncthreads();
  int cur = 0;
  for (int tt = 0; tt < NT; ++tt) {
    if (tt + 1 < NT) {
      const int k0 = (tt + 1) << 6;
#pragma unroll
      for (int i = 0; i < 4; ++i) {
        const int s = (w << 2) + i;
        gload16(A + (size_t)(m0 + (s << 3) + grow) * K + k0 + gcol, &Al[cur ^ 1][s << 9]);
        gload16(Wt + (size_t)(n0 + (s << 3) + grow) * K + k0 + gcol, &Bl[cur ^ 1][s << 9]);
      }
    }
#pragma unroll
    for (int ks = 0; ks < 2; ++ks) {
      const int kof = (ks << 5) + ((lane >> 4) << 3);
      bf16x8 af[4], bfr[4];
#pragma unroll
      for (int i = 0; i < 4; ++i) af[i] = *(const bf16x8*)&Al[cur][(wr + (i << 4) + lm) * 64 + kof];
#pragma unroll
      for (int j = 0; j < 4; ++j) bfr[j] = *(const bf16x8*)&Bl[cur][(wc + (j << 4) + lm) * 64 + kof];
#pragma unroll
      for (int i = 0; i < 4; ++i)
#pragma unroll
        for (int j = 0; j < 4; ++j)
          acc[i][j] = __builtin_amdgcn_mfma_f32_16x16x32_bf16(af[i], bfr[j], acc[i][j], 0, 0, 0);
    }
    __syncthreads();
    cur ^= 1;
  }
  const int seg = n0 >> 9;                 // block-uniform: 0=q, 1=k, 2=v
  const int nloc = n0 & 511;
  const float* bsel = (seg == 0) ? bq : (seg == 1 ? bk : bv);
  float bb[4], uu[4], vv[4];
#pragma unroll
  for (int j = 0; j < 4; ++j) {
    const int col = nloc + wc + j * 16 + lm;
    bb[j] = bsel[col];
    if (seg == 0) { uu[j] = ub[col]; vv[j] = vb[col]; }
  }
  const int rbase = m0 + wr + ((lane >> 4) << 2);
  if (seg == 2) {
    const int bloc = m0 >> 9;
    const int sbase = rbase - (bloc << 9);
#pragma unroll
    for (int i = 0; i < 4; ++i) {
#pragma unroll
      for (int j = 0; j < 4; ++j) {
        const int col = nloc + wc + j * 16 + lm;
        ushort4 o;
        o.x = f2bf(acc[i][j][0] + bb[j]);
        o.y = f2bf(acc[i][j][1] + bb[j]);
        o.z = f2bf(acc[i][j][2] + bb[j]);
        o.w = f2bf(acc[i][j][3] + bb[j]);
        *(ushort4*)&vT[((size_t)((bloc << 9) + col)) * 512 + sbase + i * 16] = o;
      }
    }
    return;
  }
#pragma unroll
  for (int i = 0; i < 4; ++i) {
#pragma unroll
    for (int r = 0; r < 4; ++r) {
      const size_t row = (size_t)(rbase + i * 16 + r);
#pragma unroll
      for (int j = 0; j < 4; ++j) {
        const int col = nloc + wc + j * 16 + lm;
        const float v = acc[i][j][r] + bb[j];
        if (seg == 0) {
          qu[row * 512 + col] = f2bf(v + uu[j]);
          qv[row * 512 + col] = f2bf(v + vv[j]);
        } else {
          kbb[row * 512 + col] = f2bf(v);
        }
      }
    }
  }
}

// ---------------- pw1 + GLU fused ----------------------------------------------
__global__ __launch_bounds__(256) void gemm_glu(const ushort* __restrict__ A,
                                                const ushort* __restrict__ Wt,
                                                const float* __restrict__ bias,
                                                ushort* __restrict__ Cout,
                                                int M, int K) {
  __shared__ ushort Al[8192];
  __shared__ ushort Ba[8192];
  __shared__ ushort Bg[8192];
  const int t = threadIdx.x;
  const int lane = t & 63;
  const int w = t >> 6;
  const int wr = (w >> 1) << 6, wc = (w & 1) << 6;
  int bx = blockIdx.x, by = blockIdx.y;
  xcd_swz(bx, by);
  const int m0 = by << 7, n0 = bx << 7;
  const int lm = lane & 15;
  const int grow = lane >> 3;
  const int gcol = (lane & 7) << 3;
  const ushort* WtA = Wt;
  const ushort* WtG = Wt + (size_t)512 * 512;
  f32x4 acca[4][4], accg[4][4];
#pragma unroll
  for (int i = 0; i < 4; ++i)
#pragma unroll
    for (int j = 0; j < 4; ++j) { acca[i][j] = (f32x4)(0.f); accg[i][j] = (f32x4)(0.f); }
  const int NT = K >> 6;
  for (int tt = 0; tt < NT; ++tt) {
    const int k0 = tt << 6;
    if (tt) __syncthreads();
#pragma unroll
    for (int i = 0; i < 4; ++i) {
      const int s = (w << 2) + i;
      gload16(A + (size_t)(m0 + (s << 3) + grow) * K + k0 + gcol, &Al[s << 9]);
      gload16(WtA + (size_t)(n0 + (s << 3) + grow) * K + k0 + gcol, &Ba[s << 9]);
      gload16(WtG + (size_t)(n0 + (s << 3) + grow) * K + k0 + gcol, &Bg[s << 9]);
    }
    __syncthreads();
#pragma unroll
    for (int ks = 0; ks < 2; ++ks) {
      const int kof = (ks << 5) + ((lane >> 4) << 3);
      bf16x8 af[4], ba4[4], bg4[4];
#pragma unroll
      for (int i = 0; i < 4; ++i) af[i] = *(const bf16x8*)&Al[(wr + (i << 4) + lm) * 64 + kof];
#pragma unroll
      for (int j = 0; j < 4; ++j) {
        ba4[j] = *(const bf16x8*)&Ba[(wc + (j << 4) + lm) * 64 + kof];
        bg4[j] = *(const bf16x8*)&Bg[(wc + (j << 4) + lm) * 64 + kof];
      }
#pragma unroll
      for (int i = 0; i < 4; ++i)
#pragma unroll
        for (int j = 0; j < 4; ++j) {
          acca[i][j] = __builtin_amdgcn_mfma_f32_16x16x32_bf16(af[i], ba4[j], acca[i][j], 0, 0, 0);
          accg[i][j] = __builtin_amdgcn_mfma_f32_16x16x32_bf16(af[i], bg4[j], accg[i][j], 0, 0, 0);
        }
    }
  }
  float bba[4], bbg[4];
#pragma unroll
  for (int j = 0; j < 4; ++j) {
    const int col = n0 + wc + j * 16 + lm;
    bba[j] = bias[col];
    bbg[j] = bias[512 + col];
  }
  const int rbase = m0 + wr + ((lane >> 4) << 2);
#pragma unroll
  for (int i = 0; i < 4; ++i) {
#pragma unroll
    for (int r = 0; r < 4; ++r) {
      const size_t row = (size_t)(rbase + i * 16 + r);
#pragma unroll
      for (int j = 0; j < 4; ++j) {
        const int col = n0 + wc + j * 16 + lm;
        const float va = acca[i][j][r] + bba[j];
        const float vg = accg[i][j][r] + bbg[j];
        Cout[row * 512 + col] = f2bf(va * sigmf(vg));
      }
    }
  }
}

// ------------- Sinusoidal PE (bf16) ---------------------------------------------
__global__ void pe_kernel_bf16(ushort* __restrict__ pe) {
  const int pos = blockIdx.x, ii = threadIdx.x;
  const float ang = (float)pos * powf(10000.f, -(float)(2 * ii) / 512.f);
  pe[((size_t)pos << 9) + 2 * ii] = f2bf(sinf(ang));
  pe[((size_t)pos << 9) + 2 * ii + 1] = f2bf(cosf(ang));
}

// ------------- fused attention v8: flat-513 PS + XOR swizzle (conflict-free) ----
// grid (16, 256). LDS = psl 34.0KB + su 18.4KB = 52.5KB -> 3 blocks/CU.
__global__ __launch_bounds__(256, 3) void attn_fused8(const ushort* __restrict__ qu,
                                                      const ushort* __restrict__ qv,
                                                      const ushort* __restrict__ kbb,
                                                      const ushort* __restrict__ ppb,
                                                      const ushort* __restrict__ vT,
                                                      float* __restrict__ attn,
                                                      ushort* __restrict__ ctx) {
  __shared__ ushort psl[17024];        // flat PS: row qq at qq*513, col 512 = 0
  __shared__ union StU {
    struct { ushort p[2][32][72]; ushort k[2][32][72]; } pk;  // 18,432 B
    ushort v2[2][64][40];              // V staging per col-half
    float scr[4][32];                  // softmax cross-half scratch
    float scrC[2][64][17];             // PV partial combine (padded: 68 dw stride)
  } su;
  const int t = threadIdx.x, lane = t & 63, w = t >> 6;
  int bx = blockIdx.x, by = blockIdx.y;
  xcd_swz(bx, by);                     // 16 q-blocks of a z land on same XCD
  const int z = by, b = z >> 3, hh = z & 7;
  const int q0 = bx << 5;
  const int band = w >> 1, half = w & 1;
  const int lm = lane & 15, g = lane >> 4;
  const int lk = g << 3, fr4 = g << 2;
  const int C0 = half << 8;

  // zero pad column (col 512) of rows 0..32 (PS never writes col 512)
  if (t < 33) {
    const int zi = t * 513 + 512;
    psl[pswz(zi)] = 0;
  }

  // A-fragments (own 16 q-rows)
  const size_t qoff = ((size_t)((b << 9) + q0 + (band << 4) + lm)) * 512 + (hh << 6);
  const bf16x8 av0 = *(const bf16x8*)&qv[qoff + lk];
  const bf16x8 av1 = *(const bf16x8*)&qv[qoff + lk + 32];
  const bf16x8 au0 = *(const bf16x8*)&qu[qoff + lk];
  const bf16x8 au1 = *(const bf16x8*)&qu[qoff + lk + 32];
  int er = q0 + 32 + lm;
  if (er > 511) er = 511;
  const size_t eoff = ((size_t)((b << 9) + er)) * 512 + (hh << 6);
  const bf16x8 e0 = *(const bf16x8*)&qv[eoff + lk];
  const bf16x8 e1 = *(const bf16x8*)&qv[eoff + lk + 32];

  // staging map: 64 rows (2 halves x 32) x 64 cols per array; thread: row=t>>2
  const int srow = t >> 2, scg = (t & 3) << 4;
  const int sh = srow >> 5, sr = srow & 31;

  // ======== merged PS + QK pass: stage pp-tile AND K-tile per iteration ========
  f32x4 acc[16];
#pragma unroll
  for (int i = 0; i < 16; ++i) acc[i] = (f32x4)(0.f);
  {
    const ushort* pb_ = ppb + (hh << 6);
    const ushort* kb_ = kbb + ((size_t)(b << 9)) * 512 + (hh << 6);
    const size_t off0 = (size_t)((sh << 8) + sr) * 512 + scg;
    bf16x8 rp0 = *(const bf16x8*)&pb_[off0];
    bf16x8 rp1 = *(const bf16x8*)&pb_[off0 + 8];
    bf16x8 rk0 = *(const bf16x8*)&kb_[off0];
    bf16x8 rk1 = *(const bf16x8*)&kb_[off0 + 8];
#pragma unroll
    for (int it = 0; it < 8; ++it) {
      __syncthreads();                      // prev tile's MFMA reads done
      *(bf16x8*)&su.pk.p[sh][sr][scg] = rp0;
      *(bf16x8*)&su.pk.p[sh][sr][scg + 8] = rp1;
      *(bf16x8*)&su.pk.k[sh][sr][scg] = rk0;
      *(bf16x8*)&su.pk.k[sh][sr][scg + 8] = rk1;
      if (it < 7) {                         // prefetch next tile (hides under MFMA)
        const size_t off = (size_t)((sh << 8) + ((it + 1) << 5) + sr) * 512 + scg;
        rp0 = *(const bf16x8*)&pb_[off];
        rp1 = *(const bf16x8*)&pb_[off + 8];
        rk0 = *(const bf16x8*)&kb_[off];
        rk1 = *(const bf16x8*)&kb_[off + 8];
      }
      __syncthreads();
      __builtin_amdgcn_s_setprio(1);
#pragma unroll
      for (int ctl = 0; ctl < 2; ++ctl) {
        // PS
        {
          const bf16x8 b0 = *(const bf16x8*)&su.pk.p[half][(ctl << 4) + lm][lk];
          const bf16x8 b1 = *(const bf16x8*)&su.pk.p[half][(ctl << 4) + lm][32 + lk];
          f32x4 a = (f32x4)(0.f);
          a = __builtin_amdgcn_mfma_f32_16x16x32_bf16(av0, b0, a, 0, 0, 0);
          a = __builtin_amdgcn_mfma_f32_16x16x32_bf16(av1, b1, a, 0, 0, 0);
          const int col = C0 + (it << 5) + (ctl << 4) + lm;
#pragma unroll
          for (int r = 0; r < 4; ++r) {
            const int idx = ((band << 4) + fr4 + r) * 513 + col;
            psl[pswz(idx)] = f2bf(a[r]);
          }
          if (ctl == band) {  // boundary row q0+32, split between bands
            f32x4 e = (f32x4)(0.f);
            e = __builtin_amdgcn_mfma_f32_16x16x32_bf16(e0, b0, e, 0, 0, 0);
            e = __builtin_amdgcn_mfma_f32_16x16x32_bf16(e1, b1, e, 0, 0, 0);
            if (g == 0) {
              const int idx = 32 * 513 + col;
              psl[pswz(idx)] = f2bf(e[0]);
            }
          }
        }
        // QK
        {
          const int lct = (it << 1) + ctl;
          const bf16x8 b0 = *(const bf16x8*)&su.pk.k[half][(ctl << 4) + lm][lk];
          const bf16x8 b1 = *(const bf16x8*)&su.pk.k[half][(ctl << 4) + lm][32 + lk];
          acc[lct] = __builtin_amdgcn_mfma_f32_16x16x32_bf16(au0, b0, acc[lct], 0, 0, 0);
          acc[lct] = __builtin_amdgcn_mfma_f32_16x16x32_bf16(au1, b1, acc[lct], 0, 0, 0);
        }
      }
      __builtin_amdgcn_s_setprio(0);
    }
  }
  __syncthreads();  // psl complete, pk reads complete

  // ======== rel-shift add via linear flat read + scale ========
  // pos[q][c] = psl_flat[qq*513 + (c-q+511)] == psl_flat[qq*512 + 511 - q0 + c]
  const float scale = 0.044194173824159216f;  // 1/sqrt(512)
  const int qq0 = (band << 4) + fr4;
#pragma unroll
  for (int r = 0; r < 4; ++r) {
    const int qq = qq0 + r;
    const int pbase = qq * 512 + 511 - q0 + C0 + lm;
#pragma unroll
    for (int lct = 0; lct < 16; ++lct) {
      const float f = bf2f(psl[pswz(pbase + (lct << 4))]);
      acc[lct][r] = (acc[lct][r] + f) * scale;
    }
  }

  // ======== softmax (intra-wave over lm; cross-half via scr) ========
  float mx[4] = {-3.0e38f, -3.0e38f, -3.0e38f, -3.0e38f};
#pragma unroll
  for (int lct = 0; lct < 16; ++lct)
#pragma unroll
    for (int r = 0; r < 4; ++r) mx[r] = fmaxf(mx[r], acc[lct][r]);
#pragma unroll
  for (int o = 1; o < 16; o <<= 1)
#pragma unroll
    for (int r = 0; r < 4; ++r) mx[r] = fmaxf(mx[r], __shfl_xor(mx[r], o));
  if (lm == 0) {
#pragma unroll
    for (int r = 0; r < 4; ++r) su.scr[half][qq0 + r] = mx[r];
  }
  __syncthreads();
#pragma unroll
  for (int r = 0; r < 4; ++r) mx[r] = fmaxf(mx[r], su.scr[half ^ 1][qq0 + r]);
  float sme[4] = {0.f, 0.f, 0.f, 0.f};
#pragma unroll
  for (int lct = 0; lct < 16; ++lct)
#pragma unroll
    for (int r = 0; r < 4; ++r) {
      acc[lct][r] = __expf(acc[lct][r] - mx[r]);
      sme[r] += acc[lct][r];
    }
#pragma unroll
  for (int o = 1; o < 16; o <<= 1)
#pragma unroll
    for (int r = 0; r < 4; ++r) sme[r] += __shfl_xor(sme[r], o);
  if (lm == 0) {
#pragma unroll
    for (int r = 0; r < 4; ++r) su.scr[2 + half][qq0 + r] = sme[r];
  }
  __syncthreads();
#pragma unroll
  for (int r = 0; r < 4; ++r) {
    const float inv = 1.f / (sme[r] + su.scr[2 + (half ^ 1)][qq0 + r]);
#pragma unroll
    for (int lct = 0; lct < 16; ++lct) acc[lct][r] *= inv;
  }
  __syncthreads();  // all psl gather reads done -> safe to carve Pl from psl

  // ======== PV + coalesced attn write: 8 chunks of 32 c per half ========
  // Pl slab per wave: [16 q][46 c] (stride 46 ush = 23 dw, odd -> conflict-free)
  ushort* Pl = psl + ((band << 1) | half) * 736;
  const ushort* vtb = vT + ((size_t)((b << 9) + (hh << 6))) * 512;
  const int vrow = t >> 1, vc = (t & 1) << 4;
  const int vh = vrow >> 6, vd = vrow & 63;
  float* abase = attn + ((size_t)z << 18);
  f32x4 acc2[4];
#pragma unroll
  for (int i = 0; i < 4; ++i) acc2[i] = (f32x4)(0.f);
  bf16x8 p0 = *(const bf16x8*)&vtb[(size_t)vd * 512 + (vh << 8) + vc];
  bf16x8 p1 = *(const bf16x8*)&vtb[(size_t)vd * 512 + (vh << 8) + vc + 8];
#pragma unroll
  for (int ch = 0; ch < 8; ++ch) {
    // P chunk -> Pl (wave-private)
#pragma unroll
    for (int ctl = 0; ctl < 2; ++ctl) {
      const int lct = (ch << 1) + ctl;
#pragma unroll
      for (int r = 0; r < 4; ++r)
        Pl[(fr4 + r) * 46 + (ctl << 4) + lm] = f2bf(acc[lct][r]);
    }
    __syncthreads();  // prev v2 reads done
    *(bf16x8*)&su.v2[vh][vd][vc] = p0;
    *(bf16x8*)&su.v2[vh][vd][vc + 8] = p1;
    if (ch < 7) {
      const size_t off = (size_t)vd * 512 + (vh << 8) + ((ch + 1) << 5) + vc;
      p0 = *(const bf16x8*)&vtb[off];
      p1 = *(const bf16x8*)&vtb[off + 8];
    }
    // attn write from Pl (float4, coalesced within rows)
    {
      const int row = lane >> 2, colg = (lane & 3) << 3;
      const ushort* ps = Pl + row * 46 + colg;
      float* ar = abase + (size_t)(q0 + (band << 4) + row) * 512 + C0 + (ch << 5) + colg;
      float4 o0, o1;
      o0.x = bf2f(ps[0]); o0.y = bf2f(ps[1]); o0.z = bf2f(ps[2]); o0.w = bf2f(ps[3]);
      o1.x = bf2f(ps[4]); o1.y = bf2f(ps[5]); o1.z = bf2f(ps[6]); o1.w = bf2f(ps[7]);
      *(float4*)&ar[0] = o0;
      *(float4*)&ar[4] = o1;
    }
    __syncthreads();  // v2 ready
    __builtin_amdgcn_s_setprio(1);
#pragma unroll
    for (int dt = 0; dt < 4; ++dt) {
      const bf16x8 va = *(const bf16x8*)&su.v2[half][(dt << 4) + lm][lk];
      const bf16x8 pbf = *(const bf16x8*)&Pl[lm * 46 + lk];
      acc2[dt] = __builtin_amdgcn_mfma_f32_16x16x32_bf16(va, pbf, acc2[dt], 0, 0, 0);
    }
    __builtin_amdgcn_s_setprio(0);
  }
  // combine col-half partials via scrC, then write ctx
  __syncthreads();
  if (half == 1) {
#pragma unroll
    for (int dt = 0; dt < 4; ++dt)
#pragma unroll
      for (int r = 0; r < 4; ++r)
        su.scrC[band][(dt << 4) + fr4 + r][lm] = acc2[dt][r];
  }
  __syncthreads();
  if (half == 0) {
    const int qq2 = q0 + (band << 4) + lm;
#pragma unroll
    for (int dt = 0; dt < 4; ++dt) {
      ushort4 o;
      o.x = f2bf(acc2[dt][0] + su.scrC[band][(dt << 4) + fr4 + 0][lm]);
      o.y = f2bf(acc2[dt][1] + su.scrC[band][(dt << 4) + fr4 + 1][lm]);
      o.z = f2bf(acc2[dt][2] + su.scrC[band][(dt << 4) + fr4 + 2][lm]);
      o.w = f2bf(acc2[dt][3] + su.scrC[band][(dt << 4) + fr4 + 3][lm]);
      *(ushort4*)&ctx[((size_t)((b << 9) + qq2)) * 512 + (hh << 6) + (dt << 4) + fr4] = o;
    }
  }
}

// ------------- depthwise conv (K=31) + BN + swish, register sliding window ------
__global__ __launch_bounds__(256) void dwconv2(const ushort* __restrict__ in,
                                               const float* __restrict__ w,
                                               const float* __restrict__ bng,
                                               const float* __restrict__ bnb,
                                               const float* __restrict__ bnm,
                                               const float* __restrict__ bnv,
                                               ushort* __restrict__ out) {
  __shared__ float wl[31][128];
  const int t = threadIdx.x;
  const int dbase = blockIdx.x << 7;
  const int b = blockIdx.z;
  const int sb = (blockIdx.y << 6) + ((t >> 6) << 4);
  if (t < 128) {
    const float* ws = &w[(dbase + t) * 31];
#pragma unroll
    for (int k = 0; k < 31; ++k) wl[k][t] = ws[k];
  }
  __syncthreads();
  const int dl = (t & 63) << 1;
  const int d = dbase + dl;
  const size_t base = (((size_t)b) << 18) + d;
  float2 win[46];
#pragma unroll
  for (int i = 0; i < 46; ++i) {
    const int s = sb - 15 + i;
    if (s >= 0 && s < 512) {
      const ushort2 u = *(const ushort2*)&in[base + ((size_t)s << 9)];
      win[i].x = bf2f(u.x); win[i].y = bf2f(u.y);
    } else {
      win[i].x = 0.f; win[i].y = 0.f;
    }
  }
  float2 acc[16];
#pragma unroll
  for (int p = 0; p < 16; ++p) { acc[p].x = 0.f; acc[p].y = 0.f; }
#pragma unroll
  for (int k = 0; k < 31; ++k) {
    const float2 w2 = *(const float2*)&wl[k][dl];
#pragma unroll
    for (int p = 0; p < 16; ++p) {
      acc[p].x = fmaf(win[p + k].x, w2.x, acc[p].x);
      acc[p].y = fmaf(win[p + k].y, w2.y, acc[p].y);
    }
  }
  const float g0 = bng[d] * rsqrtf(bnv[d] + EPSF);
  const float g1 = bng[d + 1] * rsqrtf(bnv[d + 1] + EPSF);
  const float m0 = bnm[d], m1 = bnm[d + 1];
  const float bb0 = bnb[d], bb1 = bnb[d + 1];
#pragma unroll
  for (int p = 0; p < 16; ++p) {
    float v0 = (acc[p].x - m0) * g0 + bb0;
    float v1 = (acc[p].y - m1) * g1 + bb1;
    v0 = v0 * sigmf(v0);
    v1 = v1 * sigmf(v1);
    ushort2 o;
    o.x = f2bf(v0); o.y = f2bf(v1);
    *(ushort2*)&out[base + ((size_t)(sb + p) << 9)] = o;
  }
}

extern "C" void kernel_launch(void* const* d_in, const int* in_sizes, int n_in,
                              void* d_out, int out_size, void* d_ws, size_t ws_size,
                              hipStream_t stream) {
  const float* x      = (const float*)d_in[0];
  const float* ff1_g  = (const float*)d_in[1];
  const float* ff1_b  = (const float*)d_in[2];
  const float* ff1_w1 = (const float*)d_in[3];
  const float* ff1_b1 = (const float*)d_in[4];
  const float* ff1_w2 = (const float*)d_in[5];
  const float* ff1_b2 = (const float*)d_in[6];
  const float* attn_g = (const float*)d_in[7];
  const float* attn_b = (const float*)d_in[8];
  const float* wq     = (const float*)d_in[9];
  const float* bq     = (const float*)d_in[10];
  const float* wk     = (const float*)d_in[11];
  const float* bk     = (const float*)d_in[12];
  const float* wv     = (const float*)d_in[13];
  const float* bv     = (const float*)d_in[14];
  const float* wpos   = (const float*)d_in[15];
  const float* u_bias = (const float*)d_in[16];
  const float* v_bias = (const float*)d_in[17];
  const float* wo     = (const float*)d_in[18];
  const float* bo     = (const float*)d_in[19];
  const float* conv_g = (const float*)d_in[20];
  const float* conv_b = (const float*)d_in[21];
  const float* pw1_w  = (const float*)d_in[22];
  const float* pw1_b  = (const float*)d_in[23];
  const float* dw_w   = (const float*)d_in[24];
  const float* bn_g   = (const float*)d_in[25];
  const float* bn_b   = (const float*)d_in[26];
  const float* bn_m   = (const float*)d_in[27];
  const float* bn_v   = (const float*)d_in[28];
  const float* pw2_w  = (const float*)d_in[29];
  const float* pw2_b  = (const float*)d_in[30];
  const float* ff2_g  = (const float*)d_in[31];
  const float* ff2_b  = (const float*)d_in[32];
  const float* ff2_w1 = (const float*)d_in[33];
  const float* ff2_b1 = (const float*)d_in[34];
  const float* ff2_w2 = (const float*)d_in[35];
  const float* ff2_b2 = (const float*)d_in[36];
  const float* ln_g   = (const float*)d_in[37];
  const float* ln_b   = (const float*)d_in[38];

  float* out  = (float*)d_out;            // [B,S,D] f32
  float* attn = out + ND;                 // [B,H,S,S] f32

  float*  res  = (float*)d_ws;
  ushort* ybf  = (ushort*)(res + ND);
  float*  big  = (float*)(ybf + ND);             // 2*ND f32 region
  ushort* vT   = (ushort*)(big + 2 * ND);        // ND ushorts [b][col][s]
  ushort* dwbf = vT + ND;                        // ND ushorts
  ushort* wts  = dwbf + ND;                      // 6,291,456 ushorts
  ushort* pebf = wts + 6291456;                  // 262,144
  ushort* ppbf = pebf + 262144;                  // 262,144

  ushort* ffmid = (ushort*)big;
  ushort* qu    = (ushort*)big;
  ushort* qv    = qu + ND;
  ushort* kbb   = qv + ND;
  ushort* ctxbf = ybf;
  ushort* glubf = (ushort*)big;

  ushort* ff1w1t = wts;
  ushort* ff1w2t = wts + 1048576;
  ushort* wqt    = wts + 2097152;
  ushort* wkt    = wts + 2359296;
  ushort* wvt    = wts + 2621440;
  ushort* wot    = wts + 2883584;
  ushort* pw1t   = wts + 3145728;
  ushort* pw2t   = wts + 3670016;
  ushort* ff2w1t = wts + 3932160;
  ushort* ff2w2t = wts + 4980736;
  ushort* wpost  = wts + 6029312;

  const dim3 blk(256);

  // ---- weight prep: single merged transpose dispatch ----
  TpArgs ta;
  auto set = [&](int i, const float* s, ushort* d, int K, int N) {
    ta.src[i] = s; ta.dst[i] = d; ta.K[i] = K; ta.N[i] = N;
  };
  set(0, ff1_w1, ff1w1t, 512, 2048);
  set(1, ff1_w2, ff1w2t, 2048, 512);
  set(2, wq, wqt, 512, 512);
  set(3, wk, wkt, 512, 512);
  set(4, wv, wvt, 512, 512);
  set(5, wo, wot, 512, 512);
  set(6, wpos, wpost, 512, 512);
  set(7, pw1_w, pw1t, 512, 1024);
  set(8, pw2_w, pw2t, 512, 512);
  set(9, ff2_w1, ff2w1t, 512, 2048);
  set(10, ff2_w2, ff2w2t, 2048, 512);
  int tacc = 0;
  for (int i = 0; i < 11; ++i) { ta.base[i] = tacc; tacc += (ta.N[i] >> 5) * (ta.K[i] >> 5); }
  ta.base[11] = tacc;
  transpose_all<<<tacc, blk, 0, stream>>>(ta);
  pe_kernel_bf16<<<512, blk, 0, stream>>>(pebf);
  gemm_bf16<0, 0, 0, 1><<<dim3(4, 4), blk, 0, stream>>>(pebf, wpost, nullptr, nullptr, ppbf,
                                                        512, 512, 512);

  // ---- Macaron FF1: res = x + 0.5*FF(LN(x)) ----
  ln_bf16<<<NTOK / 4, blk, 0, stream>>>(x, ff1_g, ff1_b, ybf);
  gemm_bf16<1, 0, 1, 1><<<dim3(16, 128), blk, 0, stream>>>(ybf, ff1w1t, ff1_b1, nullptr, ffmid,
                                                           NTOK, 512, 2048);
  gemm_bf16<0, 2, 1, 0><<<dim3(4, 128), blk, 0, stream>>>(ffmid, ff1w2t, ff1_b2, x, res,
                                                          NTOK, 2048, 512);

  // ---- Attention ----
  ln_bf16<<<NTOK / 4, blk, 0, stream>>>(res, attn_g, attn_b, ybf);
  gemm_qkv<<<dim3(12, 128), blk, 0, stream>>>(ybf, wqt, bq, bk, bv, u_bias, v_bias,
                                              qu, qv, kbb, vT, NTOK, 512);
  attn_fused8<<<dim3(16, 256), blk, 0, stream>>>(qu, qv, kbb, ppbf, vT, attn, ctxbf);
  gemm_bf16<0, 1, 1, 0><<<dim3(4, 128), blk, 0, stream>>>(ctxbf, wot, bo, res, res,
                                                          NTOK, 512, 512);

  // ---- Conv module ----
  ln_bf16<<<NTOK / 4, blk, 0, stream>>>(res, conv_g, conv_b, ybf);
  gemm_glu<<<dim3(4, 128), blk, 0, stream>>>(ybf, pw1t, pw1_b, glubf, NTOK, 512);
  dwconv2<<<dim3(4, 8, 32), blk, 0, stream>>>(glubf, dw_w, bn_g, bn_b, bn_m, bn_v, dwbf);
  gemm_bf16<0, 1, 1, 0><<<dim3(4, 128), blk, 0, stream>>>(dwbf, pw2t, pw2_b, res, res,
                                                          NTOK, 512, 512);

  // ---- Macaron FF2 + final LN ----
  ln_bf16<<<NTOK / 4, blk, 0, stream>>>(res, ff2_g, ff2_b, ybf);
  gemm_bf16<1, 0, 1, 1><<<dim3(16, 128), blk, 0, stream>>>(ybf, ff2w1t, ff2_b1, nullptr, ffmid,
                                                           NTOK, 512, 2048);
  gemm_bf16<0, 2, 1, 0><<<dim3(4, 128), blk, 0, stream>>>(ffmid, ff2w2t, ff2_b2, res, res,
                                                          NTOK, 2048, 512);
  ln_f32<<<NTOK / 4, blk, 0, stream>>>(res, ln_g, ln_b, out);
}

// Round 12
// 693.408 us; speedup vs baseline: 1.3860x; 1.0364x over previous
//
#include <hip/hip_runtime.h>
#include <cstddef>
#include <cstdint>

#define EPSF 1e-5f

constexpr int BB = 32, SS = 512, DD = 512, HH = 8, DH = 64;
constexpr int NTOK = BB * SS;              // 16384 rows
constexpr size_t ND = (size_t)NTOK * DD;   // 8,388,608

typedef __attribute__((ext_vector_type(8))) short bf16x8;
typedef __attribute__((ext_vector_type(4))) float f32x4;

__device__ __forceinline__ float sigmf(float v) { return 1.f / (1.f + __expf(-v)); }

__device__ __forceinline__ ushort f2bf(float f) {
  union { float f; uint32_t u; } x{f};
  uint32_t r = x.u + 0x7FFF + ((x.u >> 16) & 1);
  return (ushort)(r >> 16);
}
__device__ __forceinline__ float bf2f(ushort u) {
  union { uint32_t u; float f; } x{(uint32_t)u << 16};
  return x.f;
}

__device__ __forceinline__ void gload16(const ushort* g, ushort* ldsbase) {
  __builtin_amdgcn_global_load_lds((const __attribute__((address_space(1))) void*)g,
                                   (__attribute__((address_space(3))) void*)ldsbase, 16, 0, 0);
}

// bijective XCD-chunk swizzle (m204); requires nwg % 8 == 0.
__device__ __forceinline__ void xcd_swz(int& bx, int& by) {
  const int gx = gridDim.x;
  const int nwg = gx * gridDim.y;
  const int cpx = nwg >> 3;
  int id = by * gx + bx;
  id = (id & 7) * cpx + (id >> 3);
  bx = id % gx;
  by = id / gx;
}

// psl index swizzle: XOR bits 4-5 with bits 11-12 (bits 11-12 unmodified -> bijective)
__device__ __forceinline__ int pswz(int idx) {
  return idx ^ (((idx >> 11) & 3) << 4);
}

// ---------------- LayerNorm f32-in bf16-out (FF1 entry) -------------------------
__global__ __launch_bounds__(256) void ln_bf16(const float* __restrict__ x,
                                               const float* __restrict__ g,
                                               const float* __restrict__ b,
                                               ushort* __restrict__ y) {
  const int lane = threadIdx.x & 63;
  const int row = blockIdx.x * 4 + (threadIdx.x >> 6);
  const float* xr = x + (size_t)row * 512;
  const float4 v0 = *(const float4*)&xr[lane << 3];
  const float4 v1 = *(const float4*)&xr[(lane << 3) + 4];
  float f[8] = {v0.x, v0.y, v0.z, v0.w, v1.x, v1.y, v1.z, v1.w};
  float s = 0.f;
#pragma unroll
  for (int k = 0; k < 8; ++k) s += f[k];
#pragma unroll
  for (int o = 32; o > 0; o >>= 1) s += __shfl_xor(s, o);
  const float mean = s * (1.f / 512.f);
  float q = 0.f;
#pragma unroll
  for (int k = 0; k < 8; ++k) q += (f[k] - mean) * (f[k] - mean);
#pragma unroll
  for (int o = 32; o > 0; o >>= 1) q += __shfl_xor(q, o);
  const float rs = rsqrtf(q * (1.f / 512.f) + EPSF);
  const float4 g0 = *(const float4*)&g[lane << 3];
  const float4 g1 = *(const float4*)&g[(lane << 3) + 4];
  const float4 b0 = *(const float4*)&b[lane << 3];
  const float4 b1 = *(const float4*)&b[(lane << 3) + 4];
  const float gg[8] = {g0.x, g0.y, g0.z, g0.w, g1.x, g1.y, g1.z, g1.w};
  const float bb[8] = {b0.x, b0.y, b0.z, b0.w, b1.x, b1.y, b1.z, b1.w};
  ushort tmp[8];
#pragma unroll
  for (int k = 0; k < 8; ++k) tmp[k] = f2bf((f[k] - mean) * rs * gg[k] + bb[k]);
  *(bf16x8*)&y[(size_t)row * 512 + (lane << 3)] = *(bf16x8*)tmp;
}

// ---------------- LayerNorm bf16-in bf16-out ------------------------------------
__global__ __launch_bounds__(256) void lnb_bf16(const ushort* __restrict__ x,
                                                const float* __restrict__ g,
                                                const float* __restrict__ b,
                                                ushort* __restrict__ y) {
  const int lane = threadIdx.x & 63;
  const int row = blockIdx.x * 4 + (threadIdx.x >> 6);
  const bf16x8 v = *(const bf16x8*)&x[(size_t)row * 512 + (lane << 3)];
  float f[8];
#pragma unroll
  for (int k = 0; k < 8; ++k) f[k] = bf2f((ushort)v[k]);
  float s = 0.f;
#pragma unroll
  for (int k = 0; k < 8; ++k) s += f[k];
#pragma unroll
  for (int o = 32; o > 0; o >>= 1) s += __shfl_xor(s, o);
  const float mean = s * (1.f / 512.f);
  float q = 0.f;
#pragma unroll
  for (int k = 0; k < 8; ++k) q += (f[k] - mean) * (f[k] - mean);
#pragma unroll
  for (int o = 32; o > 0; o >>= 1) q += __shfl_xor(q, o);
  const float rs = rsqrtf(q * (1.f / 512.f) + EPSF);
  const float4 g0 = *(const float4*)&g[lane << 3];
  const float4 g1 = *(const float4*)&g[(lane << 3) + 4];
  const float4 b0 = *(const float4*)&b[lane << 3];
  const float4 b1 = *(const float4*)&b[(lane << 3) + 4];
  const float gg[8] = {g0.x, g0.y, g0.z, g0.w, g1.x, g1.y, g1.z, g1.w};
  const float bb[8] = {b0.x, b0.y, b0.z, b0.w, b1.x, b1.y, b1.z, b1.w};
  ushort tmp[8];
#pragma unroll
  for (int k = 0; k < 8; ++k) tmp[k] = f2bf((f[k] - mean) * rs * gg[k] + bb[k]);
  *(bf16x8*)&y[(size_t)row * 512 + (lane << 3)] = *(bf16x8*)tmp;
}

// ---------------- final LayerNorm bf16-in f32-out --------------------------------
__global__ __launch_bounds__(256) void lnb_f32(const ushort* __restrict__ x,
                                               const float* __restrict__ g,
                                               const float* __restrict__ b,
                                               float* __restrict__ y) {
  const int lane = threadIdx.x & 63;
  const int row = blockIdx.x * 4 + (threadIdx.x >> 6);
  const bf16x8 v = *(const bf16x8*)&x[(size_t)row * 512 + (lane << 3)];
  float f[8];
#pragma unroll
  for (int k = 0; k < 8; ++k) f[k] = bf2f((ushort)v[k]);
  float s = 0.f;
#pragma unroll
  for (int k = 0; k < 8; ++k) s += f[k];
#pragma unroll
  for (int o = 32; o > 0; o >>= 1) s += __shfl_xor(s, o);
  const float mean = s * (1.f / 512.f);
  float q = 0.f;
#pragma unroll
  for (int k = 0; k < 8; ++k) q += (f[k] - mean) * (f[k] - mean);
#pragma unroll
  for (int o = 32; o > 0; o >>= 1) q += __shfl_xor(q, o);
  const float rs = rsqrtf(q * (1.f / 512.f) + EPSF);
  const float4 g0 = *(const float4*)&g[lane << 3];
  const float4 g1 = *(const float4*)&g[(lane << 3) + 4];
  const float4 b0 = *(const float4*)&b[lane << 3];
  const float4 b1 = *(const float4*)&b[(lane << 3) + 4];
  const float gg[8] = {g0.x, g0.y, g0.z, g0.w, g1.x, g1.y, g1.z, g1.w};
  const float bb[8] = {b0.x, b0.y, b0.z, b0.w, b1.x, b1.y, b1.z, b1.w};
  float* yr = y + (size_t)row * 512 + (lane << 3);
  float4 o0, o1;
  o0.x = (f[0] - mean) * rs * gg[0] + bb[0]; o0.y = (f[1] - mean) * rs * gg[1] + bb[1];
  o0.z = (f[2] - mean) * rs * gg[2] + bb[2]; o0.w = (f[3] - mean) * rs * gg[3] + bb[3];
  o1.x = (f[4] - mean) * rs * gg[4] + bb[4]; o1.y = (f[5] - mean) * rs * gg[5] + bb[5];
  o1.z = (f[6] - mean) * rs * gg[6] + bb[6]; o1.w = (f[7] - mean) * rs * gg[7] + bb[7];
  *(float4*)&yr[0] = o0;
  *(float4*)&yr[4] = o1;
}

// ---------------- merged weight transpose: 11 segments, one dispatch ------------
struct TpArgs {
  const float* src[11];
  ushort* dst[11];
  int K[11];
  int N[11];
  int base[12];
};

__global__ __launch_bounds__(256) void transpose_all(TpArgs a) {
  __shared__ float tile[32][33];
  int s = 0;
  const int bid = blockIdx.x;
  while (s < 10 && bid >= a.base[s + 1]) ++s;
  const int r = bid - a.base[s];
  const int K = a.K[s], N = a.N[s];
  const int ntx = N >> 5;
  const int n0 = (r % ntx) << 5;
  const int k0 = (r / ntx) << 5;
  const float* in = a.src[s];
  ushort* out = a.dst[s];
  const int tx = threadIdx.x & 31, ty = threadIdx.x >> 5;
#pragma unroll
  for (int i = 0; i < 32; i += 8)
    tile[ty + i][tx] = in[(size_t)(k0 + ty + i) * N + n0 + tx];
  __syncthreads();
#pragma unroll
  for (int i = 0; i < 32; i += 8)
    out[(size_t)(n0 + ty + i) * K + k0 + tx] = f2bf(tile[tx][ty + i]);
}

// ---------------- bf16 MFMA GEMM, T3-minimum 2-phase double-buffer --------------
// RSRC: 0 = res buffer is f32, 1 = res buffer is bf16.
template <int ACT, int RES, int HB, int OBF, int RSRC>
__global__ __launch_bounds__(256) void gemm_bf16(const ushort* __restrict__ A,
                                                 const ushort* __restrict__ Wt,
                                                 const float* __restrict__ bias,
                                                 const void* __restrict__ res,
                                                 void* __restrict__ Cv,
                                                 int M, int K, int N) {
  __shared__ ushort Al[2][8192];
  __shared__ ushort Bl[2][8192];
  const int t = threadIdx.x;
  const int lane = t & 63;
  const int w = t >> 6;
  const int wr = (w >> 1) << 6, wc = (w & 1) << 6;
  int bx = blockIdx.x, by = blockIdx.y;
  xcd_swz(bx, by);
  const int m0 = by << 7, n0 = bx << 7;
  const int lm = lane & 15;
  const int grow = lane >> 3;
  const int gcol = (lane & 7) << 3;

  f32x4 acc[4][4];
#pragma unroll
  for (int i = 0; i < 4; ++i)
#pragma unroll
    for (int j = 0; j < 4; ++j) acc[i][j] = (f32x4)(0.f);

  const int NT = K >> 6;
#pragma unroll
  for (int i = 0; i < 4; ++i) {
    const int s = (w << 2) + i;
    gload16(A + (size_t)(m0 + (s << 3) + grow) * K + gcol, &Al[0][s << 9]);
    gload16(Wt + (size_t)(n0 + (s << 3) + grow) * K + gcol, &Bl[0][s << 9]);
  }
  __syncthreads();
  int cur = 0;
  for (int tt = 0; tt < NT; ++tt) {
    if (tt + 1 < NT) {
      const int k0 = (tt + 1) << 6;
#pragma unroll
      for (int i = 0; i < 4; ++i) {
        const int s = (w << 2) + i;
        gload16(A + (size_t)(m0 + (s << 3) + grow) * K + k0 + gcol, &Al[cur ^ 1][s << 9]);
        gload16(Wt + (size_t)(n0 + (s << 3) + grow) * K + k0 + gcol, &Bl[cur ^ 1][s << 9]);
      }
    }
#pragma unroll
    for (int ks = 0; ks < 2; ++ks) {
      const int kof = (ks << 5) + ((lane >> 4) << 3);
      bf16x8 af[4], bfr[4];
#pragma unroll
      for (int i = 0; i < 4; ++i) af[i] = *(const bf16x8*)&Al[cur][(wr + (i << 4) + lm) * 64 + kof];
#pragma unroll
      for (int j = 0; j < 4; ++j) bfr[j] = *(const bf16x8*)&Bl[cur][(wc + (j << 4) + lm) * 64 + kof];
#pragma unroll
      for (int i = 0; i < 4; ++i)
#pragma unroll
        for (int j = 0; j < 4; ++j)
          acc[i][j] = __builtin_amdgcn_mfma_f32_16x16x32_bf16(af[i], bfr[j], acc[i][j], 0, 0, 0);
    }
    __syncthreads();
    cur ^= 1;
  }

  float bb[4] = {0.f, 0.f, 0.f, 0.f};
  if (HB) {
#pragma unroll
    for (int j = 0; j < 4; ++j) bb[j] = bias[n0 + wc + j * 16 + lm];
  }
  const int rbase = m0 + wr + ((lane >> 4) << 2);
#pragma unroll
  for (int i = 0; i < 4; ++i) {
#pragma unroll
    for (int r = 0; r < 4; ++r) {
      const size_t row = (size_t)(rbase + i * 16 + r);
#pragma unroll
      for (int j = 0; j < 4; ++j) {
        const int col = n0 + wc + j * 16 + lm;
        float v = acc[i][j][r] + bb[j];
        if (ACT == 1) v = v * sigmf(v);
        if (RES == 1 || RES == 2) {
          float rv;
          if (RSRC) rv = bf2f(((const ushort*)res)[row * N + col]);
          else rv = ((const float*)res)[row * N + col];
          v = (RES == 1) ? (rv + v) : (rv + 0.5f * v);
        }
        if (OBF) ((ushort*)Cv)[row * N + col] = f2bf(v);
        else ((float*)Cv)[row * N + col] = v;
      }
    }
  }
}

// ---------------- merged QKV projection: N=1536, routed epilogue ----------------
__global__ __launch_bounds__(256) void gemm_qkv(const ushort* __restrict__ A,
                                                const ushort* __restrict__ Wt,
                                                const float* __restrict__ bq,
                                                const float* __restrict__ bk,
                                                const float* __restrict__ bv,
                                                const float* __restrict__ ub,
                                                const float* __restrict__ vb,
                                                ushort* __restrict__ qu,
                                                ushort* __restrict__ qv,
                                                ushort* __restrict__ kbb,
                                                ushort* __restrict__ vT,
                                                int M, int K) {
  __shared__ ushort Al[2][8192];
  __shared__ ushort Bl[2][8192];
  const int t = threadIdx.x;
  const int lane = t & 63;
  const int w = t >> 6;
  const int wr = (w >> 1) << 6, wc = (w & 1) << 6;
  int bx = blockIdx.x, by = blockIdx.y;
  xcd_swz(bx, by);
  const int m0 = by << 7, n0 = bx << 7;
  const int lm = lane & 15;
  const int grow = lane >> 3;
  const int gcol = (lane & 7) << 3;
  f32x4 acc[4][4];
#pragma unroll
  for (int i = 0; i < 4; ++i)
#pragma unroll
    for (int j = 0; j < 4; ++j) acc[i][j] = (f32x4)(0.f);
  const int NT = K >> 6;
#pragma unroll
  for (int i = 0; i < 4; ++i) {
    const int s = (w << 2) + i;
    gload16(A + (size_t)(m0 + (s << 3) + grow) * K + gcol, &Al[0][s << 9]);
    gload16(Wt + (size_t)(n0 + (s << 3) + grow) * K + gcol, &Bl[0][s << 9]);
  }
  __syncthreads();
  int cur = 0;
  for (int tt = 0; tt < NT; ++tt) {
    if (tt + 1 < NT) {
      const int k0 = (tt + 1) << 6;
#pragma unroll
      for (int i = 0; i < 4; ++i) {
        const int s = (w << 2) + i;
        gload16(A + (size_t)(m0 + (s << 3) + grow) * K + k0 + gcol, &Al[cur ^ 1][s << 9]);
        gload16(Wt + (size_t)(n0 + (s << 3) + grow) * K + k0 + gcol, &Bl[cur ^ 1][s << 9]);
      }
    }
#pragma unroll
    for (int ks = 0; ks < 2; ++ks) {
      const int kof = (ks << 5) + ((lane >> 4) << 3);
      bf16x8 af[4], bfr[4];
#pragma unroll
      for (int i = 0; i < 4; ++i) af[i] = *(const bf16x8*)&Al[cur][(wr + (i << 4) + lm) * 64 + kof];
#pragma unroll
      for (int j = 0; j < 4; ++j) bfr[j] = *(const bf16x8*)&Bl[cur][(wc + (j << 4) + lm) * 64 + kof];
#pragma unroll
      for (int i = 0; i < 4; ++i)
#pragma unroll
        for (int j = 0; j < 4; ++j)
          acc[i][j] = __builtin_amdgcn_mfma_f32_16x16x32_bf16(af[i], bfr[j], acc[i][j], 0, 0, 0);
    }
    __syncthreads();
    cur ^= 1;
  }
  const int seg = n0 >> 9;                 // block-uniform: 0=q, 1=k, 2=v
  const int nloc = n0 & 511;
  const float* bsel = (seg == 0) ? bq : (seg == 1 ? bk : bv);
  float bb[4], uu[4], vv[4];
#pragma unroll
  for (int j = 0; j < 4; ++j) {
    const int col = nloc + wc + j * 16 + lm;
    bb[j] = bsel[col];
    if (seg == 0) { uu[j] = ub[col]; vv[j] = vb[col]; }
  }
  const int rbase = m0 + wr + ((lane >> 4) << 2);
  if (seg == 2) {
    const int bloc = m0 >> 9;
    const int sbase = rbase - (bloc << 9);
#pragma unroll
    for (int i = 0; i < 4; ++i) {
#pragma unroll
      for (int j = 0; j < 4; ++j) {
        const int col = nloc + wc + j * 16 + lm;
        ushort4 o;
        o.x = f2bf(acc[i][j][0] + bb[j]);
        o.y = f2bf(acc[i][j][1] + bb[j]);
        o.z = f2bf(acc[i][j][2] + bb[j]);
        o.w = f2bf(acc[i][j][3] + bb[j]);
        *(ushort4*)&vT[((size_t)((bloc << 9) + col)) * 512 + sbase + i * 16] = o;
      }
    }
    return;
  }
#pragma unroll
  for (int i = 0; i < 4; ++i) {
#pragma unroll
    for (int r = 0; r < 4; ++r) {
      const size_t row = (size_t)(rbase + i * 16 + r);
#pragma unroll
      for (int j = 0; j < 4; ++j) {
        const int col = nloc + wc + j * 16 + lm;
        const float v = acc[i][j][r] + bb[j];
        if (seg == 0) {
          qu[row * 512 + col] = f2bf(v + uu[j]);
          qv[row * 512 + col] = f2bf(v + vv[j]);
        } else {
          kbb[row * 512 + col] = f2bf(v);
        }
      }
    }
  }
}

// ---------------- pw1 + GLU fused ----------------------------------------------
__global__ __launch_bounds__(256) void gemm_glu(const ushort* __restrict__ A,
                                                const ushort* __restrict__ Wt,
                                                const float* __restrict__ bias,
                                                ushort* __restrict__ Cout,
                                                int M, int K) {
  __shared__ ushort Al[8192];
  __shared__ ushort Ba[8192];
  __shared__ ushort Bg[8192];
  const int t = threadIdx.x;
  const int lane = t & 63;
  const int w = t >> 6;
  const int wr = (w >> 1) << 6, wc = (w & 1) << 6;
  int bx = blockIdx.x, by = blockIdx.y;
  xcd_swz(bx, by);
  const int m0 = by << 7, n0 = bx << 7;
  const int lm = lane & 15;
  const int grow = lane >> 3;
  const int gcol = (lane & 7) << 3;
  const ushort* WtA = Wt;
  const ushort* WtG = Wt + (size_t)512 * 512;
  f32x4 acca[4][4], accg[4][4];
#pragma unroll
  for (int i = 0; i < 4; ++i)
#pragma unroll
    for (int j = 0; j < 4; ++j) { acca[i][j] = (f32x4)(0.f); accg[i][j] = (f32x4)(0.f); }
  const int NT = K >> 6;
  for (int tt = 0; tt < NT; ++tt) {
    const int k0 = tt << 6;
    if (tt) __syncthreads();
#pragma unroll
    for (int i = 0; i < 4; ++i) {
      const int s = (w << 2) + i;
      gload16(A + (size_t)(m0 + (s << 3) + grow) * K + k0 + gcol, &Al[s << 9]);
      gload16(WtA + (size_t)(n0 + (s << 3) + grow) * K + k0 + gcol, &Ba[s << 9]);
      gload16(WtG + (size_t)(n0 + (s << 3) + grow) * K + k0 + gcol, &Bg[s << 9]);
    }
    __syncthreads();
#pragma unroll
    for (int ks = 0; ks < 2; ++ks) {
      const int kof = (ks << 5) + ((lane >> 4) << 3);
      bf16x8 af[4], ba4[4], bg4[4];
#pragma unroll
      for (int i = 0; i < 4; ++i) af[i] = *(const bf16x8*)&Al[(wr + (i << 4) + lm) * 64 + kof];
#pragma unroll
      for (int j = 0; j < 4; ++j) {
        ba4[j] = *(const bf16x8*)&Ba[(wc + (j << 4) + lm) * 64 + kof];
        bg4[j] = *(const bf16x8*)&Bg[(wc + (j << 4) + lm) * 64 + kof];
      }
#pragma unroll
      for (int i = 0; i < 4; ++i)
#pragma unroll
        for (int j = 0; j < 4; ++j) {
          acca[i][j] = __builtin_amdgcn_mfma_f32_16x16x32_bf16(af[i], ba4[j], acca[i][j], 0, 0, 0);
          accg[i][j] = __builtin_amdgcn_mfma_f32_16x16x32_bf16(af[i], bg4[j], accg[i][j], 0, 0, 0);
        }
    }
  }
  float bba[4], bbg[4];
#pragma unroll
  for (int j = 0; j < 4; ++j) {
    const int col = n0 + wc + j * 16 + lm;
    bba[j] = bias[col];
    bbg[j] = bias[512 + col];
  }
  const int rbase = m0 + wr + ((lane >> 4) << 2);
#pragma unroll
  for (int i = 0; i < 4; ++i) {
#pragma unroll
    for (int r = 0; r < 4; ++r) {
      const size_t row = (size_t)(rbase + i * 16 + r);
#pragma unroll
      for (int j = 0; j < 4; ++j) {
        const int col = n0 + wc + j * 16 + lm;
        const float va = acca[i][j][r] + bba[j];
        const float vg = accg[i][j][r] + bbg[j];
        Cout[row * 512 + col] = f2bf(va * sigmf(vg));
      }
    }
  }
}

// ------------- Sinusoidal PE (bf16) ---------------------------------------------
__global__ void pe_kernel_bf16(ushort* __restrict__ pe) {
  const int pos = blockIdx.x, ii = threadIdx.x;
  const float ang = (float)pos * powf(10000.f, -(float)(2 * ii) / 512.f);
  pe[((size_t)pos << 9) + 2 * ii] = f2bf(sinf(ang));
  pe[((size_t)pos << 9) + 2 * ii + 1] = f2bf(cosf(ang));
}

// ------------- fused attention v9: 16B-aligned Pl slabs + b128 attn-write -------
// grid (16, 256). LDS = psl 34.0KB + su 18.4KB = 52.5KB -> 3 blocks/CU.
__global__ __launch_bounds__(256, 3) void attn_fused9(const ushort* __restrict__ qu,
                                                      const ushort* __restrict__ qv,
                                                      const ushort* __restrict__ kbb,
                                                      const ushort* __restrict__ ppb,
                                                      const ushort* __restrict__ vT,
                                                      float* __restrict__ attn,
                                                      ushort* __restrict__ ctx) {
  __shared__ ushort psl[17024];        // flat PS: row qq at qq*513, col 512 = 0
  __shared__ union StU {
    struct { ushort p[2][32][72]; ushort k[2][32][72]; } pk;  // 18,432 B
    ushort v2[2][64][40];              // V staging per col-half
    float scr[4][32];                  // softmax cross-half scratch
    float scrC[2][64][17];             // PV partial combine (padded stride)
  } su;
  const int t = threadIdx.x, lane = t & 63, w = t >> 6;
  int bx = blockIdx.x, by = blockIdx.y;
  xcd_swz(bx, by);                     // 16 q-blocks of a z land on same XCD
  const int z = by, b = z >> 3, hh = z & 7;
  const int q0 = bx << 5;
  const int band = w >> 1, half = w & 1;
  const int lm = lane & 15, g = lane >> 4;
  const int lk = g << 3, fr4 = g << 2;
  const int C0 = half << 8;

  if (t < 33) {
    const int zi = t * 513 + 512;
    psl[pswz(zi)] = 0;
  }

  const size_t qoff = ((size_t)((b << 9) + q0 + (band << 4) + lm)) * 512 + (hh << 6);
  const bf16x8 av0 = *(const bf16x8*)&qv[qoff + lk];
  const bf16x8 av1 = *(const bf16x8*)&qv[qoff + lk + 32];
  const bf16x8 au0 = *(const bf16x8*)&qu[qoff + lk];
  const bf16x8 au1 = *(const bf16x8*)&qu[qoff + lk + 32];
  int er = q0 + 32 + lm;
  if (er > 511) er = 511;
  const size_t eoff = ((size_t)((b << 9) + er)) * 512 + (hh << 6);
  const bf16x8 e0 = *(const bf16x8*)&qv[eoff + lk];
  const bf16x8 e1 = *(const bf16x8*)&qv[eoff + lk + 32];

  const int srow = t >> 2, scg = (t & 3) << 4;
  const int sh = srow >> 5, sr = srow & 31;

  // ======== merged PS + QK pass ========
  f32x4 acc[16];
#pragma unroll
  for (int i = 0; i < 16; ++i) acc[i] = (f32x4)(0.f);
  {
    const ushort* pb_ = ppb + (hh << 6);
    const ushort* kb_ = kbb + ((size_t)(b << 9)) * 512 + (hh << 6);
    const size_t off0 = (size_t)((sh << 8) + sr) * 512 + scg;
    bf16x8 rp0 = *(const bf16x8*)&pb_[off0];
    bf16x8 rp1 = *(const bf16x8*)&pb_[off0 + 8];
    bf16x8 rk0 = *(const bf16x8*)&kb_[off0];
    bf16x8 rk1 = *(const bf16x8*)&kb_[off0 + 8];
#pragma unroll
    for (int it = 0; it < 8; ++it) {
      __syncthreads();
      *(bf16x8*)&su.pk.p[sh][sr][scg] = rp0;
      *(bf16x8*)&su.pk.p[sh][sr][scg + 8] = rp1;
      *(bf16x8*)&su.pk.k[sh][sr][scg] = rk0;
      *(bf16x8*)&su.pk.k[sh][sr][scg + 8] = rk1;
      if (it < 7) {
        const size_t off = (size_t)((sh << 8) + ((it + 1) << 5) + sr) * 512 + scg;
        rp0 = *(const bf16x8*)&pb_[off];
        rp1 = *(const bf16x8*)&pb_[off + 8];
        rk0 = *(const bf16x8*)&kb_[off];
        rk1 = *(const bf16x8*)&kb_[off + 8];
      }
      __syncthreads();
      __builtin_amdgcn_s_setprio(1);
#pragma unroll
      for (int ctl = 0; ctl < 2; ++ctl) {
        {
          const bf16x8 b0 = *(const bf16x8*)&su.pk.p[half][(ctl << 4) + lm][lk];
          const bf16x8 b1 = *(const bf16x8*)&su.pk.p[half][(ctl << 4) + lm][32 + lk];
          f32x4 a = (f32x4)(0.f);
          a = __builtin_amdgcn_mfma_f32_16x16x32_bf16(av0, b0, a, 0, 0, 0);
          a = __builtin_amdgcn_mfma_f32_16x16x32_bf16(av1, b1, a, 0, 0, 0);
          const int col = C0 + (it << 5) + (ctl << 4) + lm;
#pragma unroll
          for (int r = 0; r < 4; ++r) {
            const int idx = ((band << 4) + fr4 + r) * 513 + col;
            psl[pswz(idx)] = f2bf(a[r]);
          }
          if (ctl == band) {
            f32x4 e = (f32x4)(0.f);
            e = __builtin_amdgcn_mfma_f32_16x16x32_bf16(e0, b0, e, 0, 0, 0);
            e = __builtin_amdgcn_mfma_f32_16x16x32_bf16(e1, b1, e, 0, 0, 0);
            if (g == 0) {
              const int idx = 32 * 513 + col;
              psl[pswz(idx)] = f2bf(e[0]);
            }
          }
        }
        {
          const int lct = (it << 1) + ctl;
          const bf16x8 b0 = *(const bf16x8*)&su.pk.k[half][(ctl << 4) + lm][lk];
          const bf16x8 b1 = *(const bf16x8*)&su.pk.k[half][(ctl << 4) + lm][32 + lk];
          acc[lct] = __builtin_amdgcn_mfma_f32_16x16x32_bf16(au0, b0, acc[lct], 0, 0, 0);
          acc[lct] = __builtin_amdgcn_mfma_f32_16x16x32_bf16(au1, b1, acc[lct], 0, 0, 0);
        }
      }
      __builtin_amdgcn_s_setprio(0);
    }
  }
  __syncthreads();

  // ======== rel-shift add via linear flat read + scale ========
  const float scale = 0.044194173824159216f;  // 1/sqrt(512)
  const int qq0 = (band << 4) + fr4;
#pragma unroll
  for (int r = 0; r < 4; ++r) {
    const int qq = qq0 + r;
    const int pbase = qq * 512 + 511 - q0 + C0 + lm;
#pragma unroll
    for (int lct = 0; lct < 16; ++lct) {
      const float f = bf2f(psl[pswz(pbase + (lct << 4))]);
      acc[lct][r] = (acc[lct][r] + f) * scale;
    }
  }

  // ======== softmax ========
  float mx[4] = {-3.0e38f, -3.0e38f, -3.0e38f, -3.0e38f};
#pragma unroll
  for (int lct = 0; lct < 16; ++lct)
#pragma unroll
    for (int r = 0; r < 4; ++r) mx[r] = fmaxf(mx[r], acc[lct][r]);
#pragma unroll
  for (int o = 1; o < 16; o <<= 1)
#pragma unroll
    for (int r = 0; r < 4; ++r) mx[r] = fmaxf(mx[r], __shfl_xor(mx[r], o));
  if (lm == 0) {
#pragma unroll
    for (int r = 0; r < 4; ++r) su.scr[half][qq0 + r] = mx[r];
  }
  __syncthreads();
#pragma unroll
  for (int r = 0; r < 4; ++r) mx[r] = fmaxf(mx[r], su.scr[half ^ 1][qq0 + r]);
  float sme[4] = {0.f, 0.f, 0.f, 0.f};
#pragma unroll
  for (int lct = 0; lct < 16; ++lct)
#pragma unroll
    for (int r = 0; r < 4; ++r) {
      acc[lct][r] = __expf(acc[lct][r] - mx[r]);
      sme[r] += acc[lct][r];
    }
#pragma unroll
  for (int o = 1; o < 16; o <<= 1)
#pragma unroll
    for (int r = 0; r < 4; ++r) sme[r] += __shfl_xor(sme[r], o);
  if (lm == 0) {
#pragma unroll
    for (int r = 0; r < 4; ++r) su.scr[2 + half][qq0 + r] = sme[r];
  }
  __syncthreads();
#pragma unroll
  for (int r = 0; r < 4; ++r) {
    const float inv = 1.f / (sme[r] + su.scr[2 + (half ^ 1)][qq0 + r]);
#pragma unroll
    for (int lct = 0; lct < 16; ++lct) acc[lct][r] *= inv;
  }
  __syncthreads();

  // ======== PV + coalesced attn write: 8 chunks of 32 c per half ========
  // Pl slab per wave: [16 q][72 c] ushort, 16B-aligned rows -> b128 reads.
  ushort* Pl = psl + ((band << 1) | half) * 1152;
  const ushort* vtb = vT + ((size_t)((b << 9) + (hh << 6))) * 512;
  const int vrow = t >> 1, vc = (t & 1) << 4;
  const int vh = vrow >> 6, vd = vrow & 63;
  float* abase = attn + ((size_t)z << 18);
  f32x4 acc2[4];
#pragma unroll
  for (int i = 0; i < 4; ++i) acc2[i] = (f32x4)(0.f);
  bf16x8 p0 = *(const bf16x8*)&vtb[(size_t)vd * 512 + (vh << 8) + vc];
  bf16x8 p1 = *(const bf16x8*)&vtb[(size_t)vd * 512 + (vh << 8) + vc + 8];
#pragma unroll
  for (int ch = 0; ch < 8; ++ch) {
#pragma unroll
    for (int ctl = 0; ctl < 2; ++ctl) {
      const int lct = (ch << 1) + ctl;
#pragma unroll
      for (int r = 0; r < 4; ++r)
        Pl[(fr4 + r) * 72 + (ctl << 4) + lm] = f2bf(acc[lct][r]);
    }
    __syncthreads();
    *(bf16x8*)&su.v2[vh][vd][vc] = p0;
    *(bf16x8*)&su.v2[vh][vd][vc + 8] = p1;
    if (ch < 7) {
      const size_t off = (size_t)vd * 512 + (vh << 8) + ((ch + 1) << 5) + vc;
      p0 = *(const bf16x8*)&vtb[off];
      p1 = *(const bf16x8*)&vtb[off + 8];
    }
    // attn write from Pl: one b128 read + float4 x2 stores
    {
      const int row = lane >> 2, colg = (lane & 3) << 3;
      const bf16x8 pv8 = *(const bf16x8*)&Pl[row * 72 + colg];
      float* ar = abase + (size_t)(q0 + (band << 4) + row) * 512 + C0 + (ch << 5) + colg;
      float4 o0, o1;
      o0.x = bf2f((ushort)pv8[0]); o0.y = bf2f((ushort)pv8[1]);
      o0.z = bf2f((ushort)pv8[2]); o0.w = bf2f((ushort)pv8[3]);
      o1.x = bf2f((ushort)pv8[4]); o1.y = bf2f((ushort)pv8[5]);
      o1.z = bf2f((ushort)pv8[6]); o1.w = bf2f((ushort)pv8[7]);
      *(float4*)&ar[0] = o0;
      *(float4*)&ar[4] = o1;
    }
    __syncthreads();
    __builtin_amdgcn_s_setprio(1);
#pragma unroll
    for (int dt = 0; dt < 4; ++dt) {
      const bf16x8 va = *(const bf16x8*)&su.v2[half][(dt << 4) + lm][lk];
      const bf16x8 pbf = *(const bf16x8*)&Pl[lm * 72 + lk];
      acc2[dt] = __builtin_amdgcn_mfma_f32_16x16x32_bf16(va, pbf, acc2[dt], 0, 0, 0);
    }
    __builtin_amdgcn_s_setprio(0);
  }
  __syncthreads();
  if (half == 1) {
#pragma unroll
    for (int dt = 0; dt < 4; ++dt)
#pragma unroll
      for (int r = 0; r < 4; ++r)
        su.scrC[band][(dt << 4) + fr4 + r][lm] = acc2[dt][r];
  }
  __syncthreads();
  if (half == 0) {
    const int qq2 = q0 + (band << 4) + lm;
#pragma unroll
    for (int dt = 0; dt < 4; ++dt) {
      ushort4 o;
      o.x = f2bf(acc2[dt][0] + su.scrC[band][(dt << 4) + fr4 + 0][lm]);
      o.y = f2bf(acc2[dt][1] + su.scrC[band][(dt << 4) + fr4 + 1][lm]);
      o.z = f2bf(acc2[dt][2] + su.scrC[band][(dt << 4) + fr4 + 2][lm]);
      o.w = f2bf(acc2[dt][3] + su.scrC[band][(dt << 4) + fr4 + 3][lm]);
      *(ushort4*)&ctx[((size_t)((b << 9) + qq2)) * 512 + (hh << 6) + (dt << 4) + fr4] = o;
    }
  }
}

// ------------- depthwise conv (K=31) + BN + swish, register sliding window ------
__global__ __launch_bounds__(256) void dwconv2(const ushort* __restrict__ in,
                                               const float* __restrict__ w,
                                               const float* __restrict__ bng,
                                               const float* __restrict__ bnb,
                                               const float* __restrict__ bnm,
                                               const float* __restrict__ bnv,
                                               ushort* __restrict__ out) {
  __shared__ float wl[31][128];
  const int t = threadIdx.x;
  const int dbase = blockIdx.x << 7;
  const int b = blockIdx.z;
  const int sb = (blockIdx.y << 6) + ((t >> 6) << 4);
  if (t < 128) {
    const float* ws = &w[(dbase + t) * 31];
#pragma unroll
    for (int k = 0; k < 31; ++k) wl[k][t] = ws[k];
  }
  __syncthreads();
  const int dl = (t & 63) << 1;
  const int d = dbase + dl;
  const size_t base = (((size_t)b) << 18) + d;
  float2 win[46];
#pragma unroll
  for (int i = 0; i < 46; ++i) {
    const int s = sb - 15 + i;
    if (s >= 0 && s < 512) {
      const ushort2 u = *(const ushort2*)&in[base + ((size_t)s << 9)];
      win[i].x = bf2f(u.x); win[i].y = bf2f(u.y);
    } else {
      win[i].x = 0.f; win[i].y = 0.f;
    }
  }
  float2 acc[16];
#pragma unroll
  for (int p = 0; p < 16; ++p) { acc[p].x = 0.f; acc[p].y = 0.f; }
#pragma unroll
  for (int k = 0; k < 31; ++k) {
    const float2 w2 = *(const float2*)&wl[k][dl];
#pragma unroll
    for (int p = 0; p < 16; ++p) {
      acc[p].x = fmaf(win[p + k].x, w2.x, acc[p].x);
      acc[p].y = fmaf(win[p + k].y, w2.y, acc[p].y);
    }
  }
  const float g0 = bng[d] * rsqrtf(bnv[d] + EPSF);
  const float g1 = bng[d + 1] * rsqrtf(bnv[d + 1] + EPSF);
  const float m0 = bnm[d], m1 = bnm[d + 1];
  const float bb0 = bnb[d], bb1 = bnb[d + 1];
#pragma unroll
  for (int p = 0; p < 16; ++p) {
    float v0 = (acc[p].x - m0) * g0 + bb0;
    float v1 = (acc[p].y - m1) * g1 + bb1;
    v0 = v0 * sigmf(v0);
    v1 = v1 * sigmf(v1);
    ushort2 o;
    o.x = f2bf(v0); o.y = f2bf(v1);
    *(ushort2*)&out[base + ((size_t)(sb + p) << 9)] = o;
  }
}

extern "C" void kernel_launch(void* const* d_in, const int* in_sizes, int n_in,
                              void* d_out, int out_size, void* d_ws, size_t ws_size,
                              hipStream_t stream) {
  const float* x      = (const float*)d_in[0];
  const float* ff1_g  = (const float*)d_in[1];
  const float* ff1_b  = (const float*)d_in[2];
  const float* ff1_w1 = (const float*)d_in[3];
  const float* ff1_b1 = (const float*)d_in[4];
  const float* ff1_w2 = (const float*)d_in[5];
  const float* ff1_b2 = (const float*)d_in[6];
  const float* attn_g = (const float*)d_in[7];
  const float* attn_b = (const float*)d_in[8];
  const float* wq     = (const float*)d_in[9];
  const float* bq     = (const float*)d_in[10];
  const float* wk     = (const float*)d_in[11];
  const float* bk     = (const float*)d_in[12];
  const float* wv     = (const float*)d_in[13];
  const float* bv     = (const float*)d_in[14];
  const float* wpos   = (const float*)d_in[15];
  const float* u_bias = (const float*)d_in[16];
  const float* v_bias = (const float*)d_in[17];
  const float* wo     = (const float*)d_in[18];
  const float* bo     = (const float*)d_in[19];
  const float* conv_g = (const float*)d_in[20];
  const float* conv_b = (const float*)d_in[21];
  const float* pw1_w  = (const float*)d_in[22];
  const float* pw1_b  = (const float*)d_in[23];
  const float* dw_w   = (const float*)d_in[24];
  const float* bn_g   = (const float*)d_in[25];
  const float* bn_b   = (const float*)d_in[26];
  const float* bn_m   = (const float*)d_in[27];
  const float* bn_v   = (const float*)d_in[28];
  const float* pw2_w  = (const float*)d_in[29];
  const float* pw2_b  = (const float*)d_in[30];
  const float* ff2_g  = (const float*)d_in[31];
  const float* ff2_b  = (const float*)d_in[32];
  const float* ff2_w1 = (const float*)d_in[33];
  const float* ff2_b1 = (const float*)d_in[34];
  const float* ff2_w2 = (const float*)d_in[35];
  const float* ff2_b2 = (const float*)d_in[36];
  const float* ln_g   = (const float*)d_in[37];
  const float* ln_b   = (const float*)d_in[38];

  float* out  = (float*)d_out;            // [B,S,D] f32
  float* attn = out + ND;                 // [B,H,S,S] f32

  // workspace layout (region sizes conservative; res now bf16)
  ushort* resb = (ushort*)d_ws;                  // ND ushorts (residual, bf16)
  ushort* ybf  = resb + ND;                      // ND ushorts (LN out)
  float*  big  = (float*)(ybf + ND);             // 2*ND f32 region
  ushort* vT   = (ushort*)(big + 2 * ND);        // ND ushorts [b][col][s]
  ushort* dwbf = vT + ND;                        // ND ushorts
  ushort* wts  = dwbf + ND;                      // 6,291,456 ushorts
  ushort* pebf = wts + 6291456;                  // 262,144
  ushort* ppbf = pebf + 262144;                  // 262,144

  ushort* ffmid = (ushort*)big;
  ushort* qu    = (ushort*)big;
  ushort* qv    = qu + ND;
  ushort* kbb   = qv + ND;
  ushort* ctxbf = ybf;
  ushort* glubf = (ushort*)big;

  ushort* ff1w1t = wts;
  ushort* ff1w2t = wts + 1048576;
  ushort* wqt    = wts + 2097152;
  ushort* wkt    = wts + 2359296;
  ushort* wvt    = wts + 2621440;
  ushort* wot    = wts + 2883584;
  ushort* pw1t   = wts + 3145728;
  ushort* pw2t   = wts + 3670016;
  ushort* ff2w1t = wts + 3932160;
  ushort* ff2w2t = wts + 4980736;
  ushort* wpost  = wts + 6029312;

  const dim3 blk(256);

  // ---- weight prep: single merged transpose dispatch ----
  TpArgs ta;
  auto set = [&](int i, const float* s, ushort* d, int K, int N) {
    ta.src[i] = s; ta.dst[i] = d; ta.K[i] = K; ta.N[i] = N;
  };
  set(0, ff1_w1, ff1w1t, 512, 2048);
  set(1, ff1_w2, ff1w2t, 2048, 512);
  set(2, wq, wqt, 512, 512);
  set(3, wk, wkt, 512, 512);
  set(4, wv, wvt, 512, 512);
  set(5, wo, wot, 512, 512);
  set(6, wpos, wpost, 512, 512);
  set(7, pw1_w, pw1t, 512, 1024);
  set(8, pw2_w, pw2t, 512, 512);
  set(9, ff2_w1, ff2w1t, 512, 2048);
  set(10, ff2_w2, ff2w2t, 2048, 512);
  int tacc = 0;
  for (int i = 0; i < 11; ++i) { ta.base[i] = tacc; tacc += (ta.N[i] >> 5) * (ta.K[i] >> 5); }
  ta.base[11] = tacc;
  transpose_all<<<tacc, blk, 0, stream>>>(ta);
  pe_kernel_bf16<<<512, blk, 0, stream>>>(pebf);
  gemm_bf16<0, 0, 0, 1, 0><<<dim3(4, 4), blk, 0, stream>>>(pebf, wpost, nullptr, nullptr, ppbf,
                                                           512, 512, 512);

  // ---- Macaron FF1: resb = bf16(x + 0.5*FF(LN(x))) ----
  ln_bf16<<<NTOK / 4, blk, 0, stream>>>(x, ff1_g, ff1_b, ybf);
  gemm_bf16<1, 0, 1, 1, 0><<<dim3(16, 128), blk, 0, stream>>>(ybf, ff1w1t, ff1_b1, nullptr,
                                                              ffmid, NTOK, 512, 2048);
  gemm_bf16<0, 2, 1, 1, 0><<<dim3(4, 128), blk, 0, stream>>>(ffmid, ff1w2t, ff1_b2, x, resb,
                                                             NTOK, 2048, 512);

  // ---- Attention ----
  lnb_bf16<<<NTOK / 4, blk, 0, stream>>>(resb, attn_g, attn_b, ybf);
  gemm_qkv<<<dim3(12, 128), blk, 0, stream>>>(ybf, wqt, bq, bk, bv, u_bias, v_bias,
                                              qu, qv, kbb, vT, NTOK, 512);
  attn_fused9<<<dim3(16, 256), blk, 0, stream>>>(qu, qv, kbb, ppbf, vT, attn, ctxbf);
  gemm_bf16<0, 1, 1, 1, 1><<<dim3(4, 128), blk, 0, stream>>>(ctxbf, wot, bo, resb, resb,
                                                             NTOK, 512, 512);

  // ---- Conv module ----
  lnb_bf16<<<NTOK / 4, blk, 0, stream>>>(resb, conv_g, conv_b, ybf);
  gemm_glu<<<dim3(4, 128), blk, 0, stream>>>(ybf, pw1t, pw1_b, glubf, NTOK, 512);
  dwconv2<<<dim3(4, 8, 32), blk, 0, stream>>>(glubf, dw_w, bn_g, bn_b, bn_m, bn_v, dwbf);
  gemm_bf16<0, 1, 1, 1, 1><<<dim3(4, 128), blk, 0, stream>>>(dwbf, pw2t, pw2_b, resb, resb,
                                                             NTOK, 512, 512);

  // ---- Macaron FF2 + final LN ----
  lnb_bf16<<<NTOK / 4, blk, 0, stream>>>(resb, ff2_g, ff2_b, ybf);
  gemm_bf16<1, 0, 1, 1, 0><<<dim3(16, 128), blk, 0, stream>>>(ybf, ff2w1t, ff2_b1, nullptr,
                                                              ffmid, NTOK, 512, 2048);
  gemm_bf16<0, 2, 1, 1, 1><<<dim3(4, 128), blk, 0, stream>>>(ffmid, ff2w2t, ff2_b2, resb, resb,
                                                             NTOK, 2048, 512);
  lnb_f32<<<NTOK / 4, blk, 0, stream>>>(resb, ln_g, ln_b, out);
}